// Round 14
// baseline (742.380 us; speedup 1.0000x reference)
//
#include <hip/hip_runtime.h>
#include <hip/hip_bf16.h>

// Problem constants (from reference)
#define BATCH 4
#define NPROP 1024
#define HID 1024
#define NUM_CLASSES 21
#define FEAT_DIM 12544
#define NPB (BATCH * NPROP)             // 4096
#define IMG 800.0f
#define SCORE_THRESH 0.1f
#define NMS_THRESH 0.5f
#define NCOL 112                        // padded 21+84

typedef unsigned short u16;
typedef unsigned int u32;
typedef unsigned long long u64;
typedef short s16x8 __attribute__((ext_vector_type(8)));
typedef float f32x4 __attribute__((ext_vector_type(4)));

// hi/lo split of 2 floats via native RTNE bf16 converts (v_cvt_pk_bf16_f32).
__device__ __forceinline__ void split2(float x0, float x1, u32& hp, u32& lp) {
    __hip_bfloat162 h2 = __float22bfloat162_rn(make_float2(x0, x1));
    u32 h = *(u32*)&h2;
    float f0 = __uint_as_float(h << 16);
    float f1 = __uint_as_float(h & 0xffff0000u);
    __hip_bfloat162 l2 = __float22bfloat162_rn(make_float2(x0 - f0, x1 - f1));
    hp = h;
    lp = *(u32*)&l2;
}

// Tiled layout (LDS-image order, swizzle baked in):
//   T[blk][t][c(8)][lane(64)][8 u16], flat u16 off = ((blk*NTt + t)*8 + c)*512 + lane*8
__device__ __forceinline__ size_t tile_off(int blk, int NTt, int t, int row, int g) {
    int r = row & 127;
    int c = r >> 4;
    int lanei = ((r & 15) << 2) | (g ^ ((r >> 1) & 3));
    return ((((size_t)blk * NTt + t) * 8 + c) << 9) + lanei * 8;
}

// ============ fused prep kernel (all global R/W full-line coalesced) ============
#define NB_WCAT 448
#define NB_T7C  256          // 8 nb x 32 t
#define NB_T6C  3136         // 8 nb x 392 t
#define NB_SPA  2048
#define NB_PREP (NB_WCAT + NB_T7C + NB_T6C + NB_SPA)

// one block per (nb, t): stage W[t*32..+32][nb*128..+128] via LDS, emit 8 chunks
__device__ __forceinline__ void w_chunks(
    const float* __restrict__ W, u16* __restrict__ Th, u16* __restrict__ Tl,
    int NTt, int nb, int t, int tid, float (*lt)[129])
{
    const int n0 = nb * 128;
#pragma unroll
    for (int p = 0; p < 4; ++p) {
        int e = (p * 256 + tid) * 4;            // 0..4095 step 4
        int k = e >> 7;                          // tile row (k) 0..31
        int n = e & 127;                         // tile col (n)
        float4 v = *(const float4*)(W + (size_t)(t * 32 + k) * 1024 + n0 + n);
        lt[k][n] = v.x; lt[k][n + 1] = v.y; lt[k][n + 2] = v.z; lt[k][n + 3] = v.w;
    }
    __syncthreads();
    const int lane = tid & 63, w = tid >> 6;
#pragma unroll
    for (int i = 0; i < 2; ++i) {
        const int c = w * 2 + i;
        const int rl = c * 16 + (lane >> 2);            // local row (n) 0..127
        const int q = (lane & 3) ^ ((rl >> 1) & 3);     // content k-group
        u32 hp[4], lp[4];
#pragma unroll
        for (int e2 = 0; e2 < 4; ++e2)
            split2(lt[q * 8 + 2 * e2][rl], lt[q * 8 + 2 * e2 + 1][rl], hp[e2], lp[e2]);
        const size_t dsto = ((((size_t)nb * NTt + t) * 8 + c) << 9) + lane * 8;
        *(uint4*)&Th[dsto] = make_uint4(hp[0], hp[1], hp[2], hp[3]);
        *(uint4*)&Tl[dsto] = make_uint4(lp[0], lp[1], lp[2], lp[3]);
    }
    __syncthreads();
}

__global__ __launch_bounds__(256) void prep_kernel(
    const float* __restrict__ fc6_w, const float* __restrict__ fc7_w,
    const float* __restrict__ cls_w, const float* __restrict__ box_w,
    const float* __restrict__ A,
    u16* __restrict__ W6h, u16* __restrict__ W6l,
    u16* __restrict__ W7h, u16* __restrict__ W7l,
    float* __restrict__ Wcat, u16* __restrict__ A6h, u16* __restrict__ A6l)
{
    __shared__ float lt[32][129];
    const int b = blockIdx.x;
    const int tid = threadIdx.x;

    if (b < NB_WCAT) {
        int i = b * 256 + tid;
        if (i < HID * NCOL) {
            int k = i / NCOL, c = i % NCOL;
            float v = 0.0f;
            if (c < 21) v = cls_w[k * 21 + c];
            else if (c < 105) v = box_w[k * 84 + (c - 21)];
            Wcat[i] = v;
        }
    } else if (b < NB_WCAT + NB_T7C) {
        int idx = b - NB_WCAT;                  // 8 nb x 32 t
        w_chunks(fc7_w, W7h, W7l, 32, idx / 32, idx % 32, tid, lt);
    } else if (b < NB_WCAT + NB_T7C + NB_T6C) {
        int idx = b - NB_WCAT - NB_T7C;         // 8 nb x 392 t
        w_chunks(fc6_w, W6h, W6l, 392, idx / 392, idx % 392, tid, lt);
    } else {
        // A chunk-gather: wave builds one 1KB chunk (reads permuted full lines)
        const int sb = b - NB_WCAT - NB_T7C - NB_T6C;   // 0..2047
        const int lane = tid & 63;
        const int w = tid >> 6;
        const int NCH = (NPB / 128) * (FEAT_DIM / 32) * 8;   // 100352
        for (int ch = sb * 4 + w; ch < NCH; ch += NB_SPA * 4) {
            const int c = ch & 7;
            const int tmp = ch >> 3;
            const int t = tmp % (FEAT_DIM / 32);
            const int blk = tmp / (FEAT_DIM / 32);
            const int r = blk * 128 + c * 16 + (lane >> 2);
            const int col = t * 32 + (((lane & 3) ^ ((r >> 1) & 3)) << 3);
            const float* src = A + (size_t)r * FEAT_DIM + col;
            float4 v0 = *(const float4*)(src);
            float4 v1 = *(const float4*)(src + 4);
            u32 hp[4], lp[4];
            split2(v0.x, v0.y, hp[0], lp[0]);
            split2(v0.z, v0.w, hp[1], lp[1]);
            split2(v1.x, v1.y, hp[2], lp[2]);
            split2(v1.z, v1.w, hp[3], lp[3]);
            const size_t dsto = ((size_t)ch << 9) + lane * 8;
            *(uint4*)&A6h[dsto] = make_uint4(hp[0], hp[1], hp[2], hp[3]);
            *(uint4*)&A6l[dsto] = make_uint4(lp[0], lp[1], lp[2], lp[3]);
        }
    }
}

// ============ linear transpose+split (fallback paths) ============
__global__ __launch_bounds__(256) void transpose_split(
    const float* __restrict__ W, u16* __restrict__ WhT, u16* __restrict__ WlT,
    int K, int N)
{
    __shared__ float tile[32][33];
    const int tid = threadIdx.x;
    const int n0 = blockIdx.x * 32;
    const int k0 = blockIdx.y * 32;
    {
        int i = tid >> 3, j4 = (tid & 7) * 4;
        float4 v = *(const float4*)(W + (size_t)(k0 + i) * N + n0 + j4);
        tile[i][j4] = v.x; tile[i][j4 + 1] = v.y; tile[i][j4 + 2] = v.z; tile[i][j4 + 3] = v.w;
    }
    __syncthreads();
    {
        int i = tid >> 3, j4 = (tid & 7) * 4;
        u32 hp0, lp0, hp1, lp1;
        split2(tile[j4 + 0][i], tile[j4 + 1][i], hp0, lp0);
        split2(tile[j4 + 2][i], tile[j4 + 3][i], hp1, lp1);
        size_t o = (size_t)(n0 + i) * K + k0 + j4;
        *(uint2*)&WhT[o] = make_uint2(hp0, hp1);
        *(uint2*)&WlT[o] = make_uint2(lp0, lp1);
    }
}

// ============ concat cls_w | box_w (fallback paths) ============
__global__ void build_wcat(const float* __restrict__ cls_w, const float* __restrict__ box_w,
                           float* __restrict__ Wcat)
{
    int i = blockIdx.x * 256 + threadIdx.x;
    if (i >= HID * NCOL) return;
    int k = i / NCOL, c = i % NCOL;
    float v = 0.0f;
    if (c < 21) v = cls_w[k * 21 + c];
    else if (c < 105) v = box_w[k * 84 + (c - 21)];
    Wcat[i] = v;
}

// ============ tiled 2-phase GEMM: pure contiguous global_load_lds staging ========
// Generalized swizzle: mb = mb0 + xcd*(ymask+1) + yy, bz = j>>bzshift.
__global__ __launch_bounds__(256) void gemm_2ph_tiled(
    const u16* __restrict__ Ah, const u16* __restrict__ Al,
    const u16* __restrict__ Wh, const u16* __restrict__ Wl,
    const float* __restrict__ bias, float* __restrict__ Cout,
    int M, int Nn, int NTt, int tN, int mb0, int ymask, int bzshift)
{
    __shared__ u16 sm[2 * 16384];

    const int tid = threadIdx.x;
    const int lane = tid & 63;
    const int wv = tid >> 6;
    const int wr = wv >> 1, wc = wv & 1;

    const int flat = blockIdx.x + (blockIdx.y << 3) + blockIdx.z * 8 * gridDim.y;
    const int xcd = flat & 7;
    const int j = flat >> 3;
    const int bxi = j & 7;
    const int yy = (j >> 3) & ymask;
    const int bz = j >> bzshift;
    const int mb = mb0 + xcd * (ymask + 1) + yy;
    const int nb = bxi;
    const int bm = mb * 128, bn = nb * 128;
    const int t0 = bz * tN;

    const size_t abase = (size_t)mb * NTt * 4096;
    const size_t wbase = (size_t)nb * NTt * 4096;

    const int fr = lane & 15, fq = lane >> 4;
    int ia[4], ib[4];
#pragma unroll
    for (int m = 0; m < 4; ++m) {
        int ra = wr * 64 + m * 16 + fr;
        ia[m] = ra * 32 + ((fq ^ ((ra >> 1) & 3)) << 3);
        int rb = wc * 64 + m * 16 + fr;
        ib[m] = rb * 32 + ((fq ^ ((rb >> 1) & 3)) << 3);
    }

    f32x4 acc[4][4];
#pragma unroll
    for (int m = 0; m < 4; ++m)
#pragma unroll
        for (int n = 0; n < 4; ++n)
            acc[m][n] = (f32x4){0.f, 0.f, 0.f, 0.f};

    auto stage = [&](u16* dst, int t) {
#pragma unroll
        for (int i = 0; i < 2; ++i) {
            const int c = wv * 2 + i;
            const size_t so = (((size_t)t * 8 + c) << 9) + lane * 8;
            __builtin_amdgcn_global_load_lds(
                (const __attribute__((address_space(1))) u32*)(Ah + abase + so),
                (__attribute__((address_space(3))) u32*)(dst + c * 512), 16, 0, 0);
            __builtin_amdgcn_global_load_lds(
                (const __attribute__((address_space(1))) u32*)(Al + abase + so),
                (__attribute__((address_space(3))) u32*)(dst + 4096 + c * 512), 16, 0, 0);
            __builtin_amdgcn_global_load_lds(
                (const __attribute__((address_space(1))) u32*)(Wh + wbase + so),
                (__attribute__((address_space(3))) u32*)(dst + 8192 + c * 512), 16, 0, 0);
            __builtin_amdgcn_global_load_lds(
                (const __attribute__((address_space(1))) u32*)(Wl + wbase + so),
                (__attribute__((address_space(3))) u32*)(dst + 12288 + c * 512), 16, 0, 0);
        }
    };

    auto compute = [&](const u16* src) {
        s16x8 fah[4], fal[4], fbh[4], fbl[4];
#pragma unroll
        for (int m = 0; m < 4; ++m) {
            fah[m] = *(const s16x8*)&src[ia[m]];
            fal[m] = *(const s16x8*)&src[4096 + ia[m]];
            fbh[m] = *(const s16x8*)&src[8192 + ib[m]];
            fbl[m] = *(const s16x8*)&src[12288 + ib[m]];
        }
        __builtin_amdgcn_s_setprio(1);
#pragma unroll
        for (int m = 0; m < 4; ++m)
#pragma unroll
            for (int n = 0; n < 4; ++n) {
                acc[m][n] = __builtin_amdgcn_mfma_f32_16x16x32_bf16(fah[m], fbh[n], acc[m][n], 0, 0, 0);
                acc[m][n] = __builtin_amdgcn_mfma_f32_16x16x32_bf16(fah[m], fbl[n], acc[m][n], 0, 0, 0);
                acc[m][n] = __builtin_amdgcn_mfma_f32_16x16x32_bf16(fal[m], fbh[n], acc[m][n], 0, 0, 0);
            }
        __builtin_amdgcn_s_setprio(0);
    };

    u16* bufc = sm;
    u16* bufn = sm + 16384;

    stage(bufc, t0);
    for (int t = 0; t < tN; ++t) {
        if (t + 1 < tN) {
            stage(bufn, t0 + t + 1);
            asm volatile("s_waitcnt vmcnt(8)" ::: "memory");
        } else {
            asm volatile("s_waitcnt vmcnt(0)" ::: "memory");
        }
        asm volatile("s_barrier" ::: "memory");
        compute(bufc);
        asm volatile("s_barrier" ::: "memory");
        u16* tmp = bufc; bufc = bufn; bufn = tmp;
    }

    if (bias != nullptr) {
#pragma unroll
        for (int n = 0; n < 4; ++n) {
            int col = bn + wc * 64 + n * 16 + fr;
            float bb = bias[col];
#pragma unroll
            for (int m = 0; m < 4; ++m) {
                int row0 = bm + wr * 64 + m * 16 + fq * 4;
#pragma unroll
                for (int jj = 0; jj < 4; ++jj)
                    Cout[(size_t)(row0 + jj) * Nn + col] = fmaxf(acc[m][n][jj] + bb, 0.0f);
            }
        }
    } else {
        float* Cp = Cout + (size_t)bz * M * Nn;
#pragma unroll
        for (int n = 0; n < 4; ++n) {
            int col = bn + wc * 64 + n * 16 + fr;
#pragma unroll
            for (int m = 0; m < 4; ++m) {
                int row0 = bm + wr * 64 + m * 16 + fq * 4;
#pragma unroll
                for (int jj = 0; jj < 4; ++jj)
                    Cp[(size_t)(row0 + jj) * Nn + col] = acc[m][n][jj];
            }
        }
    }
}

// ============ round-7 2-phase GEMM (in-loop A split) — fallback ============
__global__ __launch_bounds__(256) void gemm_2ph(
    const float* __restrict__ A, const u16* __restrict__ WhT, const u16* __restrict__ WlT,
    const float* __restrict__ bias, float* __restrict__ Cout,
    int M, int Nn, int K, int KC)
{
    __shared__ u16 sm[2 * 16384];

    const int tid = threadIdx.x;
    const int lane = tid & 63;
    const int wv = tid >> 6;
    const int wr = wv >> 1, wc = wv & 1;

    const int flat = blockIdx.x + (blockIdx.y << 3) + (blockIdx.z << 8);
    const int xcd = flat & 7;
    const int j = flat >> 3;
    const int bxi = j & 7;
    const int yy = (j >> 3) & 3;
    const int bz = j >> 5;
    const int bm = (xcd * 4 + yy) * 128;
    const int bn = bxi * 128;
    const int k0 = bz * KC;
    const int NT = KC / 32;

    const int ar = tid >> 1;
    const int ah = tid & 1;
    const float* aPtr = A + (size_t)(bm + ar) * K + ah * 16;
    const int asw = (ar >> 1) & 3;
    const int ac0 = ((2 * ah) ^ asw) << 3;
    const int ac1 = ((2 * ah + 1) ^ asw) << 3;

    int wrow[2], wlc[2];
#pragma unroll
    for (int i = 0; i < 2; ++i) {
        int c = wv * 2 + i;
        wrow[i] = c * 16 + (lane >> 2);
        wlc[i] = ((lane & 3) ^ ((wrow[i] >> 1) & 3)) * 8;
    }

    const int fr = lane & 15, fq = lane >> 4;
    int ia[4], ib[4];
#pragma unroll
    for (int m = 0; m < 4; ++m) {
        int ra = wr * 64 + m * 16 + fr;
        ia[m] = ra * 32 + ((fq ^ ((ra >> 1) & 3)) << 3);
        int rb = wc * 64 + m * 16 + fr;
        ib[m] = rb * 32 + ((fq ^ ((rb >> 1) & 3)) << 3);
    }

    f32x4 acc[4][4];
#pragma unroll
    for (int m = 0; m < 4; ++m)
#pragma unroll
        for (int n = 0; n < 4; ++n)
            acc[m][n] = (f32x4){0.f, 0.f, 0.f, 0.f};

    auto stage_w = [&](u16* dst, int kk) {
#pragma unroll
        for (int i = 0; i < 2; ++i) {
            const int c = wv * 2 + i;
            const u16* gh = WhT + (size_t)(bn + wrow[i]) * K + kk + wlc[i];
            const u16* gl = WlT + (size_t)(bn + wrow[i]) * K + kk + wlc[i];
            __builtin_amdgcn_global_load_lds(
                (const __attribute__((address_space(1))) u32*)gh,
                (__attribute__((address_space(3))) u32*)(dst + 8192 + c * 512), 16, 0, 0);
            __builtin_amdgcn_global_load_lds(
                (const __attribute__((address_space(1))) u32*)gl,
                (__attribute__((address_space(3))) u32*)(dst + 12288 + c * 512), 16, 0, 0);
        }
    };

    auto split_a = [&](u16* dst, float4 v0, float4 v1, float4 v2, float4 v3) {
        u32 hp[8], lp[8];
        split2(v0.x, v0.y, hp[0], lp[0]);
        split2(v0.z, v0.w, hp[1], lp[1]);
        split2(v1.x, v1.y, hp[2], lp[2]);
        split2(v1.z, v1.w, hp[3], lp[3]);
        split2(v2.x, v2.y, hp[4], lp[4]);
        split2(v2.z, v2.w, hp[5], lp[5]);
        split2(v3.x, v3.y, hp[6], lp[6]);
        split2(v3.z, v3.w, hp[7], lp[7]);
        *(uint4*)&dst[ar * 32 + ac0] = make_uint4(hp[0], hp[1], hp[2], hp[3]);
        *(uint4*)&dst[ar * 32 + ac1] = make_uint4(hp[4], hp[5], hp[6], hp[7]);
        *(uint4*)&dst[4096 + ar * 32 + ac0] = make_uint4(lp[0], lp[1], lp[2], lp[3]);
        *(uint4*)&dst[4096 + ar * 32 + ac1] = make_uint4(lp[4], lp[5], lp[6], lp[7]);
    };

    auto compute = [&](const u16* src) {
        s16x8 fah[4], fal[4], fbh[4], fbl[4];
#pragma unroll
        for (int m = 0; m < 4; ++m) {
            fah[m] = *(const s16x8*)&src[ia[m]];
            fal[m] = *(const s16x8*)&src[4096 + ia[m]];
            fbh[m] = *(const s16x8*)&src[8192 + ib[m]];
            fbl[m] = *(const s16x8*)&src[12288 + ib[m]];
        }
        __builtin_amdgcn_s_setprio(1);
#pragma unroll
        for (int m = 0; m < 4; ++m)
#pragma unroll
            for (int n = 0; n < 4; ++n) {
                acc[m][n] = __builtin_amdgcn_mfma_f32_16x16x32_bf16(fah[m], fbh[n], acc[m][n], 0, 0, 0);
                acc[m][n] = __builtin_amdgcn_mfma_f32_16x16x32_bf16(fah[m], fbl[n], acc[m][n], 0, 0, 0);
                acc[m][n] = __builtin_amdgcn_mfma_f32_16x16x32_bf16(fal[m], fbh[n], acc[m][n], 0, 0, 0);
            }
        __builtin_amdgcn_s_setprio(0);
    };

    u16* bufc = sm;
    u16* bufn = sm + 16384;

    stage_w(bufc, k0);
    {
        float4 a0 = *(const float4*)(aPtr + k0 + 0);
        float4 a1 = *(const float4*)(aPtr + k0 + 4);
        float4 a2 = *(const float4*)(aPtr + k0 + 8);
        float4 a3 = *(const float4*)(aPtr + k0 + 12);
        split_a(bufc, a0, a1, a2, a3);
    }
    asm volatile("s_waitcnt vmcnt(0) lgkmcnt(0)\n\ts_barrier" ::: "memory");

    for (int t = 0; t < NT; ++t) {
        float4 a0{}, a1{}, a2{}, a3{};
        const bool hn = (t + 1 < NT);
        if (hn) {
            const int kk = k0 + (t + 1) * 32;
            stage_w(bufn, kk);
            a0 = *(const float4*)(aPtr + kk + 0);
            a1 = *(const float4*)(aPtr + kk + 4);
            a2 = *(const float4*)(aPtr + kk + 8);
            a3 = *(const float4*)(aPtr + kk + 12);
        }
        compute(bufc);
        if (hn) split_a(bufn, a0, a1, a2, a3);
        asm volatile("s_waitcnt vmcnt(0) lgkmcnt(0)\n\ts_barrier" ::: "memory");
        u16* tmp = bufc; bufc = bufn; bufn = tmp;
    }

    if (bias != nullptr) {
#pragma unroll
        for (int n = 0; n < 4; ++n) {
            int col = bn + wc * 64 + n * 16 + fr;
            float bb = bias[col];
#pragma unroll
            for (int m = 0; m < 4; ++m) {
                int row0 = bm + wr * 64 + m * 16 + fq * 4;
#pragma unroll
                for (int jj = 0; jj < 4; ++jj)
                    Cout[(size_t)(row0 + jj) * Nn + col] = fmaxf(acc[m][n][jj] + bb, 0.0f);
            }
        }
    } else {
        float* Cp = Cout + (size_t)bz * M * Nn;
#pragma unroll
        for (int n = 0; n < 4; ++n) {
            int col = bn + wc * 64 + n * 16 + fr;
#pragma unroll
            for (int m = 0; m < 4; ++m) {
                int row0 = bm + wr * 64 + m * 16 + fq * 4;
#pragma unroll
                for (int jj = 0; jj < 4; ++jj)
                    Cp[(size_t)(row0 + jj) * Nn + col] = acc[m][n][jj];
            }
        }
    }
}

// ============ reduce 4 partials + bias + relu (fp32 out, fallback) ============
__global__ __launch_bounds__(256) void reduce_bias_relu(
    const float* __restrict__ Cpart, const float* __restrict__ bias,
    float* __restrict__ X, int MN, int Nn)
{
    const int total = MN / 4;
    for (int i4 = blockIdx.x * 256 + threadIdx.x; i4 < total; i4 += gridDim.x * 256) {
        const size_t o = (size_t)i4 * 4;
        float4 a = *(const float4*)(Cpart + o);
        float4 b = *(const float4*)(Cpart + (size_t)MN + o);
        float4 c = *(const float4*)(Cpart + 2 * (size_t)MN + o);
        float4 d = *(const float4*)(Cpart + 3 * (size_t)MN + o);
        float4 bb = *(const float4*)(bias + (o & (size_t)(Nn - 1)));
        float4 r;
        r.x = fmaxf(a.x + b.x + c.x + d.x + bb.x, 0.0f);
        r.y = fmaxf(a.y + b.y + c.y + d.y + bb.y, 0.0f);
        r.z = fmaxf(a.z + b.z + c.z + d.z + bb.z, 0.0f);
        r.w = fmaxf(a.w + b.w + c.w + d.w + bb.w, 0.0f);
        *(float4*)(X + o) = r;
    }
}

// ============ reduce 4 partials + bias + relu, emit tiled split bf16 ============
__global__ __launch_bounds__(256) void reduce_split_tiled(
    const float* __restrict__ Cpart, const float* __restrict__ bias,
    u16* __restrict__ Xh, u16* __restrict__ Xl, int MN, int Nn)
{
    const int total = MN / 8;
    for (int i = blockIdx.x * 256 + threadIdx.x; i < total; i += gridDim.x * 256) {
        const size_t o = (size_t)i * 8;
        float r8[8];
#pragma unroll
        for (int h = 0; h < 2; ++h) {
            float4 a = *(const float4*)(Cpart + o + h * 4);
            float4 b = *(const float4*)(Cpart + (size_t)MN + o + h * 4);
            float4 c = *(const float4*)(Cpart + 2 * (size_t)MN + o + h * 4);
            float4 d = *(const float4*)(Cpart + 3 * (size_t)MN + o + h * 4);
            float4 bb = *(const float4*)(bias + ((o + h * 4) & (size_t)(Nn - 1)));
            r8[h * 4 + 0] = fmaxf(a.x + b.x + c.x + d.x + bb.x, 0.0f);
            r8[h * 4 + 1] = fmaxf(a.y + b.y + c.y + d.y + bb.y, 0.0f);
            r8[h * 4 + 2] = fmaxf(a.z + b.z + c.z + d.z + bb.z, 0.0f);
            r8[h * 4 + 3] = fmaxf(a.w + b.w + c.w + d.w + bb.w, 0.0f);
        }
        u32 hp[4], lp[4];
#pragma unroll
        for (int t2 = 0; t2 < 4; ++t2)
            split2(r8[2 * t2], r8[2 * t2 + 1], hp[t2], lp[t2]);
        int row = (int)(o >> 10);                 // Nn == 1024
        int rem = (int)(o & 1023);
        int t = rem >> 5, g = (rem >> 3) & 3;
        size_t dsto = tile_off(row >> 7, 32, t, row, g);
        *(uint4*)&Xh[dsto] = make_uint4(hp[0], hp[1], hp[2], hp[3]);
        *(uint4*)&Xl[dsto] = make_uint4(lp[0], lp[1], lp[2], lp[3]);
    }
}

// ============ fused heads GEMM + postproc (16 rows/block, fp32 exact) ========
__global__ __launch_bounds__(256) void heads_postproc(
    const float* __restrict__ X2, const float* __restrict__ Wcat,
    const float* __restrict__ cls_b, const float* __restrict__ box_b,
    const float* __restrict__ proposals,
    float* __restrict__ bxo, float* __restrict__ sco,
    int* __restrict__ lbo, int* __restrict__ vdo)
{
    __shared__ float Xs[16][36];
    __shared__ float Ws[32 * NCOL];
    __shared__ float lgs[16][NCOL];
    const int tid = threadIdx.x;
    const int m0 = blockIdx.x * 16;
    const int tr = tid >> 4;            // 16 rows
    const int tc = tid & 15;            // 16 col-groups x 7
    float acc[7] = {};
    for (int k0 = 0; k0 < HID; k0 += 32) {
        if (tid < 128) {
            int i = tid >> 3, j4 = (tid & 7) * 4;
            float4 v = *(const float4*)(X2 + (size_t)(m0 + i) * HID + k0 + j4);
            Xs[i][j4] = v.x; Xs[i][j4 + 1] = v.y; Xs[i][j4 + 2] = v.z; Xs[i][j4 + 3] = v.w;
        }
        const float4* src = (const float4*)(Wcat + (size_t)k0 * NCOL);
        float4* dst = (float4*)Ws;
        for (int i4 = tid; i4 < (32 * NCOL) / 4; i4 += 256) dst[i4] = src[i4];
        __syncthreads();
#pragma unroll 4
        for (int kk = 0; kk < 32; ++kk) {
            float a0 = Xs[tr][kk];
#pragma unroll
            for (int j = 0; j < 7; ++j)
                acc[j] = fmaf(a0, Ws[kk * NCOL + tc * 7 + j], acc[j]);
        }
        __syncthreads();
    }
#pragma unroll
    for (int j = 0; j < 7; ++j)
        lgs[tr][tc * 7 + j] = acc[j];
    __syncthreads();

    if (tid < 16) {
        const int p = m0 + tid;
        const float* lg = lgs[tid];
        float l[21];
        float m = -1e30f;
#pragma unroll
        for (int c = 0; c < 21; ++c) { l[c] = lg[c] + cls_b[c]; m = fmaxf(m, l[c]); }
        float e[21]; float s = 0.0f;
#pragma unroll
        for (int c = 0; c < 21; ++c) { e[c] = expf(l[c] - m); s += e[c]; }
        int best = 1;
#pragma unroll
        for (int c = 2; c < 21; ++c) if (e[c] > e[best]) best = c;
        const float score = e[best] / s;

        float d0 = (lg[21 + best * 4 + 0] + box_b[best * 4 + 0]) * 0.1f;
        float d1 = (lg[21 + best * 4 + 1] + box_b[best * 4 + 1]) * 0.1f;
        float d2 = (lg[21 + best * 4 + 2] + box_b[best * 4 + 2]) * 0.2f;
        float d3 = (lg[21 + best * 4 + 3] + box_b[best * 4 + 3]) * 0.2f;
        const float* pr = proposals + p * 4;
        float w_ = pr[2] - pr[0], h_ = pr[3] - pr[1];
        float cx = pr[0] + 0.5f * w_, cy = pr[1] + 0.5f * h_;
        float pcx = d0 * w_ + cx, pcy = d1 * h_ + cy;
        float pw = expf(d2) * w_, ph = expf(d3) * h_;
        float b0 = pcx - 0.5f * pw, b1 = pcy - 0.5f * ph;
        float b2 = pcx + 0.5f * pw, b3 = pcy + 0.5f * ph;
        b0 = fminf(fmaxf(b0, 0.0f), IMG);
        b1 = fminf(fmaxf(b1, 0.0f), IMG);
        b2 = fminf(fmaxf(b2, 0.0f), IMG);
        b3 = fminf(fmaxf(b3, 0.0f), IMG);
        int vd = (b2 - b0 > 0.0f) && (b3 - b1 > 0.0f) && (score > SCORE_THRESH);
        bxo[p * 4 + 0] = b0; bxo[p * 4 + 1] = b1;
        bxo[p * 4 + 2] = b2; bxo[p * 4 + 3] = b3;
        sco[p] = score;
        lbo[p] = best;
        vdo[p] = vd;
    }
}

// ============ fused NMS + finalize ============
__global__ __launch_bounds__(1024) void nms_finalize(
    const float* __restrict__ bx, const float* __restrict__ sc,
    const int* __restrict__ label, const int* __restrict__ valid,
    const float* __restrict__ proposals, float* __restrict__ out)
{
    const int img = blockIdx.x;
    const int base = img * NPROP;
    const int tid = threadIdx.x;

    __shared__ u64 maskm[NPROP][16];
    __shared__ float4 sbx[NPROP];
    __shared__ float sarea[NPROP];
    __shared__ unsigned char skeep[NPROP];
    __shared__ u64 kword[16];
    __shared__ int nv;

    u64* skey = &maskm[0][0];

    if (tid == 0) nv = 0;

    {
        float s = valid[base + tid] ? sc[base + tid] : -1.0f;
        unsigned u = __float_as_uint(s);
        u = (u & 0x80000000u) ? ~u : (u | 0x80000000u);
        u = ~u;
        skey[tid] = ((u64)u << 32) | (unsigned)tid;
    }
    for (int k = 2; k <= NPROP; k <<= 1) {
        for (int j = k >> 1; j > 0; j >>= 1) {
            __syncthreads();
            int ixj = tid ^ j;
            if (ixj > tid) {
                u64 a = skey[tid], b = skey[ixj];
                bool up = ((tid & k) == 0);
                if (up ? (a > b) : (a < b)) { skey[tid] = b; skey[ixj] = a; }
            }
        }
    }
    __syncthreads();

    const int myp = (int)(skey[tid] & 0xffffffffu);
    {
        float off = (float)label[base + myp] * (IMG + 1.0f);
        float x0 = bx[(base + myp) * 4 + 0] + off;
        float y0 = bx[(base + myp) * 4 + 1] + off;
        float x1 = bx[(base + myp) * 4 + 2] + off;
        float y1 = bx[(base + myp) * 4 + 3] + off;
        sbx[tid] = make_float4(x0, y0, x1, y1);
        sarea[tid] = (x1 - x0) * (y1 - y0);
        int v = valid[base + myp];
        skeep[tid] = (unsigned char)v;
        if (v) atomicMax(&nv, tid + 1);
    }
    __syncthreads();
    const int nvalid = nv;

    for (int idx = tid; idx < nvalid * 16; idx += 1024) {
        const int i = idx >> 4, w = idx & 15;
        const float4 bi = sbx[i];
        const float ai = sarea[i];
        u64 bits = 0;
        const int jlo = w * 64;
        const int jhi = min(jlo + 64, nvalid);
        for (int j = max(jlo, i + 1); j < jhi; ++j) {
            float4 bj = sbx[j];
            float lt0 = fmaxf(bi.x, bj.x);
            float lt1 = fmaxf(bi.y, bj.y);
            float rb0 = fminf(bi.z, bj.z);
            float rb1 = fminf(bi.w, bj.w);
            float w_ = fmaxf(rb0 - lt0, 0.0f);
            float h_ = fmaxf(rb1 - lt1, 0.0f);
            float inter = w_ * h_;
            float denom = fmaxf(ai + sarea[j] - inter, 1e-9f);
            if (inter / denom > NMS_THRESH) bits |= 1ull << (j - jlo);
        }
        maskm[i][w] = bits;
    }
    if (tid < 16) {
        u64 kw = 0;
        for (int b = 0; b < 64; ++b)
            kw |= (u64)(skeep[tid * 64 + b] ? 1 : 0) << b;
        kword[tid] = kw;
    }
    __syncthreads();

    if (tid < 64) {
        u64 kw = (tid < 16) ? kword[tid] : 0ull;
        for (int i = 0; i < nvalid; ++i) {
            u64 srcw = __shfl(kw, i >> 6, 64);
            if ((srcw >> (i & 63)) & 1ull) {
                if (tid < 16) kw &= ~maskm[i][tid];
            }
        }
        if (tid < 16) kword[tid] = kw;
    }
    __syncthreads();

    {
        const int p = base + myp;
        const bool k = ((kword[tid >> 6] >> (tid & 63)) & 1ull) != 0;
        float* res   = out;
        float* keepo = out + NPB * 6;
        float* rpn   = keepo + NPB;
        float* rcnn  = rpn + NPB * 6;
        float b0 = bx[p * 4 + 0], b1 = bx[p * 4 + 1];
        float b2 = bx[p * 4 + 2], b3 = bx[p * 4 + 3];
        res[p * 6 + 0] = k ? b0 : 0.0f;
        res[p * 6 + 1] = k ? b1 : 0.0f;
        res[p * 6 + 2] = k ? b2 : 0.0f;
        res[p * 6 + 3] = k ? b3 : 0.0f;
        res[p * 6 + 4] = k ? (float)(label[p] - 1) : 0.0f;
        res[p * 6 + 5] = k ? sc[p] : 0.0f;
        keepo[p] = k ? 1.0f : 0.0f;
        rpn[p * 6 + 0] = proposals[p * 4 + 0];
        rpn[p * 6 + 1] = proposals[p * 4 + 1];
        rpn[p * 6 + 2] = proposals[p * 4 + 2];
        rpn[p * 6 + 3] = proposals[p * 4 + 3];
        rpn[p * 6 + 4] = 0.0f;
        rpn[p * 6 + 5] = 0.0f;
        rcnn[p * 6 + 0] = b0;
        rcnn[p * 6 + 1] = b1;
        rcnn[p * 6 + 2] = b2;
        rcnn[p * 6 + 3] = b3;
        rcnn[p * 6 + 4] = 0.0f;
        rcnn[p * 6 + 5] = 0.0f;
    }
}

// ============ launch ============
extern "C" void kernel_launch(void* const* d_in, const int* in_sizes, int n_in,
                              void* d_out, int out_size, void* d_ws, size_t ws_size,
                              hipStream_t stream)
{
    const float* props_feature = (const float*)d_in[0];
    const float* proposals     = (const float*)d_in[1];
    const float* fc6_w         = (const float*)d_in[2];
    const float* fc6_b         = (const float*)d_in[3];
    const float* fc7_w         = (const float*)d_in[4];
    const float* fc7_b         = (const float*)d_in[5];
    const float* cls_w         = (const float*)d_in[6];
    const float* cls_b         = (const float*)d_in[7];
    const float* box_w         = (const float*)d_in[8];
    const float* box_b         = (const float*)d_in[9];
    float* out = (float*)d_out;

    char* ws = (char*)d_ws;
    float* X1     = (float*)(ws);                                  // 16 MB (fallbacks)
    float* X2     = (float*)(ws + 16777216);                       // 16 MB
    float* Wcat   = (float*)(ws + 33554432);
    float* bx     = (float*)(ws + 35848192);
    float* sc     = (float*)(ws + 35913728);
    int*   label  = (int*)  (ws + 35930112);
    int*   valid  = (int*)  (ws + 35946496);
    u16*   W6h    = (u16*)  (ws + 35979264);                       // 24.5 MB
    u16*   W6l    = (u16*)  (ws + 61669376);                       // 24.5 MB
    u16*   W7h    = (u16*)  (ws + 87359488);                       // 2 MB
    u16*   W7l    = (u16*)  (ws + 89456640);                       // 2 MB
    float* Cpart  = (float*)(ws + 91553792);                       // 64 MB
    u16*   A6h    = (u16*)  (ws + 158662656);                      // 98 MB (tiled)
    u16*   A6l    = (u16*)  (ws + 261423104);                      // 98 MB
    u16*   X1h    = (u16*)  (ws + 364183552);                      // 8 MB (tiled)
    u16*   X1l    = (u16*)  (ws + 372572160);                      // 8 MB
    const size_t NEED_SK   = 158662656ull;
    const size_t NEED_FULL = 380960768ull;

    if (ws_size >= NEED_FULL) {
        // ---- fast path: fc6 split into two M-half dispatches (instrumentation) ----
        prep_kernel<<<NB_PREP, 256, 0, stream>>>(
            fc6_w, fc7_w, cls_w, box_w, props_feature,
            W6h, W6l, W7h, W7l, Wcat, A6h, A6l);
        gemm_2ph_tiled<<<dim3(8, 16, 4), 256, 0, stream>>>(
            A6h, A6l, W6h, W6l, nullptr, Cpart, NPB, HID, FEAT_DIM / 32, FEAT_DIM / 128,
            0, 1, 4);
        gemm_2ph_tiled<<<dim3(8, 16, 4), 256, 0, stream>>>(
            A6h, A6l, W6h, W6l, nullptr, Cpart, NPB, HID, FEAT_DIM / 32, FEAT_DIM / 128,
            16, 1, 4);
        reduce_split_tiled<<<1024, 256, 0, stream>>>(
            Cpart, fc6_b, X1h, X1l, NPB * HID, HID);
        gemm_2ph_tiled<<<dim3(8, 32, 1), 256, 0, stream>>>(
            X1h, X1l, W7h, W7l, fc7_b, X2, NPB, HID, HID / 32, HID / 32,
            0, 3, 5);
    } else if (ws_size >= NEED_SK) {
        build_wcat<<<(HID * NCOL + 255) / 256, 256, 0, stream>>>(cls_w, box_w, Wcat);
        transpose_split<<<dim3(HID / 32, FEAT_DIM / 32), 256, 0, stream>>>(
            fc6_w, W6h, W6l, FEAT_DIM, HID);
        transpose_split<<<dim3(HID / 32, HID / 32), 256, 0, stream>>>(
            fc7_w, W7h, W7l, HID, HID);
        gemm_2ph<<<dim3(8, 32, 4), 256, 0, stream>>>(
            props_feature, W6h, W6l, nullptr, Cpart, NPB, HID, FEAT_DIM, FEAT_DIM / 4);
        reduce_bias_relu<<<1024, 256, 0, stream>>>(Cpart, fc6_b, X1, NPB * HID, HID);
        gemm_2ph<<<dim3(8, 32, 1), 256, 0, stream>>>(
            X1, W7h, W7l, fc7_b, X2, NPB, HID, HID, HID);
    } else {
        build_wcat<<<(HID * NCOL + 255) / 256, 256, 0, stream>>>(cls_w, box_w, Wcat);
        transpose_split<<<dim3(HID / 32, FEAT_DIM / 32), 256, 0, stream>>>(
            fc6_w, W6h, W6l, FEAT_DIM, HID);
        transpose_split<<<dim3(HID / 32, HID / 32), 256, 0, stream>>>(
            fc7_w, W7h, W7l, HID, HID);
        gemm_2ph<<<dim3(8, 32, 1), 256, 0, stream>>>(
            props_feature, W6h, W6l, fc6_b, X1, NPB, HID, FEAT_DIM, FEAT_DIM);
        gemm_2ph<<<dim3(8, 32, 1), 256, 0, stream>>>(
            X1, W7h, W7l, fc7_b, X2, NPB, HID, HID, HID);
    }

    heads_postproc<<<NPB / 16, 256, 0, stream>>>(
        X2, Wcat, cls_b, box_b, proposals, bx, sc, label, valid);

    nms_finalize<<<BATCH, 1024, 0, stream>>>(bx, sc, label, valid, proposals, out);
}

// Round 15
// 681.698 us; speedup vs baseline: 1.0890x; 1.0890x over previous
//
#include <hip/hip_runtime.h>
#include <hip/hip_bf16.h>

// Problem constants (from reference)
#define BATCH 4
#define NPROP 1024
#define HID 1024
#define NUM_CLASSES 21
#define FEAT_DIM 12544
#define NPB (BATCH * NPROP)             // 4096
#define IMG 800.0f
#define SCORE_THRESH 0.1f
#define NMS_THRESH 0.5f
#define NCOL 112                        // padded 21+84

typedef unsigned short u16;
typedef unsigned int u32;
typedef unsigned long long u64;
typedef short s16x8 __attribute__((ext_vector_type(8)));
typedef float f32x4 __attribute__((ext_vector_type(4)));

// hi/lo split of 2 floats via native RTNE bf16 converts (v_cvt_pk_bf16_f32).
__device__ __forceinline__ void split2(float x0, float x1, u32& hp, u32& lp) {
    __hip_bfloat162 h2 = __float22bfloat162_rn(make_float2(x0, x1));
    u32 h = *(u32*)&h2;
    float f0 = __uint_as_float(h << 16);
    float f1 = __uint_as_float(h & 0xffff0000u);
    __hip_bfloat162 l2 = __float22bfloat162_rn(make_float2(x0 - f0, x1 - f1));
    hp = h;
    lp = *(u32*)&l2;
}

// Tiled layout (LDS-image order, swizzle baked in):
//   T[blk][t][c(8)][lane(64)][8 u16], flat u16 off = ((blk*NTt + t)*8 + c)*512 + lane*8
__device__ __forceinline__ size_t tile_off(int blk, int NTt, int t, int row, int g) {
    int r = row & 127;
    int c = r >> 4;
    int lanei = ((r & 15) << 2) | (g ^ ((r >> 1) & 3));
    return ((((size_t)blk * NTt + t) * 8 + c) << 9) + lanei * 8;
}

// ============ fused prep kernel (all global R/W full-line coalesced) ============
#define NB_WCAT 448
#define NB_T7C  256          // 8 nb x 32 t
#define NB_T6C  3136         // 8 nb x 392 t
#define NB_SPA  2048
#define NB_PREP (NB_WCAT + NB_T7C + NB_T6C + NB_SPA)

// one block per (nb, t): stage W[t*32..+32][nb*128..+128] via LDS, emit 8 chunks
__device__ __forceinline__ void w_chunks(
    const float* __restrict__ W, u16* __restrict__ Th, u16* __restrict__ Tl,
    int NTt, int nb, int t, int tid, float (*lt)[129])
{
    const int n0 = nb * 128;
#pragma unroll
    for (int p = 0; p < 4; ++p) {
        int e = (p * 256 + tid) * 4;            // 0..4095 step 4
        int k = e >> 7;                          // tile row (k) 0..31
        int n = e & 127;                         // tile col (n)
        float4 v = *(const float4*)(W + (size_t)(t * 32 + k) * 1024 + n0 + n);
        lt[k][n] = v.x; lt[k][n + 1] = v.y; lt[k][n + 2] = v.z; lt[k][n + 3] = v.w;
    }
    __syncthreads();
    const int lane = tid & 63, w = tid >> 6;
#pragma unroll
    for (int i = 0; i < 2; ++i) {
        const int c = w * 2 + i;
        const int rl = c * 16 + (lane >> 2);            // local row (n) 0..127
        const int q = (lane & 3) ^ ((rl >> 1) & 3);     // content k-group
        u32 hp[4], lp[4];
#pragma unroll
        for (int e2 = 0; e2 < 4; ++e2)
            split2(lt[q * 8 + 2 * e2][rl], lt[q * 8 + 2 * e2 + 1][rl], hp[e2], lp[e2]);
        const size_t dsto = ((((size_t)nb * NTt + t) * 8 + c) << 9) + lane * 8;
        *(uint4*)&Th[dsto] = make_uint4(hp[0], hp[1], hp[2], hp[3]);
        *(uint4*)&Tl[dsto] = make_uint4(lp[0], lp[1], lp[2], lp[3]);
    }
    __syncthreads();
}

__global__ __launch_bounds__(256) void prep_kernel(
    const float* __restrict__ fc6_w, const float* __restrict__ fc7_w,
    const float* __restrict__ cls_w, const float* __restrict__ box_w,
    const float* __restrict__ A,
    u16* __restrict__ W6h, u16* __restrict__ W6l,
    u16* __restrict__ W7h, u16* __restrict__ W7l,
    float* __restrict__ Wcat, u16* __restrict__ A6h, u16* __restrict__ A6l)
{
    __shared__ float lt[32][129];
    const int b = blockIdx.x;
    const int tid = threadIdx.x;

    if (b < NB_WCAT) {
        int i = b * 256 + tid;
        if (i < HID * NCOL) {
            int k = i / NCOL, c = i % NCOL;
            float v = 0.0f;
            if (c < 21) v = cls_w[k * 21 + c];
            else if (c < 105) v = box_w[k * 84 + (c - 21)];
            Wcat[i] = v;
        }
    } else if (b < NB_WCAT + NB_T7C) {
        int idx = b - NB_WCAT;                  // 8 nb x 32 t
        w_chunks(fc7_w, W7h, W7l, 32, idx / 32, idx % 32, tid, lt);
    } else if (b < NB_WCAT + NB_T7C + NB_T6C) {
        int idx = b - NB_WCAT - NB_T7C;         // 8 nb x 392 t
        w_chunks(fc6_w, W6h, W6l, 392, idx / 392, idx % 392, tid, lt);
    } else {
        // A chunk-gather: wave builds one 1KB chunk (reads permuted full lines)
        const int sb = b - NB_WCAT - NB_T7C - NB_T6C;   // 0..2047
        const int lane = tid & 63;
        const int w = tid >> 6;
        const int NCH = (NPB / 128) * (FEAT_DIM / 32) * 8;   // 100352
        for (int ch = sb * 4 + w; ch < NCH; ch += NB_SPA * 4) {
            const int c = ch & 7;
            const int tmp = ch >> 3;
            const int t = tmp % (FEAT_DIM / 32);
            const int blk = tmp / (FEAT_DIM / 32);
            const int r = blk * 128 + c * 16 + (lane >> 2);
            const int col = t * 32 + (((lane & 3) ^ ((r >> 1) & 3)) << 3);
            const float* src = A + (size_t)r * FEAT_DIM + col;
            float4 v0 = *(const float4*)(src);
            float4 v1 = *(const float4*)(src + 4);
            u32 hp[4], lp[4];
            split2(v0.x, v0.y, hp[0], lp[0]);
            split2(v0.z, v0.w, hp[1], lp[1]);
            split2(v1.x, v1.y, hp[2], lp[2]);
            split2(v1.z, v1.w, hp[3], lp[3]);
            const size_t dsto = ((size_t)ch << 9) + lane * 8;
            *(uint4*)&A6h[dsto] = make_uint4(hp[0], hp[1], hp[2], hp[3]);
            *(uint4*)&A6l[dsto] = make_uint4(lp[0], lp[1], lp[2], lp[3]);
        }
    }
}

// ============ linear transpose+split (fallback paths) ============
__global__ __launch_bounds__(256) void transpose_split(
    const float* __restrict__ W, u16* __restrict__ WhT, u16* __restrict__ WlT,
    int K, int N)
{
    __shared__ float tile[32][33];
    const int tid = threadIdx.x;
    const int n0 = blockIdx.x * 32;
    const int k0 = blockIdx.y * 32;
    {
        int i = tid >> 3, j4 = (tid & 7) * 4;
        float4 v = *(const float4*)(W + (size_t)(k0 + i) * N + n0 + j4);
        tile[i][j4] = v.x; tile[i][j4 + 1] = v.y; tile[i][j4 + 2] = v.z; tile[i][j4 + 3] = v.w;
    }
    __syncthreads();
    {
        int i = tid >> 3, j4 = (tid & 7) * 4;
        u32 hp0, lp0, hp1, lp1;
        split2(tile[j4 + 0][i], tile[j4 + 1][i], hp0, lp0);
        split2(tile[j4 + 2][i], tile[j4 + 3][i], hp1, lp1);
        size_t o = (size_t)(n0 + i) * K + k0 + j4;
        *(uint2*)&WhT[o] = make_uint2(hp0, hp1);
        *(uint2*)&WlT[o] = make_uint2(lp0, lp1);
    }
}

// ============ concat cls_w | box_w (fallback paths) ============
__global__ void build_wcat(const float* __restrict__ cls_w, const float* __restrict__ box_w,
                           float* __restrict__ Wcat)
{
    int i = blockIdx.x * 256 + threadIdx.x;
    if (i >= HID * NCOL) return;
    int k = i / NCOL, c = i % NCOL;
    float v = 0.0f;
    if (c < 21) v = cls_w[k * 21 + c];
    else if (c < 105) v = box_w[k * 84 + (c - 21)];
    Wcat[i] = v;
}

// ============ tiled 2-phase GEMM: pure contiguous global_load_lds staging ========
// Generalized swizzle: mb = mb0 + xcd*(ymask+1) + yy, bz = j>>bzshift.
__global__ __launch_bounds__(256) void gemm_2ph_tiled(
    const u16* __restrict__ Ah, const u16* __restrict__ Al,
    const u16* __restrict__ Wh, const u16* __restrict__ Wl,
    const float* __restrict__ bias, float* __restrict__ Cout,
    int M, int Nn, int NTt, int tN, int mb0, int ymask, int bzshift)
{
    __shared__ u16 sm[2 * 16384];

    const int tid = threadIdx.x;
    const int lane = tid & 63;
    const int wv = tid >> 6;
    const int wr = wv >> 1, wc = wv & 1;

    const int flat = blockIdx.x + (blockIdx.y << 3) + blockIdx.z * 8 * gridDim.y;
    const int xcd = flat & 7;
    const int j = flat >> 3;
    const int bxi = j & 7;
    const int yy = (j >> 3) & ymask;
    const int bz = j >> bzshift;
    const int mb = mb0 + xcd * (ymask + 1) + yy;
    const int nb = bxi;
    const int bm = mb * 128, bn = nb * 128;
    const int t0 = bz * tN;

    const size_t abase = (size_t)mb * NTt * 4096;
    const size_t wbase = (size_t)nb * NTt * 4096;

    const int fr = lane & 15, fq = lane >> 4;
    int ia[4], ib[4];
#pragma unroll
    for (int m = 0; m < 4; ++m) {
        int ra = wr * 64 + m * 16 + fr;
        ia[m] = ra * 32 + ((fq ^ ((ra >> 1) & 3)) << 3);
        int rb = wc * 64 + m * 16 + fr;
        ib[m] = rb * 32 + ((fq ^ ((rb >> 1) & 3)) << 3);
    }

    f32x4 acc[4][4];
#pragma unroll
    for (int m = 0; m < 4; ++m)
#pragma unroll
        for (int n = 0; n < 4; ++n)
            acc[m][n] = (f32x4){0.f, 0.f, 0.f, 0.f};

    auto stage = [&](u16* dst, int t) {
#pragma unroll
        for (int i = 0; i < 2; ++i) {
            const int c = wv * 2 + i;
            const size_t so = (((size_t)t * 8 + c) << 9) + lane * 8;
            __builtin_amdgcn_global_load_lds(
                (const __attribute__((address_space(1))) u32*)(Ah + abase + so),
                (__attribute__((address_space(3))) u32*)(dst + c * 512), 16, 0, 0);
            __builtin_amdgcn_global_load_lds(
                (const __attribute__((address_space(1))) u32*)(Al + abase + so),
                (__attribute__((address_space(3))) u32*)(dst + 4096 + c * 512), 16, 0, 0);
            __builtin_amdgcn_global_load_lds(
                (const __attribute__((address_space(1))) u32*)(Wh + wbase + so),
                (__attribute__((address_space(3))) u32*)(dst + 8192 + c * 512), 16, 0, 0);
            __builtin_amdgcn_global_load_lds(
                (const __attribute__((address_space(1))) u32*)(Wl + wbase + so),
                (__attribute__((address_space(3))) u32*)(dst + 12288 + c * 512), 16, 0, 0);
        }
    };

    auto compute = [&](const u16* src) {
        s16x8 fah[4], fal[4], fbh[4], fbl[4];
#pragma unroll
        for (int m = 0; m < 4; ++m) {
            fah[m] = *(const s16x8*)&src[ia[m]];
            fal[m] = *(const s16x8*)&src[4096 + ia[m]];
            fbh[m] = *(const s16x8*)&src[8192 + ib[m]];
            fbl[m] = *(const s16x8*)&src[12288 + ib[m]];
        }
        __builtin_amdgcn_s_setprio(1);
#pragma unroll
        for (int m = 0; m < 4; ++m)
#pragma unroll
            for (int n = 0; n < 4; ++n) {
                acc[m][n] = __builtin_amdgcn_mfma_f32_16x16x32_bf16(fah[m], fbh[n], acc[m][n], 0, 0, 0);
                acc[m][n] = __builtin_amdgcn_mfma_f32_16x16x32_bf16(fah[m], fbl[n], acc[m][n], 0, 0, 0);
                acc[m][n] = __builtin_amdgcn_mfma_f32_16x16x32_bf16(fal[m], fbh[n], acc[m][n], 0, 0, 0);
            }
        __builtin_amdgcn_s_setprio(0);
    };

    u16* bufc = sm;
    u16* bufn = sm + 16384;

    stage(bufc, t0);
    for (int t = 0; t < tN; ++t) {
        if (t + 1 < tN) {
            stage(bufn, t0 + t + 1);
            asm volatile("s_waitcnt vmcnt(8)" ::: "memory");
        } else {
            asm volatile("s_waitcnt vmcnt(0)" ::: "memory");
        }
        asm volatile("s_barrier" ::: "memory");
        compute(bufc);
        asm volatile("s_barrier" ::: "memory");
        u16* tmp = bufc; bufc = bufn; bufn = tmp;
    }

    if (bias != nullptr) {
#pragma unroll
        for (int n = 0; n < 4; ++n) {
            int col = bn + wc * 64 + n * 16 + fr;
            float bb = bias[col];
#pragma unroll
            for (int m = 0; m < 4; ++m) {
                int row0 = bm + wr * 64 + m * 16 + fq * 4;
#pragma unroll
                for (int jj = 0; jj < 4; ++jj)
                    Cout[(size_t)(row0 + jj) * Nn + col] = fmaxf(acc[m][n][jj] + bb, 0.0f);
            }
        }
    } else {
        float* Cp = Cout + (size_t)bz * M * Nn;
#pragma unroll
        for (int n = 0; n < 4; ++n) {
            int col = bn + wc * 64 + n * 16 + fr;
#pragma unroll
            for (int m = 0; m < 4; ++m) {
                int row0 = bm + wr * 64 + m * 16 + fq * 4;
#pragma unroll
                for (int jj = 0; jj < 4; ++jj)
                    Cp[(size_t)(row0 + jj) * Nn + col] = acc[m][n][jj];
            }
        }
    }
}

// ============ round-7 2-phase GEMM (in-loop A split) — fallback ============
__global__ __launch_bounds__(256) void gemm_2ph(
    const float* __restrict__ A, const u16* __restrict__ WhT, const u16* __restrict__ WlT,
    const float* __restrict__ bias, float* __restrict__ Cout,
    int M, int Nn, int K, int KC)
{
    __shared__ u16 sm[2 * 16384];

    const int tid = threadIdx.x;
    const int lane = tid & 63;
    const int wv = tid >> 6;
    const int wr = wv >> 1, wc = wv & 1;

    const int flat = blockIdx.x + (blockIdx.y << 3) + (blockIdx.z << 8);
    const int xcd = flat & 7;
    const int j = flat >> 3;
    const int bxi = j & 7;
    const int yy = (j >> 3) & 3;
    const int bz = j >> 5;
    const int bm = (xcd * 4 + yy) * 128;
    const int bn = bxi * 128;
    const int k0 = bz * KC;
    const int NT = KC / 32;

    const int ar = tid >> 1;
    const int ah = tid & 1;
    const float* aPtr = A + (size_t)(bm + ar) * K + ah * 16;
    const int asw = (ar >> 1) & 3;
    const int ac0 = ((2 * ah) ^ asw) << 3;
    const int ac1 = ((2 * ah + 1) ^ asw) << 3;

    int wrow[2], wlc[2];
#pragma unroll
    for (int i = 0; i < 2; ++i) {
        int c = wv * 2 + i;
        wrow[i] = c * 16 + (lane >> 2);
        wlc[i] = ((lane & 3) ^ ((wrow[i] >> 1) & 3)) * 8;
    }

    const int fr = lane & 15, fq = lane >> 4;
    int ia[4], ib[4];
#pragma unroll
    for (int m = 0; m < 4; ++m) {
        int ra = wr * 64 + m * 16 + fr;
        ia[m] = ra * 32 + ((fq ^ ((ra >> 1) & 3)) << 3);
        int rb = wc * 64 + m * 16 + fr;
        ib[m] = rb * 32 + ((fq ^ ((rb >> 1) & 3)) << 3);
    }

    f32x4 acc[4][4];
#pragma unroll
    for (int m = 0; m < 4; ++m)
#pragma unroll
        for (int n = 0; n < 4; ++n)
            acc[m][n] = (f32x4){0.f, 0.f, 0.f, 0.f};

    auto stage_w = [&](u16* dst, int kk) {
#pragma unroll
        for (int i = 0; i < 2; ++i) {
            const int c = wv * 2 + i;
            const u16* gh = WhT + (size_t)(bn + wrow[i]) * K + kk + wlc[i];
            const u16* gl = WlT + (size_t)(bn + wrow[i]) * K + kk + wlc[i];
            __builtin_amdgcn_global_load_lds(
                (const __attribute__((address_space(1))) u32*)gh,
                (__attribute__((address_space(3))) u32*)(dst + 8192 + c * 512), 16, 0, 0);
            __builtin_amdgcn_global_load_lds(
                (const __attribute__((address_space(1))) u32*)gl,
                (__attribute__((address_space(3))) u32*)(dst + 12288 + c * 512), 16, 0, 0);
        }
    };

    auto split_a = [&](u16* dst, float4 v0, float4 v1, float4 v2, float4 v3) {
        u32 hp[8], lp[8];
        split2(v0.x, v0.y, hp[0], lp[0]);
        split2(v0.z, v0.w, hp[1], lp[1]);
        split2(v1.x, v1.y, hp[2], lp[2]);
        split2(v1.z, v1.w, hp[3], lp[3]);
        split2(v2.x, v2.y, hp[4], lp[4]);
        split2(v2.z, v2.w, hp[5], lp[5]);
        split2(v3.x, v3.y, hp[6], lp[6]);
        split2(v3.z, v3.w, hp[7], lp[7]);
        *(uint4*)&dst[ar * 32 + ac0] = make_uint4(hp[0], hp[1], hp[2], hp[3]);
        *(uint4*)&dst[ar * 32 + ac1] = make_uint4(hp[4], hp[5], hp[6], hp[7]);
        *(uint4*)&dst[4096 + ar * 32 + ac0] = make_uint4(lp[0], lp[1], lp[2], lp[3]);
        *(uint4*)&dst[4096 + ar * 32 + ac1] = make_uint4(lp[4], lp[5], lp[6], lp[7]);
    };

    auto compute = [&](const u16* src) {
        s16x8 fah[4], fal[4], fbh[4], fbl[4];
#pragma unroll
        for (int m = 0; m < 4; ++m) {
            fah[m] = *(const s16x8*)&src[ia[m]];
            fal[m] = *(const s16x8*)&src[4096 + ia[m]];
            fbh[m] = *(const s16x8*)&src[8192 + ib[m]];
            fbl[m] = *(const s16x8*)&src[12288 + ib[m]];
        }
        __builtin_amdgcn_s_setprio(1);
#pragma unroll
        for (int m = 0; m < 4; ++m)
#pragma unroll
            for (int n = 0; n < 4; ++n) {
                acc[m][n] = __builtin_amdgcn_mfma_f32_16x16x32_bf16(fah[m], fbh[n], acc[m][n], 0, 0, 0);
                acc[m][n] = __builtin_amdgcn_mfma_f32_16x16x32_bf16(fah[m], fbl[n], acc[m][n], 0, 0, 0);
                acc[m][n] = __builtin_amdgcn_mfma_f32_16x16x32_bf16(fal[m], fbh[n], acc[m][n], 0, 0, 0);
            }
        __builtin_amdgcn_s_setprio(0);
    };

    u16* bufc = sm;
    u16* bufn = sm + 16384;

    stage_w(bufc, k0);
    {
        float4 a0 = *(const float4*)(aPtr + k0 + 0);
        float4 a1 = *(const float4*)(aPtr + k0 + 4);
        float4 a2 = *(const float4*)(aPtr + k0 + 8);
        float4 a3 = *(const float4*)(aPtr + k0 + 12);
        split_a(bufc, a0, a1, a2, a3);
    }
    asm volatile("s_waitcnt vmcnt(0) lgkmcnt(0)\n\ts_barrier" ::: "memory");

    for (int t = 0; t < NT; ++t) {
        float4 a0{}, a1{}, a2{}, a3{};
        const bool hn = (t + 1 < NT);
        if (hn) {
            const int kk = k0 + (t + 1) * 32;
            stage_w(bufn, kk);
            a0 = *(const float4*)(aPtr + kk + 0);
            a1 = *(const float4*)(aPtr + kk + 4);
            a2 = *(const float4*)(aPtr + kk + 8);
            a3 = *(const float4*)(aPtr + kk + 12);
        }
        compute(bufc);
        if (hn) split_a(bufn, a0, a1, a2, a3);
        asm volatile("s_waitcnt vmcnt(0) lgkmcnt(0)\n\ts_barrier" ::: "memory");
        u16* tmp = bufc; bufc = bufn; bufn = tmp;
    }

    if (bias != nullptr) {
#pragma unroll
        for (int n = 0; n < 4; ++n) {
            int col = bn + wc * 64 + n * 16 + fr;
            float bb = bias[col];
#pragma unroll
            for (int m = 0; m < 4; ++m) {
                int row0 = bm + wr * 64 + m * 16 + fq * 4;
#pragma unroll
                for (int jj = 0; jj < 4; ++jj)
                    Cout[(size_t)(row0 + jj) * Nn + col] = fmaxf(acc[m][n][jj] + bb, 0.0f);
            }
        }
    } else {
        float* Cp = Cout + (size_t)bz * M * Nn;
#pragma unroll
        for (int n = 0; n < 4; ++n) {
            int col = bn + wc * 64 + n * 16 + fr;
#pragma unroll
            for (int m = 0; m < 4; ++m) {
                int row0 = bm + wr * 64 + m * 16 + fq * 4;
#pragma unroll
                for (int jj = 0; jj < 4; ++jj)
                    Cp[(size_t)(row0 + jj) * Nn + col] = acc[m][n][jj];
            }
        }
    }
}

// ============ reduce 4 partials + bias + relu (fp32 out, fallback) ============
__global__ __launch_bounds__(256) void reduce_bias_relu(
    const float* __restrict__ Cpart, const float* __restrict__ bias,
    float* __restrict__ X, int MN, int Nn)
{
    const int total = MN / 4;
    for (int i4 = blockIdx.x * 256 + threadIdx.x; i4 < total; i4 += gridDim.x * 256) {
        const size_t o = (size_t)i4 * 4;
        float4 a = *(const float4*)(Cpart + o);
        float4 b = *(const float4*)(Cpart + (size_t)MN + o);
        float4 c = *(const float4*)(Cpart + 2 * (size_t)MN + o);
        float4 d = *(const float4*)(Cpart + 3 * (size_t)MN + o);
        float4 bb = *(const float4*)(bias + (o & (size_t)(Nn - 1)));
        float4 r;
        r.x = fmaxf(a.x + b.x + c.x + d.x + bb.x, 0.0f);
        r.y = fmaxf(a.y + b.y + c.y + d.y + bb.y, 0.0f);
        r.z = fmaxf(a.z + b.z + c.z + d.z + bb.z, 0.0f);
        r.w = fmaxf(a.w + b.w + c.w + d.w + bb.w, 0.0f);
        *(float4*)(X + o) = r;
    }
}

// ============ reduce 4 partials + bias + relu, emit tiled split bf16 ============
__global__ __launch_bounds__(256) void reduce_split_tiled(
    const float* __restrict__ Cpart, const float* __restrict__ bias,
    u16* __restrict__ Xh, u16* __restrict__ Xl, int MN, int Nn)
{
    const int total = MN / 8;
    for (int i = blockIdx.x * 256 + threadIdx.x; i < total; i += gridDim.x * 256) {
        const size_t o = (size_t)i * 8;
        float r8[8];
#pragma unroll
        for (int h = 0; h < 2; ++h) {
            float4 a = *(const float4*)(Cpart + o + h * 4);
            float4 b = *(const float4*)(Cpart + (size_t)MN + o + h * 4);
            float4 c = *(const float4*)(Cpart + 2 * (size_t)MN + o + h * 4);
            float4 d = *(const float4*)(Cpart + 3 * (size_t)MN + o + h * 4);
            float4 bb = *(const float4*)(bias + ((o + h * 4) & (size_t)(Nn - 1)));
            r8[h * 4 + 0] = fmaxf(a.x + b.x + c.x + d.x + bb.x, 0.0f);
            r8[h * 4 + 1] = fmaxf(a.y + b.y + c.y + d.y + bb.y, 0.0f);
            r8[h * 4 + 2] = fmaxf(a.z + b.z + c.z + d.z + bb.z, 0.0f);
            r8[h * 4 + 3] = fmaxf(a.w + b.w + c.w + d.w + bb.w, 0.0f);
        }
        u32 hp[4], lp[4];
#pragma unroll
        for (int t2 = 0; t2 < 4; ++t2)
            split2(r8[2 * t2], r8[2 * t2 + 1], hp[t2], lp[t2]);
        int row = (int)(o >> 10);                 // Nn == 1024
        int rem = (int)(o & 1023);
        int t = rem >> 5, g = (rem >> 3) & 3;
        size_t dsto = tile_off(row >> 7, 32, t, row, g);
        *(uint4*)&Xh[dsto] = make_uint4(hp[0], hp[1], hp[2], hp[3]);
        *(uint4*)&Xl[dsto] = make_uint4(lp[0], lp[1], lp[2], lp[3]);
    }
}

// ============ fused heads GEMM + postproc (16 rows/block, fp32 exact) ========
__global__ __launch_bounds__(256) void heads_postproc(
    const float* __restrict__ X2, const float* __restrict__ Wcat,
    const float* __restrict__ cls_b, const float* __restrict__ box_b,
    const float* __restrict__ proposals,
    float* __restrict__ bxo, float* __restrict__ sco,
    int* __restrict__ lbo, int* __restrict__ vdo)
{
    __shared__ float Xs[16][36];
    __shared__ float Ws[32 * NCOL];
    __shared__ float lgs[16][NCOL];
    const int tid = threadIdx.x;
    const int m0 = blockIdx.x * 16;
    const int tr = tid >> 4;            // 16 rows
    const int tc = tid & 15;            // 16 col-groups x 7
    float acc[7] = {};
    for (int k0 = 0; k0 < HID; k0 += 32) {
        if (tid < 128) {
            int i = tid >> 3, j4 = (tid & 7) * 4;
            float4 v = *(const float4*)(X2 + (size_t)(m0 + i) * HID + k0 + j4);
            Xs[i][j4] = v.x; Xs[i][j4 + 1] = v.y; Xs[i][j4 + 2] = v.z; Xs[i][j4 + 3] = v.w;
        }
        const float4* src = (const float4*)(Wcat + (size_t)k0 * NCOL);
        float4* dst = (float4*)Ws;
        for (int i4 = tid; i4 < (32 * NCOL) / 4; i4 += 256) dst[i4] = src[i4];
        __syncthreads();
#pragma unroll 4
        for (int kk = 0; kk < 32; ++kk) {
            float a0 = Xs[tr][kk];
#pragma unroll
            for (int j = 0; j < 7; ++j)
                acc[j] = fmaf(a0, Ws[kk * NCOL + tc * 7 + j], acc[j]);
        }
        __syncthreads();
    }
#pragma unroll
    for (int j = 0; j < 7; ++j)
        lgs[tr][tc * 7 + j] = acc[j];
    __syncthreads();

    if (tid < 16) {
        const int p = m0 + tid;
        const float* lg = lgs[tid];
        float l[21];
        float m = -1e30f;
#pragma unroll
        for (int c = 0; c < 21; ++c) { l[c] = lg[c] + cls_b[c]; m = fmaxf(m, l[c]); }
        float e[21]; float s = 0.0f;
#pragma unroll
        for (int c = 0; c < 21; ++c) { e[c] = expf(l[c] - m); s += e[c]; }
        int best = 1;
#pragma unroll
        for (int c = 2; c < 21; ++c) if (e[c] > e[best]) best = c;
        const float score = e[best] / s;

        float d0 = (lg[21 + best * 4 + 0] + box_b[best * 4 + 0]) * 0.1f;
        float d1 = (lg[21 + best * 4 + 1] + box_b[best * 4 + 1]) * 0.1f;
        float d2 = (lg[21 + best * 4 + 2] + box_b[best * 4 + 2]) * 0.2f;
        float d3 = (lg[21 + best * 4 + 3] + box_b[best * 4 + 3]) * 0.2f;
        const float* pr = proposals + p * 4;
        float w_ = pr[2] - pr[0], h_ = pr[3] - pr[1];
        float cx = pr[0] + 0.5f * w_, cy = pr[1] + 0.5f * h_;
        float pcx = d0 * w_ + cx, pcy = d1 * h_ + cy;
        float pw = expf(d2) * w_, ph = expf(d3) * h_;
        float b0 = pcx - 0.5f * pw, b1 = pcy - 0.5f * ph;
        float b2 = pcx + 0.5f * pw, b3 = pcy + 0.5f * ph;
        b0 = fminf(fmaxf(b0, 0.0f), IMG);
        b1 = fminf(fmaxf(b1, 0.0f), IMG);
        b2 = fminf(fmaxf(b2, 0.0f), IMG);
        b3 = fminf(fmaxf(b3, 0.0f), IMG);
        int vd = (b2 - b0 > 0.0f) && (b3 - b1 > 0.0f) && (score > SCORE_THRESH);
        bxo[p * 4 + 0] = b0; bxo[p * 4 + 1] = b1;
        bxo[p * 4 + 2] = b2; bxo[p * 4 + 3] = b3;
        sco[p] = score;
        lbo[p] = best;
        vdo[p] = vd;
    }
}

// ============ fused NMS + finalize: ballot mask build + pipelined scan ============
__global__ __launch_bounds__(1024) void nms_finalize(
    const float* __restrict__ bx, const float* __restrict__ sc,
    const int* __restrict__ label, const int* __restrict__ valid,
    const float* __restrict__ proposals, float* __restrict__ out)
{
    const int img = blockIdx.x;
    const int base = img * NPROP;
    const int tid = threadIdx.x;
    const int lane = tid & 63;
    const int wv = tid >> 6;                // 16 waves

    __shared__ u64 maskm[NPROP][16];        // 128 KB (aliases sort keys)
    __shared__ float4 sbx[NPROP];           // 16 KB
    __shared__ float sarea[NPROP];          // 4 KB
    __shared__ u64 kword[16];
    __shared__ int nv;

    u64* skey = &maskm[0][0];               // alias (dead before mask build)

    if (tid == 0) nv = 0;

    // key: ascending <=> (score desc, index asc) — stable argsort(-sc)
    {
        float s = valid[base + tid] ? sc[base + tid] : -1.0f;
        unsigned u = __float_as_uint(s);
        u = (u & 0x80000000u) ? ~u : (u | 0x80000000u);
        u = ~u;
        skey[tid] = ((u64)u << 32) | (unsigned)tid;
    }
    for (int k = 2; k <= NPROP; k <<= 1) {
        for (int j = k >> 1; j > 0; j >>= 1) {
            __syncthreads();
            int ixj = tid ^ j;
            if (ixj > tid) {
                u64 a = skey[tid], b = skey[ixj];
                bool up = ((tid & k) == 0);
                if (up ? (a > b) : (a < b)) { skey[tid] = b; skey[ixj] = a; }
            }
        }
    }
    __syncthreads();

    // sorted order; offset boxes (reference arithmetic); kword via per-wave ballot
    const int myp = (int)(skey[tid] & 0xffffffffu);
    {
        float off = (float)label[base + myp] * (IMG + 1.0f);
        float x0 = bx[(base + myp) * 4 + 0] + off;
        float y0 = bx[(base + myp) * 4 + 1] + off;
        float x1 = bx[(base + myp) * 4 + 2] + off;
        float y1 = bx[(base + myp) * 4 + 3] + off;
        sbx[tid] = make_float4(x0, y0, x1, y1);
        sarea[tid] = (x1 - x0) * (y1 - y0);
        int v = valid[base + myp];
        u64 bb = __ballot(v != 0);           // wave wv covers exactly word wv
        if (lane == 0) kword[wv] = bb;
        if (v) atomicMax(&nv, tid + 1);      // valids sort to the front
    }
    __syncthreads();
    const int nvalid = nv;

    // ballot mask build: wave owns row i; lane handles j = w*64 + lane.
    // sbx[j] reads are consecutive (conflict-free); one lane writes the word.
    for (int i = wv; i < nvalid; i += 16) {
        const float4 bi = sbx[i];
        const float ai = sarea[i];
#pragma unroll 4
        for (int w = 0; w < 16; ++w) {
            const int j = w * 64 + lane;
            bool sup = false;
            if (j > i && j < nvalid) {
                float4 bj = sbx[j];
                float lt0 = fmaxf(bi.x, bj.x);
                float lt1 = fmaxf(bi.y, bj.y);
                float rb0 = fminf(bi.z, bj.z);
                float rb1 = fminf(bi.w, bj.w);
                float w_ = fmaxf(rb0 - lt0, 0.0f);
                float h_ = fmaxf(rb1 - lt1, 0.0f);
                float inter = w_ * h_;
                float denom = fmaxf(ai + sarea[j] - inter, 1e-9f);
                sup = inter / denom > NMS_THRESH;
            }
            u64 bits = __ballot(sup);
            if (lane == 0) maskm[i][w] = bits;
        }
    }
    __syncthreads();

    // serial greedy scan — single wave, depth-4 row prefetch (named regs, rule #20)
    if (tid < 64) {
        u64 kw = (tid < 16) ? kword[tid] : 0ull;
        u64 ra = 0, rb = 0, rc = 0, rd = 0;
        if (tid < 16) {
            if (0 < nvalid) ra = maskm[0][tid];
            if (1 < nvalid) rb = maskm[1][tid];
            if (2 < nvalid) rc = maskm[2][tid];
            if (3 < nvalid) rd = maskm[3][tid];
        }
        for (int i = 0; i < nvalid; i += 4) {
            {
                u64 srcw = __shfl(kw, i >> 6, 64);
                if ((srcw >> (i & 63)) & 1ull) { if (tid < 16) kw &= ~ra; }
                if (tid < 16 && i + 4 < nvalid) ra = maskm[i + 4][tid];
            }
            if (i + 1 < nvalid) {
                u64 srcw = __shfl(kw, (i + 1) >> 6, 64);
                if ((srcw >> ((i + 1) & 63)) & 1ull) { if (tid < 16) kw &= ~rb; }
                if (tid < 16 && i + 5 < nvalid) rb = maskm[i + 5][tid];
            }
            if (i + 2 < nvalid) {
                u64 srcw = __shfl(kw, (i + 2) >> 6, 64);
                if ((srcw >> ((i + 2) & 63)) & 1ull) { if (tid < 16) kw &= ~rc; }
                if (tid < 16 && i + 6 < nvalid) rc = maskm[i + 6][tid];
            }
            if (i + 3 < nvalid) {
                u64 srcw = __shfl(kw, (i + 3) >> 6, 64);
                if ((srcw >> ((i + 3) & 63)) & 1ull) { if (tid < 16) kw &= ~rd; }
                if (tid < 16 && i + 7 < nvalid) rd = maskm[i + 7][tid];
            }
        }
        if (tid < 16) kword[tid] = kw;
    }
    __syncthreads();

    // fused finalize: thread tid owns original proposal (base + myp)
    {
        const int p = base + myp;
        const bool k = ((kword[tid >> 6] >> (tid & 63)) & 1ull) != 0;
        float* res   = out;
        float* keepo = out + NPB * 6;
        float* rpn   = keepo + NPB;
        float* rcnn  = rpn + NPB * 6;
        float b0 = bx[p * 4 + 0], b1 = bx[p * 4 + 1];
        float b2 = bx[p * 4 + 2], b3 = bx[p * 4 + 3];
        res[p * 6 + 0] = k ? b0 : 0.0f;
        res[p * 6 + 1] = k ? b1 : 0.0f;
        res[p * 6 + 2] = k ? b2 : 0.0f;
        res[p * 6 + 3] = k ? b3 : 0.0f;
        res[p * 6 + 4] = k ? (float)(label[p] - 1) : 0.0f;
        res[p * 6 + 5] = k ? sc[p] : 0.0f;
        keepo[p] = k ? 1.0f : 0.0f;
        rpn[p * 6 + 0] = proposals[p * 4 + 0];
        rpn[p * 6 + 1] = proposals[p * 4 + 1];
        rpn[p * 6 + 2] = proposals[p * 4 + 2];
        rpn[p * 6 + 3] = proposals[p * 4 + 3];
        rpn[p * 6 + 4] = 0.0f;
        rpn[p * 6 + 5] = 0.0f;
        rcnn[p * 6 + 0] = b0;
        rcnn[p * 6 + 1] = b1;
        rcnn[p * 6 + 2] = b2;
        rcnn[p * 6 + 3] = b3;
        rcnn[p * 6 + 4] = 0.0f;
        rcnn[p * 6 + 5] = 0.0f;
    }
}

// ============ launch ============
extern "C" void kernel_launch(void* const* d_in, const int* in_sizes, int n_in,
                              void* d_out, int out_size, void* d_ws, size_t ws_size,
                              hipStream_t stream)
{
    const float* props_feature = (const float*)d_in[0];
    const float* proposals     = (const float*)d_in[1];
    const float* fc6_w         = (const float*)d_in[2];
    const float* fc6_b         = (const float*)d_in[3];
    const float* fc7_w         = (const float*)d_in[4];
    const float* fc7_b         = (const float*)d_in[5];
    const float* cls_w         = (const float*)d_in[6];
    const float* cls_b         = (const float*)d_in[7];
    const float* box_w         = (const float*)d_in[8];
    const float* box_b         = (const float*)d_in[9];
    float* out = (float*)d_out;

    char* ws = (char*)d_ws;
    float* X1     = (float*)(ws);                                  // 16 MB (fallbacks)
    float* X2     = (float*)(ws + 16777216);                       // 16 MB
    float* Wcat   = (float*)(ws + 33554432);
    float* bx     = (float*)(ws + 35848192);
    float* sc     = (float*)(ws + 35913728);
    int*   label  = (int*)  (ws + 35930112);
    int*   valid  = (int*)  (ws + 35946496);
    u16*   W6h    = (u16*)  (ws + 35979264);                       // 24.5 MB
    u16*   W6l    = (u16*)  (ws + 61669376);                       // 24.5 MB
    u16*   W7h    = (u16*)  (ws + 87359488);                       // 2 MB
    u16*   W7l    = (u16*)  (ws + 89456640);                       // 2 MB
    float* Cpart  = (float*)(ws + 91553792);                       // 64 MB
    u16*   A6h    = (u16*)  (ws + 158662656);                      // 98 MB (tiled)
    u16*   A6l    = (u16*)  (ws + 261423104);                      // 98 MB
    u16*   X1h    = (u16*)  (ws + 364183552);                      // 8 MB (tiled)
    u16*   X1l    = (u16*)  (ws + 372572160);                      // 8 MB
    const size_t NEED_SK   = 158662656ull;
    const size_t NEED_FULL = 380960768ull;

    if (ws_size >= NEED_FULL) {
        // ---- fast path: fc6 split into two M-half dispatches (visibility) ----
        prep_kernel<<<NB_PREP, 256, 0, stream>>>(
            fc6_w, fc7_w, cls_w, box_w, props_feature,
            W6h, W6l, W7h, W7l, Wcat, A6h, A6l);
        gemm_2ph_tiled<<<dim3(8, 16, 4), 256, 0, stream>>>(
            A6h, A6l, W6h, W6l, nullptr, Cpart, NPB, HID, FEAT_DIM / 32, FEAT_DIM / 128,
            0, 1, 4);
        gemm_2ph_tiled<<<dim3(8, 16, 4), 256, 0, stream>>>(
            A6h, A6l, W6h, W6l, nullptr, Cpart, NPB, HID, FEAT_DIM / 32, FEAT_DIM / 128,
            16, 1, 4);
        reduce_split_tiled<<<1024, 256, 0, stream>>>(
            Cpart, fc6_b, X1h, X1l, NPB * HID, HID);
        gemm_2ph_tiled<<<dim3(8, 32, 1), 256, 0, stream>>>(
            X1h, X1l, W7h, W7l, fc7_b, X2, NPB, HID, HID / 32, HID / 32,
            0, 3, 5);
    } else if (ws_size >= NEED_SK) {
        build_wcat<<<(HID * NCOL + 255) / 256, 256, 0, stream>>>(cls_w, box_w, Wcat);
        transpose_split<<<dim3(HID / 32, FEAT_DIM / 32), 256, 0, stream>>>(
            fc6_w, W6h, W6l, FEAT_DIM, HID);
        transpose_split<<<dim3(HID / 32, HID / 32), 256, 0, stream>>>(
            fc7_w, W7h, W7l, HID, HID);
        gemm_2ph<<<dim3(8, 32, 4), 256, 0, stream>>>(
            props_feature, W6h, W6l, nullptr, Cpart, NPB, HID, FEAT_DIM, FEAT_DIM / 4);
        reduce_bias_relu<<<1024, 256, 0, stream>>>(Cpart, fc6_b, X1, NPB * HID, HID);
        gemm_2ph<<<dim3(8, 32, 1), 256, 0, stream>>>(
            X1, W7h, W7l, fc7_b, X2, NPB, HID, HID, HID);
    } else {
        build_wcat<<<(HID * NCOL + 255) / 256, 256, 0, stream>>>(cls_w, box_w, Wcat);
        transpose_split<<<dim3(HID / 32, FEAT_DIM / 32), 256, 0, stream>>>(
            fc6_w, W6h, W6l, FEAT_DIM, HID);
        transpose_split<<<dim3(HID / 32, HID / 32), 256, 0, stream>>>(
            fc7_w, W7h, W7l, HID, HID);
        gemm_2ph<<<dim3(8, 32, 1), 256, 0, stream>>>(
            props_feature, W6h, W6l, fc6_b, X1, NPB, HID, FEAT_DIM, FEAT_DIM);
        gemm_2ph<<<dim3(8, 32, 1), 256, 0, stream>>>(
            X1, W7h, W7l, fc7_b, X2, NPB, HID, HID, HID);
    }

    heads_postproc<<<NPB / 16, 256, 0, stream>>>(
        X2, Wcat, cls_b, box_b, proposals, bx, sc, label, valid);

    nms_finalize<<<BATCH, 1024, 0, stream>>>(bx, sc, label, valid, proposals, out);
}

// Round 16
// 655.413 us; speedup vs baseline: 1.1327x; 1.0401x over previous
//
#include <hip/hip_runtime.h>
#include <hip/hip_bf16.h>

// Problem constants (from reference)
#define BATCH 4
#define NPROP 1024
#define HID 1024
#define NUM_CLASSES 21
#define FEAT_DIM 12544
#define NPB (BATCH * NPROP)             // 4096
#define IMG 800.0f
#define SCORE_THRESH 0.1f
#define NMS_THRESH 0.5f
#define NCOL 112                        // padded 21+84

typedef unsigned short u16;
typedef unsigned int u32;
typedef unsigned long long u64;
typedef short s16x8 __attribute__((ext_vector_type(8)));
typedef float f32x4 __attribute__((ext_vector_type(4)));

// hi/lo split of 2 floats via native RTNE bf16 converts (v_cvt_pk_bf16_f32).
__device__ __forceinline__ void split2(float x0, float x1, u32& hp, u32& lp) {
    __hip_bfloat162 h2 = __float22bfloat162_rn(make_float2(x0, x1));
    u32 h = *(u32*)&h2;
    float f0 = __uint_as_float(h << 16);
    float f1 = __uint_as_float(h & 0xffff0000u);
    __hip_bfloat162 l2 = __float22bfloat162_rn(make_float2(x0 - f0, x1 - f1));
    hp = h;
    lp = *(u32*)&l2;
}

// Tiled layout (LDS-image order, swizzle baked in):
//   T[blk][t][c(8)][lane(64)][8 u16], flat u16 off = ((blk*NTt + t)*8 + c)*512 + lane*8
__device__ __forceinline__ size_t tile_off(int blk, int NTt, int t, int row, int g) {
    int r = row & 127;
    int c = r >> 4;
    int lanei = ((r & 15) << 2) | (g ^ ((r >> 1) & 3));
    return ((((size_t)blk * NTt + t) * 8 + c) << 9) + lanei * 8;
}

// ============ fused prep kernel (all global R/W full-line coalesced) ============
#define NB_WCAT 448
#define NB_T7C  256          // 8 nb x 32 t
#define NB_T6C  3136         // 8 nb x 392 t
#define NB_SPA  2048
#define NB_PREP (NB_WCAT + NB_T7C + NB_T6C + NB_SPA)

// one block per (nb, t): stage W[t*32..+32][nb*128..+128] via LDS, emit 8 chunks
__device__ __forceinline__ void w_chunks(
    const float* __restrict__ W, u16* __restrict__ Th, u16* __restrict__ Tl,
    int NTt, int nb, int t, int tid, float (*lt)[129])
{
    const int n0 = nb * 128;
#pragma unroll
    for (int p = 0; p < 4; ++p) {
        int e = (p * 256 + tid) * 4;            // 0..4095 step 4
        int k = e >> 7;                          // tile row (k) 0..31
        int n = e & 127;                         // tile col (n)
        float4 v = *(const float4*)(W + (size_t)(t * 32 + k) * 1024 + n0 + n);
        lt[k][n] = v.x; lt[k][n + 1] = v.y; lt[k][n + 2] = v.z; lt[k][n + 3] = v.w;
    }
    __syncthreads();
    const int lane = tid & 63, w = tid >> 6;
#pragma unroll
    for (int i = 0; i < 2; ++i) {
        const int c = w * 2 + i;
        const int rl = c * 16 + (lane >> 2);            // local row (n) 0..127
        const int q = (lane & 3) ^ ((rl >> 1) & 3);     // content k-group
        u32 hp[4], lp[4];
#pragma unroll
        for (int e2 = 0; e2 < 4; ++e2)
            split2(lt[q * 8 + 2 * e2][rl], lt[q * 8 + 2 * e2 + 1][rl], hp[e2], lp[e2]);
        const size_t dsto = ((((size_t)nb * NTt + t) * 8 + c) << 9) + lane * 8;
        *(uint4*)&Th[dsto] = make_uint4(hp[0], hp[1], hp[2], hp[3]);
        *(uint4*)&Tl[dsto] = make_uint4(lp[0], lp[1], lp[2], lp[3]);
    }
    __syncthreads();
}

__global__ __launch_bounds__(256) void prep_kernel(
    const float* __restrict__ fc6_w, const float* __restrict__ fc7_w,
    const float* __restrict__ cls_w, const float* __restrict__ box_w,
    const float* __restrict__ A,
    u16* __restrict__ W6h, u16* __restrict__ W6l,
    u16* __restrict__ W7h, u16* __restrict__ W7l,
    float* __restrict__ Wcat, u16* __restrict__ A6h, u16* __restrict__ A6l)
{
    __shared__ float lt[32][129];
    const int b = blockIdx.x;
    const int tid = threadIdx.x;

    if (b < NB_WCAT) {
        int i = b * 256 + tid;
        if (i < HID * NCOL) {
            int k = i / NCOL, c = i % NCOL;
            float v = 0.0f;
            if (c < 21) v = cls_w[k * 21 + c];
            else if (c < 105) v = box_w[k * 84 + (c - 21)];
            Wcat[i] = v;
        }
    } else if (b < NB_WCAT + NB_T7C) {
        int idx = b - NB_WCAT;                  // 8 nb x 32 t
        w_chunks(fc7_w, W7h, W7l, 32, idx / 32, idx % 32, tid, lt);
    } else if (b < NB_WCAT + NB_T7C + NB_T6C) {
        int idx = b - NB_WCAT - NB_T7C;         // 8 nb x 392 t
        w_chunks(fc6_w, W6h, W6l, 392, idx / 392, idx % 392, tid, lt);
    } else {
        // A chunk-gather, depth-4 software pipeline (8 loads in flight per wave).
        // Chunk->lane mapping, values, and store addresses identical to round 15.
        const int sb = b - NB_WCAT - NB_T7C - NB_T6C;   // 0..2047
        const int lane = tid & 63;
        const int w = tid >> 6;
        const int NCH = (NPB / 128) * (FEAT_DIM / 32) * 8;   // 100352
        const int STRIDE = NB_SPA * 4;                        // 8192
        const int STRIDE4 = STRIDE * 4;                       // 32768

        auto srcaddr = [&](int ch) -> const float* {
            const int c = ch & 7;
            const int tmp = ch >> 3;
            const int t = tmp % (FEAT_DIM / 32);
            const int blk = tmp / (FEAT_DIM / 32);
            const int r = blk * 128 + c * 16 + (lane >> 2);
            const int col = t * 32 + (((lane & 3) ^ ((r >> 1) & 3)) << 3);
            return A + (size_t)r * FEAT_DIM + col;
        };
        auto proc = [&](int ch, const float4& xx, const float4& yy) {
            u32 hp0, hp1, hp2, hp3, lp0, lp1, lp2, lp3;
            split2(xx.x, xx.y, hp0, lp0);
            split2(xx.z, xx.w, hp1, lp1);
            split2(yy.x, yy.y, hp2, lp2);
            split2(yy.z, yy.w, hp3, lp3);
            const size_t dsto = ((size_t)ch << 9) + lane * 8;
            *(uint4*)&A6h[dsto] = make_uint4(hp0, hp1, hp2, hp3);
            *(uint4*)&A6l[dsto] = make_uint4(lp0, lp1, lp2, lp3);
        };

        int c0 = sb * 4 + w;                 // base in [0, 8192)
        int c1 = c0 + STRIDE;
        int c2 = c1 + STRIDE;
        int c3 = c2 + STRIDE;
        float4 x0{}, y0{}, x1{}, y1{}, x2{}, y2{}, x3{}, y3{};
        { const float* s = srcaddr(c0); x0 = *(const float4*)s; y0 = *(const float4*)(s + 4); }
        { const float* s = srcaddr(c1); x1 = *(const float4*)s; y1 = *(const float4*)(s + 4); }
        { const float* s = srcaddr(c2); x2 = *(const float4*)s; y2 = *(const float4*)(s + 4); }
        { const float* s = srcaddr(c3); x3 = *(const float4*)s; y3 = *(const float4*)(s + 4); }

        while (c0 < NCH || c1 < NCH || c2 < NCH || c3 < NCH) {
            if (c0 < NCH) {
                proc(c0, x0, y0);
                c0 += STRIDE4;
                if (c0 < NCH) { const float* s = srcaddr(c0); x0 = *(const float4*)s; y0 = *(const float4*)(s + 4); }
            }
            if (c1 < NCH) {
                proc(c1, x1, y1);
                c1 += STRIDE4;
                if (c1 < NCH) { const float* s = srcaddr(c1); x1 = *(const float4*)s; y1 = *(const float4*)(s + 4); }
            }
            if (c2 < NCH) {
                proc(c2, x2, y2);
                c2 += STRIDE4;
                if (c2 < NCH) { const float* s = srcaddr(c2); x2 = *(const float4*)s; y2 = *(const float4*)(s + 4); }
            }
            if (c3 < NCH) {
                proc(c3, x3, y3);
                c3 += STRIDE4;
                if (c3 < NCH) { const float* s = srcaddr(c3); x3 = *(const float4*)s; y3 = *(const float4*)(s + 4); }
            }
        }
    }
}

// ============ linear transpose+split (fallback paths) ============
__global__ __launch_bounds__(256) void transpose_split(
    const float* __restrict__ W, u16* __restrict__ WhT, u16* __restrict__ WlT,
    int K, int N)
{
    __shared__ float tile[32][33];
    const int tid = threadIdx.x;
    const int n0 = blockIdx.x * 32;
    const int k0 = blockIdx.y * 32;
    {
        int i = tid >> 3, j4 = (tid & 7) * 4;
        float4 v = *(const float4*)(W + (size_t)(k0 + i) * N + n0 + j4);
        tile[i][j4] = v.x; tile[i][j4 + 1] = v.y; tile[i][j4 + 2] = v.z; tile[i][j4 + 3] = v.w;
    }
    __syncthreads();
    {
        int i = tid >> 3, j4 = (tid & 7) * 4;
        u32 hp0, lp0, hp1, lp1;
        split2(tile[j4 + 0][i], tile[j4 + 1][i], hp0, lp0);
        split2(tile[j4 + 2][i], tile[j4 + 3][i], hp1, lp1);
        size_t o = (size_t)(n0 + i) * K + k0 + j4;
        *(uint2*)&WhT[o] = make_uint2(hp0, hp1);
        *(uint2*)&WlT[o] = make_uint2(lp0, lp1);
    }
}

// ============ concat cls_w | box_w (fallback paths) ============
__global__ void build_wcat(const float* __restrict__ cls_w, const float* __restrict__ box_w,
                           float* __restrict__ Wcat)
{
    int i = blockIdx.x * 256 + threadIdx.x;
    if (i >= HID * NCOL) return;
    int k = i / NCOL, c = i % NCOL;
    float v = 0.0f;
    if (c < 21) v = cls_w[k * 21 + c];
    else if (c < 105) v = box_w[k * 84 + (c - 21)];
    Wcat[i] = v;
}

// ============ tiled 2-phase GEMM: pure contiguous global_load_lds staging ========
// Generalized swizzle: mb = mb0 + xcd*(ymask+1) + yy, bz = j>>bzshift.
__global__ __launch_bounds__(256) void gemm_2ph_tiled(
    const u16* __restrict__ Ah, const u16* __restrict__ Al,
    const u16* __restrict__ Wh, const u16* __restrict__ Wl,
    const float* __restrict__ bias, float* __restrict__ Cout,
    int M, int Nn, int NTt, int tN, int mb0, int ymask, int bzshift)
{
    __shared__ u16 sm[2 * 16384];

    const int tid = threadIdx.x;
    const int lane = tid & 63;
    const int wv = tid >> 6;
    const int wr = wv >> 1, wc = wv & 1;

    const int flat = blockIdx.x + (blockIdx.y << 3) + blockIdx.z * 8 * gridDim.y;
    const int xcd = flat & 7;
    const int j = flat >> 3;
    const int bxi = j & 7;
    const int yy = (j >> 3) & ymask;
    const int bz = j >> bzshift;
    const int mb = mb0 + xcd * (ymask + 1) + yy;
    const int nb = bxi;
    const int bm = mb * 128, bn = nb * 128;
    const int t0 = bz * tN;

    const size_t abase = (size_t)mb * NTt * 4096;
    const size_t wbase = (size_t)nb * NTt * 4096;

    const int fr = lane & 15, fq = lane >> 4;
    int ia[4], ib[4];
#pragma unroll
    for (int m = 0; m < 4; ++m) {
        int ra = wr * 64 + m * 16 + fr;
        ia[m] = ra * 32 + ((fq ^ ((ra >> 1) & 3)) << 3);
        int rb = wc * 64 + m * 16 + fr;
        ib[m] = rb * 32 + ((fq ^ ((rb >> 1) & 3)) << 3);
    }

    f32x4 acc[4][4];
#pragma unroll
    for (int m = 0; m < 4; ++m)
#pragma unroll
        for (int n = 0; n < 4; ++n)
            acc[m][n] = (f32x4){0.f, 0.f, 0.f, 0.f};

    auto stage = [&](u16* dst, int t) {
#pragma unroll
        for (int i = 0; i < 2; ++i) {
            const int c = wv * 2 + i;
            const size_t so = (((size_t)t * 8 + c) << 9) + lane * 8;
            __builtin_amdgcn_global_load_lds(
                (const __attribute__((address_space(1))) u32*)(Ah + abase + so),
                (__attribute__((address_space(3))) u32*)(dst + c * 512), 16, 0, 0);
            __builtin_amdgcn_global_load_lds(
                (const __attribute__((address_space(1))) u32*)(Al + abase + so),
                (__attribute__((address_space(3))) u32*)(dst + 4096 + c * 512), 16, 0, 0);
            __builtin_amdgcn_global_load_lds(
                (const __attribute__((address_space(1))) u32*)(Wh + wbase + so),
                (__attribute__((address_space(3))) u32*)(dst + 8192 + c * 512), 16, 0, 0);
            __builtin_amdgcn_global_load_lds(
                (const __attribute__((address_space(1))) u32*)(Wl + wbase + so),
                (__attribute__((address_space(3))) u32*)(dst + 12288 + c * 512), 16, 0, 0);
        }
    };

    auto compute = [&](const u16* src) {
        s16x8 fah[4], fal[4], fbh[4], fbl[4];
#pragma unroll
        for (int m = 0; m < 4; ++m) {
            fah[m] = *(const s16x8*)&src[ia[m]];
            fal[m] = *(const s16x8*)&src[4096 + ia[m]];
            fbh[m] = *(const s16x8*)&src[8192 + ib[m]];
            fbl[m] = *(const s16x8*)&src[12288 + ib[m]];
        }
        __builtin_amdgcn_s_setprio(1);
#pragma unroll
        for (int m = 0; m < 4; ++m)
#pragma unroll
            for (int n = 0; n < 4; ++n) {
                acc[m][n] = __builtin_amdgcn_mfma_f32_16x16x32_bf16(fah[m], fbh[n], acc[m][n], 0, 0, 0);
                acc[m][n] = __builtin_amdgcn_mfma_f32_16x16x32_bf16(fah[m], fbl[n], acc[m][n], 0, 0, 0);
                acc[m][n] = __builtin_amdgcn_mfma_f32_16x16x32_bf16(fal[m], fbh[n], acc[m][n], 0, 0, 0);
            }
        __builtin_amdgcn_s_setprio(0);
    };

    u16* bufc = sm;
    u16* bufn = sm + 16384;

    stage(bufc, t0);
    for (int t = 0; t < tN; ++t) {
        if (t + 1 < tN) {
            stage(bufn, t0 + t + 1);
            asm volatile("s_waitcnt vmcnt(8)" ::: "memory");
        } else {
            asm volatile("s_waitcnt vmcnt(0)" ::: "memory");
        }
        asm volatile("s_barrier" ::: "memory");
        compute(bufc);
        asm volatile("s_barrier" ::: "memory");
        u16* tmp = bufc; bufc = bufn; bufn = tmp;
    }

    if (bias != nullptr) {
#pragma unroll
        for (int n = 0; n < 4; ++n) {
            int col = bn + wc * 64 + n * 16 + fr;
            float bb = bias[col];
#pragma unroll
            for (int m = 0; m < 4; ++m) {
                int row0 = bm + wr * 64 + m * 16 + fq * 4;
#pragma unroll
                for (int jj = 0; jj < 4; ++jj)
                    Cout[(size_t)(row0 + jj) * Nn + col] = fmaxf(acc[m][n][jj] + bb, 0.0f);
            }
        }
    } else {
        float* Cp = Cout + (size_t)bz * M * Nn;
#pragma unroll
        for (int n = 0; n < 4; ++n) {
            int col = bn + wc * 64 + n * 16 + fr;
#pragma unroll
            for (int m = 0; m < 4; ++m) {
                int row0 = bm + wr * 64 + m * 16 + fq * 4;
#pragma unroll
                for (int jj = 0; jj < 4; ++jj)
                    Cp[(size_t)(row0 + jj) * Nn + col] = acc[m][n][jj];
            }
        }
    }
}

// ============ round-7 2-phase GEMM (in-loop A split) — fallback ============
__global__ __launch_bounds__(256) void gemm_2ph(
    const float* __restrict__ A, const u16* __restrict__ WhT, const u16* __restrict__ WlT,
    const float* __restrict__ bias, float* __restrict__ Cout,
    int M, int Nn, int K, int KC)
{
    __shared__ u16 sm[2 * 16384];

    const int tid = threadIdx.x;
    const int lane = tid & 63;
    const int wv = tid >> 6;
    const int wr = wv >> 1, wc = wv & 1;

    const int flat = blockIdx.x + (blockIdx.y << 3) + (blockIdx.z << 8);
    const int xcd = flat & 7;
    const int j = flat >> 3;
    const int bxi = j & 7;
    const int yy = (j >> 3) & 3;
    const int bz = j >> 5;
    const int bm = (xcd * 4 + yy) * 128;
    const int bn = bxi * 128;
    const int k0 = bz * KC;
    const int NT = KC / 32;

    const int ar = tid >> 1;
    const int ah = tid & 1;
    const float* aPtr = A + (size_t)(bm + ar) * K + ah * 16;
    const int asw = (ar >> 1) & 3;
    const int ac0 = ((2 * ah) ^ asw) << 3;
    const int ac1 = ((2 * ah + 1) ^ asw) << 3;

    int wrow[2], wlc[2];
#pragma unroll
    for (int i = 0; i < 2; ++i) {
        int c = wv * 2 + i;
        wrow[i] = c * 16 + (lane >> 2);
        wlc[i] = ((lane & 3) ^ ((wrow[i] >> 1) & 3)) * 8;
    }

    const int fr = lane & 15, fq = lane >> 4;
    int ia[4], ib[4];
#pragma unroll
    for (int m = 0; m < 4; ++m) {
        int ra = wr * 64 + m * 16 + fr;
        ia[m] = ra * 32 + ((fq ^ ((ra >> 1) & 3)) << 3);
        int rb = wc * 64 + m * 16 + fr;
        ib[m] = rb * 32 + ((fq ^ ((rb >> 1) & 3)) << 3);
    }

    f32x4 acc[4][4];
#pragma unroll
    for (int m = 0; m < 4; ++m)
#pragma unroll
        for (int n = 0; n < 4; ++n)
            acc[m][n] = (f32x4){0.f, 0.f, 0.f, 0.f};

    auto stage_w = [&](u16* dst, int kk) {
#pragma unroll
        for (int i = 0; i < 2; ++i) {
            const int c = wv * 2 + i;
            const u16* gh = WhT + (size_t)(bn + wrow[i]) * K + kk + wlc[i];
            const u16* gl = WlT + (size_t)(bn + wrow[i]) * K + kk + wlc[i];
            __builtin_amdgcn_global_load_lds(
                (const __attribute__((address_space(1))) u32*)gh,
                (__attribute__((address_space(3))) u32*)(dst + 8192 + c * 512), 16, 0, 0);
            __builtin_amdgcn_global_load_lds(
                (const __attribute__((address_space(1))) u32*)gl,
                (__attribute__((address_space(3))) u32*)(dst + 12288 + c * 512), 16, 0, 0);
        }
    };

    auto split_a = [&](u16* dst, float4 v0, float4 v1, float4 v2, float4 v3) {
        u32 hp[8], lp[8];
        split2(v0.x, v0.y, hp[0], lp[0]);
        split2(v0.z, v0.w, hp[1], lp[1]);
        split2(v1.x, v1.y, hp[2], lp[2]);
        split2(v1.z, v1.w, hp[3], lp[3]);
        split2(v2.x, v2.y, hp[4], lp[4]);
        split2(v2.z, v2.w, hp[5], lp[5]);
        split2(v3.x, v3.y, hp[6], lp[6]);
        split2(v3.z, v3.w, hp[7], lp[7]);
        *(uint4*)&dst[ar * 32 + ac0] = make_uint4(hp[0], hp[1], hp[2], hp[3]);
        *(uint4*)&dst[ar * 32 + ac1] = make_uint4(hp[4], hp[5], hp[6], hp[7]);
        *(uint4*)&dst[4096 + ar * 32 + ac0] = make_uint4(lp[0], lp[1], lp[2], lp[3]);
        *(uint4*)&dst[4096 + ar * 32 + ac1] = make_uint4(lp[4], lp[5], lp[6], lp[7]);
    };

    auto compute = [&](const u16* src) {
        s16x8 fah[4], fal[4], fbh[4], fbl[4];
#pragma unroll
        for (int m = 0; m < 4; ++m) {
            fah[m] = *(const s16x8*)&src[ia[m]];
            fal[m] = *(const s16x8*)&src[4096 + ia[m]];
            fbh[m] = *(const s16x8*)&src[8192 + ib[m]];
            fbl[m] = *(const s16x8*)&src[12288 + ib[m]];
        }
        __builtin_amdgcn_s_setprio(1);
#pragma unroll
        for (int m = 0; m < 4; ++m)
#pragma unroll
            for (int n = 0; n < 4; ++n) {
                acc[m][n] = __builtin_amdgcn_mfma_f32_16x16x32_bf16(fah[m], fbh[n], acc[m][n], 0, 0, 0);
                acc[m][n] = __builtin_amdgcn_mfma_f32_16x16x32_bf16(fah[m], fbl[n], acc[m][n], 0, 0, 0);
                acc[m][n] = __builtin_amdgcn_mfma_f32_16x16x32_bf16(fal[m], fbh[n], acc[m][n], 0, 0, 0);
            }
        __builtin_amdgcn_s_setprio(0);
    };

    u16* bufc = sm;
    u16* bufn = sm + 16384;

    stage_w(bufc, k0);
    {
        float4 a0 = *(const float4*)(aPtr + k0 + 0);
        float4 a1 = *(const float4*)(aPtr + k0 + 4);
        float4 a2 = *(const float4*)(aPtr + k0 + 8);
        float4 a3 = *(const float4*)(aPtr + k0 + 12);
        split_a(bufc, a0, a1, a2, a3);
    }
    asm volatile("s_waitcnt vmcnt(0) lgkmcnt(0)\n\ts_barrier" ::: "memory");

    for (int t = 0; t < NT; ++t) {
        float4 a0{}, a1{}, a2{}, a3{};
        const bool hn = (t + 1 < NT);
        if (hn) {
            const int kk = k0 + (t + 1) * 32;
            stage_w(bufn, kk);
            a0 = *(const float4*)(aPtr + kk + 0);
            a1 = *(const float4*)(aPtr + kk + 4);
            a2 = *(const float4*)(aPtr + kk + 8);
            a3 = *(const float4*)(aPtr + kk + 12);
        }
        compute(bufc);
        if (hn) split_a(bufn, a0, a1, a2, a3);
        asm volatile("s_waitcnt vmcnt(0) lgkmcnt(0)\n\ts_barrier" ::: "memory");
        u16* tmp = bufc; bufc = bufn; bufn = tmp;
    }

    if (bias != nullptr) {
#pragma unroll
        for (int n = 0; n < 4; ++n) {
            int col = bn + wc * 64 + n * 16 + fr;
            float bb = bias[col];
#pragma unroll
            for (int m = 0; m < 4; ++m) {
                int row0 = bm + wr * 64 + m * 16 + fq * 4;
#pragma unroll
                for (int jj = 0; jj < 4; ++jj)
                    Cout[(size_t)(row0 + jj) * Nn + col] = fmaxf(acc[m][n][jj] + bb, 0.0f);
            }
        }
    } else {
        float* Cp = Cout + (size_t)bz * M * Nn;
#pragma unroll
        for (int n = 0; n < 4; ++n) {
            int col = bn + wc * 64 + n * 16 + fr;
#pragma unroll
            for (int m = 0; m < 4; ++m) {
                int row0 = bm + wr * 64 + m * 16 + fq * 4;
#pragma unroll
                for (int jj = 0; jj < 4; ++jj)
                    Cp[(size_t)(row0 + jj) * Nn + col] = acc[m][n][jj];
            }
        }
    }
}

// ============ reduce 4 partials + bias + relu (fp32 out, fallback) ============
__global__ __launch_bounds__(256) void reduce_bias_relu(
    const float* __restrict__ Cpart, const float* __restrict__ bias,
    float* __restrict__ X, int MN, int Nn)
{
    const int total = MN / 4;
    for (int i4 = blockIdx.x * 256 + threadIdx.x; i4 < total; i4 += gridDim.x * 256) {
        const size_t o = (size_t)i4 * 4;
        float4 a = *(const float4*)(Cpart + o);
        float4 b = *(const float4*)(Cpart + (size_t)MN + o);
        float4 c = *(const float4*)(Cpart + 2 * (size_t)MN + o);
        float4 d = *(const float4*)(Cpart + 3 * (size_t)MN + o);
        float4 bb = *(const float4*)(bias + (o & (size_t)(Nn - 1)));
        float4 r;
        r.x = fmaxf(a.x + b.x + c.x + d.x + bb.x, 0.0f);
        r.y = fmaxf(a.y + b.y + c.y + d.y + bb.y, 0.0f);
        r.z = fmaxf(a.z + b.z + c.z + d.z + bb.z, 0.0f);
        r.w = fmaxf(a.w + b.w + c.w + d.w + bb.w, 0.0f);
        *(float4*)(X + o) = r;
    }
}

// ============ reduce 4 partials + bias + relu, emit tiled split bf16 ============
__global__ __launch_bounds__(256) void reduce_split_tiled(
    const float* __restrict__ Cpart, const float* __restrict__ bias,
    u16* __restrict__ Xh, u16* __restrict__ Xl, int MN, int Nn)
{
    const int total = MN / 8;
    for (int i = blockIdx.x * 256 + threadIdx.x; i < total; i += gridDim.x * 256) {
        const size_t o = (size_t)i * 8;
        float r8[8];
#pragma unroll
        for (int h = 0; h < 2; ++h) {
            float4 a = *(const float4*)(Cpart + o + h * 4);
            float4 b = *(const float4*)(Cpart + (size_t)MN + o + h * 4);
            float4 c = *(const float4*)(Cpart + 2 * (size_t)MN + o + h * 4);
            float4 d = *(const float4*)(Cpart + 3 * (size_t)MN + o + h * 4);
            float4 bb = *(const float4*)(bias + ((o + h * 4) & (size_t)(Nn - 1)));
            r8[h * 4 + 0] = fmaxf(a.x + b.x + c.x + d.x + bb.x, 0.0f);
            r8[h * 4 + 1] = fmaxf(a.y + b.y + c.y + d.y + bb.y, 0.0f);
            r8[h * 4 + 2] = fmaxf(a.z + b.z + c.z + d.z + bb.z, 0.0f);
            r8[h * 4 + 3] = fmaxf(a.w + b.w + c.w + d.w + bb.w, 0.0f);
        }
        u32 hp[4], lp[4];
#pragma unroll
        for (int t2 = 0; t2 < 4; ++t2)
            split2(r8[2 * t2], r8[2 * t2 + 1], hp[t2], lp[t2]);
        int row = (int)(o >> 10);                 // Nn == 1024
        int rem = (int)(o & 1023);
        int t = rem >> 5, g = (rem >> 3) & 3;
        size_t dsto = tile_off(row >> 7, 32, t, row, g);
        *(uint4*)&Xh[dsto] = make_uint4(hp[0], hp[1], hp[2], hp[3]);
        *(uint4*)&Xl[dsto] = make_uint4(lp[0], lp[1], lp[2], lp[3]);
    }
}

// ============ fused heads GEMM + postproc (16 rows/block, fp32 exact) ========
__global__ __launch_bounds__(256) void heads_postproc(
    const float* __restrict__ X2, const float* __restrict__ Wcat,
    const float* __restrict__ cls_b, const float* __restrict__ box_b,
    const float* __restrict__ proposals,
    float* __restrict__ bxo, float* __restrict__ sco,
    int* __restrict__ lbo, int* __restrict__ vdo)
{
    __shared__ float Xs[16][36];
    __shared__ float Ws[32 * NCOL];
    __shared__ float lgs[16][NCOL];
    const int tid = threadIdx.x;
    const int m0 = blockIdx.x * 16;
    const int tr = tid >> 4;            // 16 rows
    const int tc = tid & 15;            // 16 col-groups x 7
    float acc[7] = {};
    for (int k0 = 0; k0 < HID; k0 += 32) {
        if (tid < 128) {
            int i = tid >> 3, j4 = (tid & 7) * 4;
            float4 v = *(const float4*)(X2 + (size_t)(m0 + i) * HID + k0 + j4);
            Xs[i][j4] = v.x; Xs[i][j4 + 1] = v.y; Xs[i][j4 + 2] = v.z; Xs[i][j4 + 3] = v.w;
        }
        const float4* src = (const float4*)(Wcat + (size_t)k0 * NCOL);
        float4* dst = (float4*)Ws;
        for (int i4 = tid; i4 < (32 * NCOL) / 4; i4 += 256) dst[i4] = src[i4];
        __syncthreads();
#pragma unroll 4
        for (int kk = 0; kk < 32; ++kk) {
            float a0 = Xs[tr][kk];
#pragma unroll
            for (int j = 0; j < 7; ++j)
                acc[j] = fmaf(a0, Ws[kk * NCOL + tc * 7 + j], acc[j]);
        }
        __syncthreads();
    }
#pragma unroll
    for (int j = 0; j < 7; ++j)
        lgs[tr][tc * 7 + j] = acc[j];
    __syncthreads();

    if (tid < 16) {
        const int p = m0 + tid;
        const float* lg = lgs[tid];
        float l[21];
        float m = -1e30f;
#pragma unroll
        for (int c = 0; c < 21; ++c) { l[c] = lg[c] + cls_b[c]; m = fmaxf(m, l[c]); }
        float e[21]; float s = 0.0f;
#pragma unroll
        for (int c = 0; c < 21; ++c) { e[c] = expf(l[c] - m); s += e[c]; }
        int best = 1;
#pragma unroll
        for (int c = 2; c < 21; ++c) if (e[c] > e[best]) best = c;
        const float score = e[best] / s;

        float d0 = (lg[21 + best * 4 + 0] + box_b[best * 4 + 0]) * 0.1f;
        float d1 = (lg[21 + best * 4 + 1] + box_b[best * 4 + 1]) * 0.1f;
        float d2 = (lg[21 + best * 4 + 2] + box_b[best * 4 + 2]) * 0.2f;
        float d3 = (lg[21 + best * 4 + 3] + box_b[best * 4 + 3]) * 0.2f;
        const float* pr = proposals + p * 4;
        float w_ = pr[2] - pr[0], h_ = pr[3] - pr[1];
        float cx = pr[0] + 0.5f * w_, cy = pr[1] + 0.5f * h_;
        float pcx = d0 * w_ + cx, pcy = d1 * h_ + cy;
        float pw = expf(d2) * w_, ph = expf(d3) * h_;
        float b0 = pcx - 0.5f * pw, b1 = pcy - 0.5f * ph;
        float b2 = pcx + 0.5f * pw, b3 = pcy + 0.5f * ph;
        b0 = fminf(fmaxf(b0, 0.0f), IMG);
        b1 = fminf(fmaxf(b1, 0.0f), IMG);
        b2 = fminf(fmaxf(b2, 0.0f), IMG);
        b3 = fminf(fmaxf(b3, 0.0f), IMG);
        int vd = (b2 - b0 > 0.0f) && (b3 - b1 > 0.0f) && (score > SCORE_THRESH);
        bxo[p * 4 + 0] = b0; bxo[p * 4 + 1] = b1;
        bxo[p * 4 + 2] = b2; bxo[p * 4 + 3] = b3;
        sco[p] = score;
        lbo[p] = best;
        vdo[p] = vd;
    }
}

// ============ fused NMS + finalize: ballot mask build + pipelined scan ============
__global__ __launch_bounds__(1024) void nms_finalize(
    const float* __restrict__ bx, const float* __restrict__ sc,
    const int* __restrict__ label, const int* __restrict__ valid,
    const float* __restrict__ proposals, float* __restrict__ out)
{
    const int img = blockIdx.x;
    const int base = img * NPROP;
    const int tid = threadIdx.x;
    const int lane = tid & 63;
    const int wv = tid >> 6;                // 16 waves

    __shared__ u64 maskm[NPROP][16];        // 128 KB (aliases sort keys)
    __shared__ float4 sbx[NPROP];           // 16 KB
    __shared__ float sarea[NPROP];          // 4 KB
    __shared__ u64 kword[16];
    __shared__ int nv;

    u64* skey = &maskm[0][0];               // alias (dead before mask build)

    if (tid == 0) nv = 0;

    // key: ascending <=> (score desc, index asc) — stable argsort(-sc)
    {
        float s = valid[base + tid] ? sc[base + tid] : -1.0f;
        unsigned u = __float_as_uint(s);
        u = (u & 0x80000000u) ? ~u : (u | 0x80000000u);
        u = ~u;
        skey[tid] = ((u64)u << 32) | (unsigned)tid;
    }
    for (int k = 2; k <= NPROP; k <<= 1) {
        for (int j = k >> 1; j > 0; j >>= 1) {
            __syncthreads();
            int ixj = tid ^ j;
            if (ixj > tid) {
                u64 a = skey[tid], b = skey[ixj];
                bool up = ((tid & k) == 0);
                if (up ? (a > b) : (a < b)) { skey[tid] = b; skey[ixj] = a; }
            }
        }
    }
    __syncthreads();

    // sorted order; offset boxes (reference arithmetic); kword via per-wave ballot
    const int myp = (int)(skey[tid] & 0xffffffffu);
    {
        float off = (float)label[base + myp] * (IMG + 1.0f);
        float x0 = bx[(base + myp) * 4 + 0] + off;
        float y0 = bx[(base + myp) * 4 + 1] + off;
        float x1 = bx[(base + myp) * 4 + 2] + off;
        float y1 = bx[(base + myp) * 4 + 3] + off;
        sbx[tid] = make_float4(x0, y0, x1, y1);
        sarea[tid] = (x1 - x0) * (y1 - y0);
        int v = valid[base + myp];
        u64 bb = __ballot(v != 0);           // wave wv covers exactly word wv
        if (lane == 0) kword[wv] = bb;
        if (v) atomicMax(&nv, tid + 1);      // valids sort to the front
    }
    __syncthreads();
    const int nvalid = nv;

    // ballot mask build: wave owns row i; lane handles j = w*64 + lane.
    for (int i = wv; i < nvalid; i += 16) {
        const float4 bi = sbx[i];
        const float ai = sarea[i];
#pragma unroll 4
        for (int w = 0; w < 16; ++w) {
            const int j = w * 64 + lane;
            bool sup = false;
            if (j > i && j < nvalid) {
                float4 bj = sbx[j];
                float lt0 = fmaxf(bi.x, bj.x);
                float lt1 = fmaxf(bi.y, bj.y);
                float rb0 = fminf(bi.z, bj.z);
                float rb1 = fminf(bi.w, bj.w);
                float w_ = fmaxf(rb0 - lt0, 0.0f);
                float h_ = fmaxf(rb1 - lt1, 0.0f);
                float inter = w_ * h_;
                float denom = fmaxf(ai + sarea[j] - inter, 1e-9f);
                sup = inter / denom > NMS_THRESH;
            }
            u64 bits = __ballot(sup);
            if (lane == 0) maskm[i][w] = bits;
        }
    }
    __syncthreads();

    // serial greedy scan — single wave, depth-4 row prefetch (named regs, rule #20)
    if (tid < 64) {
        u64 kw = (tid < 16) ? kword[tid] : 0ull;
        u64 ra = 0, rb = 0, rc = 0, rd = 0;
        if (tid < 16) {
            if (0 < nvalid) ra = maskm[0][tid];
            if (1 < nvalid) rb = maskm[1][tid];
            if (2 < nvalid) rc = maskm[2][tid];
            if (3 < nvalid) rd = maskm[3][tid];
        }
        for (int i = 0; i < nvalid; i += 4) {
            {
                u64 srcw = __shfl(kw, i >> 6, 64);
                if ((srcw >> (i & 63)) & 1ull) { if (tid < 16) kw &= ~ra; }
                if (tid < 16 && i + 4 < nvalid) ra = maskm[i + 4][tid];
            }
            if (i + 1 < nvalid) {
                u64 srcw = __shfl(kw, (i + 1) >> 6, 64);
                if ((srcw >> ((i + 1) & 63)) & 1ull) { if (tid < 16) kw &= ~rb; }
                if (tid < 16 && i + 5 < nvalid) rb = maskm[i + 5][tid];
            }
            if (i + 2 < nvalid) {
                u64 srcw = __shfl(kw, (i + 2) >> 6, 64);
                if ((srcw >> ((i + 2) & 63)) & 1ull) { if (tid < 16) kw &= ~rc; }
                if (tid < 16 && i + 6 < nvalid) rc = maskm[i + 6][tid];
            }
            if (i + 3 < nvalid) {
                u64 srcw = __shfl(kw, (i + 3) >> 6, 64);
                if ((srcw >> ((i + 3) & 63)) & 1ull) { if (tid < 16) kw &= ~rd; }
                if (tid < 16 && i + 7 < nvalid) rd = maskm[i + 7][tid];
            }
        }
        if (tid < 16) kword[tid] = kw;
    }
    __syncthreads();

    // fused finalize: thread tid owns original proposal (base + myp)
    {
        const int p = base + myp;
        const bool k = ((kword[tid >> 6] >> (tid & 63)) & 1ull) != 0;
        float* res   = out;
        float* keepo = out + NPB * 6;
        float* rpn   = keepo + NPB;
        float* rcnn  = rpn + NPB * 6;
        float b0 = bx[p * 4 + 0], b1 = bx[p * 4 + 1];
        float b2 = bx[p * 4 + 2], b3 = bx[p * 4 + 3];
        res[p * 6 + 0] = k ? b0 : 0.0f;
        res[p * 6 + 1] = k ? b1 : 0.0f;
        res[p * 6 + 2] = k ? b2 : 0.0f;
        res[p * 6 + 3] = k ? b3 : 0.0f;
        res[p * 6 + 4] = k ? (float)(label[p] - 1) : 0.0f;
        res[p * 6 + 5] = k ? sc[p] : 0.0f;
        keepo[p] = k ? 1.0f : 0.0f;
        rpn[p * 6 + 0] = proposals[p * 4 + 0];
        rpn[p * 6 + 1] = proposals[p * 4 + 1];
        rpn[p * 6 + 2] = proposals[p * 4 + 2];
        rpn[p * 6 + 3] = proposals[p * 4 + 3];
        rpn[p * 6 + 4] = 0.0f;
        rpn[p * 6 + 5] = 0.0f;
        rcnn[p * 6 + 0] = b0;
        rcnn[p * 6 + 1] = b1;
        rcnn[p * 6 + 2] = b2;
        rcnn[p * 6 + 3] = b3;
        rcnn[p * 6 + 4] = 0.0f;
        rcnn[p * 6 + 5] = 0.0f;
    }
}

// ============ launch ============
extern "C" void kernel_launch(void* const* d_in, const int* in_sizes, int n_in,
                              void* d_out, int out_size, void* d_ws, size_t ws_size,
                              hipStream_t stream)
{
    const float* props_feature = (const float*)d_in[0];
    const float* proposals     = (const float*)d_in[1];
    const float* fc6_w         = (const float*)d_in[2];
    const float* fc6_b         = (const float*)d_in[3];
    const float* fc7_w         = (const float*)d_in[4];
    const float* fc7_b         = (const float*)d_in[5];
    const float* cls_w         = (const float*)d_in[6];
    const float* cls_b         = (const float*)d_in[7];
    const float* box_w         = (const float*)d_in[8];
    const float* box_b         = (const float*)d_in[9];
    float* out = (float*)d_out;

    char* ws = (char*)d_ws;
    float* X1     = (float*)(ws);                                  // 16 MB (fallbacks)
    float* X2     = (float*)(ws + 16777216);                       // 16 MB
    float* Wcat   = (float*)(ws + 33554432);
    float* bx     = (float*)(ws + 35848192);
    float* sc     = (float*)(ws + 35913728);
    int*   label  = (int*)  (ws + 35930112);
    int*   valid  = (int*)  (ws + 35946496);
    u16*   W6h    = (u16*)  (ws + 35979264);                       // 24.5 MB
    u16*   W6l    = (u16*)  (ws + 61669376);                       // 24.5 MB
    u16*   W7h    = (u16*)  (ws + 87359488);                       // 2 MB
    u16*   W7l    = (u16*)  (ws + 89456640);                       // 2 MB
    float* Cpart  = (float*)(ws + 91553792);                       // 64 MB
    u16*   A6h    = (u16*)  (ws + 158662656);                      // 98 MB (tiled)
    u16*   A6l    = (u16*)  (ws + 261423104);                      // 98 MB
    u16*   X1h    = (u16*)  (ws + 364183552);                      // 8 MB (tiled)
    u16*   X1l    = (u16*)  (ws + 372572160);                      // 8 MB
    const size_t NEED_SK   = 158662656ull;
    const size_t NEED_FULL = 380960768ull;

    if (ws_size >= NEED_FULL) {
        prep_kernel<<<NB_PREP, 256, 0, stream>>>(
            fc6_w, fc7_w, cls_w, box_w, props_feature,
            W6h, W6l, W7h, W7l, Wcat, A6h, A6l);
        gemm_2ph_tiled<<<dim3(8, 16, 4), 256, 0, stream>>>(
            A6h, A6l, W6h, W6l, nullptr, Cpart, NPB, HID, FEAT_DIM / 32, FEAT_DIM / 128,
            0, 1, 4);
        gemm_2ph_tiled<<<dim3(8, 16, 4), 256, 0, stream>>>(
            A6h, A6l, W6h, W6l, nullptr, Cpart, NPB, HID, FEAT_DIM / 32, FEAT_DIM / 128,
            16, 1, 4);
        reduce_split_tiled<<<1024, 256, 0, stream>>>(
            Cpart, fc6_b, X1h, X1l, NPB * HID, HID);
        gemm_2ph_tiled<<<dim3(8, 32, 1), 256, 0, stream>>>(
            X1h, X1l, W7h, W7l, fc7_b, X2, NPB, HID, HID / 32, HID / 32,
            0, 3, 5);
    } else if (ws_size >= NEED_SK) {
        build_wcat<<<(HID * NCOL + 255) / 256, 256, 0, stream>>>(cls_w, box_w, Wcat);
        transpose_split<<<dim3(HID / 32, FEAT_DIM / 32), 256, 0, stream>>>(
            fc6_w, W6h, W6l, FEAT_DIM, HID);
        transpose_split<<<dim3(HID / 32, HID / 32), 256, 0, stream>>>(
            fc7_w, W7h, W7l, HID, HID);
        gemm_2ph<<<dim3(8, 32, 4), 256, 0, stream>>>(
            props_feature, W6h, W6l, nullptr, Cpart, NPB, HID, FEAT_DIM, FEAT_DIM / 4);
        reduce_bias_relu<<<1024, 256, 0, stream>>>(Cpart, fc6_b, X1, NPB * HID, HID);
        gemm_2ph<<<dim3(8, 32, 1), 256, 0, stream>>>(
            X1, W7h, W7l, fc7_b, X2, NPB, HID, HID, HID);
    } else {
        build_wcat<<<(HID * NCOL + 255) / 256, 256, 0, stream>>>(cls_w, box_w, Wcat);
        transpose_split<<<dim3(HID / 32, FEAT_DIM / 32), 256, 0, stream>>>(
            fc6_w, W6h, W6l, FEAT_DIM, HID);
        transpose_split<<<dim3(HID / 32, HID / 32), 256, 0, stream>>>(
            fc7_w, W7h, W7l, HID, HID);
        gemm_2ph<<<dim3(8, 32, 1), 256, 0, stream>>>(
            props_feature, W6h, W6l, fc6_b, X1, NPB, HID, FEAT_DIM, FEAT_DIM);
        gemm_2ph<<<dim3(8, 32, 1), 256, 0, stream>>>(
            X1, W7h, W7l, fc7_b, X2, NPB, HID, HID, HID);
    }

    heads_postproc<<<NPB / 16, 256, 0, stream>>>(
        X2, Wcat, cls_b, box_b, proposals, bx, sc, label, valid);

    nms_finalize<<<BATCH, 1024, 0, stream>>>(bx, sc, label, valid, proposals, out);
}

// Round 18
// 643.553 us; speedup vs baseline: 1.1536x; 1.0184x over previous
//
#include <hip/hip_runtime.h>
#include <hip/hip_bf16.h>

// Problem constants (from reference)
#define BATCH 4
#define NPROP 1024
#define HID 1024
#define NUM_CLASSES 21
#define FEAT_DIM 12544
#define NPB (BATCH * NPROP)             // 4096
#define IMG 800.0f
#define SCORE_THRESH 0.1f
#define NMS_THRESH 0.5f
#define NCOL 112                        // padded 21+84

typedef unsigned short u16;
typedef unsigned int u32;
typedef unsigned long long u64;
typedef short s16x8 __attribute__((ext_vector_type(8)));
typedef float f32x4 __attribute__((ext_vector_type(4)));

// hi/lo split of 2 floats via native RTNE bf16 converts (v_cvt_pk_bf16_f32).
__device__ __forceinline__ void split2(float x0, float x1, u32& hp, u32& lp) {
    __hip_bfloat162 h2 = __float22bfloat162_rn(make_float2(x0, x1));
    u32 h = *(u32*)&h2;
    float f0 = __uint_as_float(h << 16);
    float f1 = __uint_as_float(h & 0xffff0000u);
    __hip_bfloat162 l2 = __float22bfloat162_rn(make_float2(x0 - f0, x1 - f1));
    hp = h;
    lp = *(u32*)&l2;
}

// Tiled layout (LDS-image order, swizzle baked in):
//   T[blk][t][c(8)][lane(64)][8 u16], flat u16 off = ((blk*NTt + t)*8 + c)*512 + lane*8
__device__ __forceinline__ size_t tile_off(int blk, int NTt, int t, int row, int g) {
    int r = row & 127;
    int c = r >> 4;
    int lanei = ((r & 15) << 2) | (g ^ ((r >> 1) & 3));
    return ((((size_t)blk * NTt + t) * 8 + c) << 9) + lanei * 8;
}

// ============ fused prep kernel (all global R/W full-line coalesced) ============
#define NB_WCAT 448
#define NB_T7C  256          // 8 nb x 32 t
#define NB_T6C  3136         // 8 nb x 392 t
#define NB_SPA  2048
#define NB_PREP (NB_WCAT + NB_T7C + NB_T6C + NB_SPA)

// one block per (nb, t): stage W[t*32..+32][nb*128..+128] via LDS, emit 8 chunks
__device__ __forceinline__ void w_chunks(
    const float* __restrict__ W, u16* __restrict__ Th, u16* __restrict__ Tl,
    int NTt, int nb, int t, int tid, float (*lt)[129])
{
    const int n0 = nb * 128;
#pragma unroll
    for (int p = 0; p < 4; ++p) {
        int e = (p * 256 + tid) * 4;            // 0..4095 step 4
        int k = e >> 7;                          // tile row (k) 0..31
        int n = e & 127;                         // tile col (n)
        float4 v = *(const float4*)(W + (size_t)(t * 32 + k) * 1024 + n0 + n);
        lt[k][n] = v.x; lt[k][n + 1] = v.y; lt[k][n + 2] = v.z; lt[k][n + 3] = v.w;
    }
    __syncthreads();
    const int lane = tid & 63, w = tid >> 6;
#pragma unroll
    for (int i = 0; i < 2; ++i) {
        const int c = w * 2 + i;
        const int rl = c * 16 + (lane >> 2);            // local row (n) 0..127
        const int q = (lane & 3) ^ ((rl >> 1) & 3);     // content k-group
        u32 hp[4], lp[4];
#pragma unroll
        for (int e2 = 0; e2 < 4; ++e2)
            split2(lt[q * 8 + 2 * e2][rl], lt[q * 8 + 2 * e2 + 1][rl], hp[e2], lp[e2]);
        const size_t dsto = ((((size_t)nb * NTt + t) * 8 + c) << 9) + lane * 8;
        *(uint4*)&Th[dsto] = make_uint4(hp[0], hp[1], hp[2], hp[3]);
        *(uint4*)&Tl[dsto] = make_uint4(lp[0], lp[1], lp[2], lp[3]);
    }
    __syncthreads();
}

__global__ __launch_bounds__(256) void prep_kernel(
    const float* __restrict__ fc6_w, const float* __restrict__ fc7_w,
    const float* __restrict__ cls_w, const float* __restrict__ box_w,
    const float* __restrict__ A,
    u16* __restrict__ W6h, u16* __restrict__ W6l,
    u16* __restrict__ W7h, u16* __restrict__ W7l,
    float* __restrict__ Wcat, u16* __restrict__ A6h, u16* __restrict__ A6l)
{
    __shared__ float lt[32][129];
    const int b = blockIdx.x;
    const int tid = threadIdx.x;

    if (b < NB_WCAT) {
        int i = b * 256 + tid;
        if (i < HID * NCOL) {
            int k = i / NCOL, c = i % NCOL;
            float v = 0.0f;
            if (c < 21) v = cls_w[k * 21 + c];
            else if (c < 105) v = box_w[k * 84 + (c - 21)];
            Wcat[i] = v;
        }
    } else if (b < NB_WCAT + NB_T7C) {
        int idx = b - NB_WCAT;                  // 8 nb x 32 t
        w_chunks(fc7_w, W7h, W7l, 32, idx / 32, idx % 32, tid, lt);
    } else if (b < NB_WCAT + NB_T7C + NB_T6C) {
        int idx = b - NB_WCAT - NB_T7C;         // 8 nb x 392 t
        w_chunks(fc6_w, W6h, W6l, 392, idx / 392, idx % 392, tid, lt);
    } else {
        // A chunk-gather, depth-4 software pipeline (8 loads in flight per wave).
        const int sb = b - NB_WCAT - NB_T7C - NB_T6C;   // 0..2047
        const int lane = tid & 63;
        const int w = tid >> 6;
        const int NCH = (NPB / 128) * (FEAT_DIM / 32) * 8;   // 100352
        const int STRIDE = NB_SPA * 4;                        // 8192
        const int STRIDE4 = STRIDE * 4;                       // 32768

        auto srcaddr = [&](int ch) -> const float* {
            const int c = ch & 7;
            const int tmp = ch >> 3;
            const int t = tmp % (FEAT_DIM / 32);
            const int blk = tmp / (FEAT_DIM / 32);
            const int r = blk * 128 + c * 16 + (lane >> 2);
            const int col = t * 32 + (((lane & 3) ^ ((r >> 1) & 3)) << 3);
            return A + (size_t)r * FEAT_DIM + col;
        };
        auto proc = [&](int ch, const float4& xx, const float4& yy) {
            u32 hp0, hp1, hp2, hp3, lp0, lp1, lp2, lp3;
            split2(xx.x, xx.y, hp0, lp0);
            split2(xx.z, xx.w, hp1, lp1);
            split2(yy.x, yy.y, hp2, lp2);
            split2(yy.z, yy.w, hp3, lp3);
            const size_t dsto = ((size_t)ch << 9) + lane * 8;
            *(uint4*)&A6h[dsto] = make_uint4(hp0, hp1, hp2, hp3);
            *(uint4*)&A6l[dsto] = make_uint4(lp0, lp1, lp2, lp3);
        };

        int c0 = sb * 4 + w;
        int c1 = c0 + STRIDE;
        int c2 = c1 + STRIDE;
        int c3 = c2 + STRIDE;
        float4 x0{}, y0{}, x1{}, y1{}, x2{}, y2{}, x3{}, y3{};
        { const float* s = srcaddr(c0); x0 = *(const float4*)s; y0 = *(const float4*)(s + 4); }
        { const float* s = srcaddr(c1); x1 = *(const float4*)s; y1 = *(const float4*)(s + 4); }
        { const float* s = srcaddr(c2); x2 = *(const float4*)s; y2 = *(const float4*)(s + 4); }
        { const float* s = srcaddr(c3); x3 = *(const float4*)s; y3 = *(const float4*)(s + 4); }

        while (c0 < NCH || c1 < NCH || c2 < NCH || c3 < NCH) {
            if (c0 < NCH) {
                proc(c0, x0, y0);
                c0 += STRIDE4;
                if (c0 < NCH) { const float* s = srcaddr(c0); x0 = *(const float4*)s; y0 = *(const float4*)(s + 4); }
            }
            if (c1 < NCH) {
                proc(c1, x1, y1);
                c1 += STRIDE4;
                if (c1 < NCH) { const float* s = srcaddr(c1); x1 = *(const float4*)s; y1 = *(const float4*)(s + 4); }
            }
            if (c2 < NCH) {
                proc(c2, x2, y2);
                c2 += STRIDE4;
                if (c2 < NCH) { const float* s = srcaddr(c2); x2 = *(const float4*)s; y2 = *(const float4*)(s + 4); }
            }
            if (c3 < NCH) {
                proc(c3, x3, y3);
                c3 += STRIDE4;
                if (c3 < NCH) { const float* s = srcaddr(c3); x3 = *(const float4*)s; y3 = *(const float4*)(s + 4); }
            }
        }
    }
}

// ============ linear transpose+split (fallback paths) ============
__global__ __launch_bounds__(256) void transpose_split(
    const float* __restrict__ W, u16* __restrict__ WhT, u16* __restrict__ WlT,
    int K, int N)
{
    __shared__ float tile[32][33];
    const int tid = threadIdx.x;
    const int n0 = blockIdx.x * 32;
    const int k0 = blockIdx.y * 32;
    {
        int i = tid >> 3, j4 = (tid & 7) * 4;
        float4 v = *(const float4*)(W + (size_t)(k0 + i) * N + n0 + j4);
        tile[i][j4] = v.x; tile[i][j4 + 1] = v.y; tile[i][j4 + 2] = v.z; tile[i][j4 + 3] = v.w;
    }
    __syncthreads();
    {
        int i = tid >> 3, j4 = (tid & 7) * 4;
        u32 hp0, lp0, hp1, lp1;
        split2(tile[j4 + 0][i], tile[j4 + 1][i], hp0, lp0);
        split2(tile[j4 + 2][i], tile[j4 + 3][i], hp1, lp1);
        size_t o = (size_t)(n0 + i) * K + k0 + j4;
        *(uint2*)&WhT[o] = make_uint2(hp0, hp1);
        *(uint2*)&WlT[o] = make_uint2(lp0, lp1);
    }
}

// ============ concat cls_w | box_w (fallback paths) ============
__global__ void build_wcat(const float* __restrict__ cls_w, const float* __restrict__ box_w,
                           float* __restrict__ Wcat)
{
    int i = blockIdx.x * 256 + threadIdx.x;
    if (i >= HID * NCOL) return;
    int k = i / NCOL, c = i % NCOL;
    float v = 0.0f;
    if (c < 21) v = cls_w[k * 21 + c];
    else if (c < 105) v = box_w[k * 84 + (c - 21)];
    Wcat[i] = v;
}

// ============ tiled 2-phase GEMM: pure contiguous global_load_lds staging ========
// Generalized swizzle: mb = mb0 + xcd*(ymask+1) + yy, bz = j>>bzshift.
__global__ __launch_bounds__(256) void gemm_2ph_tiled(
    const u16* __restrict__ Ah, const u16* __restrict__ Al,
    const u16* __restrict__ Wh, const u16* __restrict__ Wl,
    const float* __restrict__ bias, float* __restrict__ Cout,
    int M, int Nn, int NTt, int tN, int mb0, int ymask, int bzshift)
{
    __shared__ u16 sm[2 * 16384];

    const int tid = threadIdx.x;
    const int lane = tid & 63;
    const int wv = tid >> 6;
    const int wr = wv >> 1, wc = wv & 1;

    const int flat = blockIdx.x + (blockIdx.y << 3) + blockIdx.z * 8 * gridDim.y;
    const int xcd = flat & 7;
    const int j = flat >> 3;
    const int bxi = j & 7;
    const int yy = (j >> 3) & ymask;
    const int bz = j >> bzshift;
    const int mb = mb0 + xcd * (ymask + 1) + yy;
    const int nb = bxi;
    const int bm = mb * 128, bn = nb * 128;
    const int t0 = bz * tN;

    const size_t abase = (size_t)mb * NTt * 4096;
    const size_t wbase = (size_t)nb * NTt * 4096;

    const int fr = lane & 15, fq = lane >> 4;
    int ia[4], ib[4];
#pragma unroll
    for (int m = 0; m < 4; ++m) {
        int ra = wr * 64 + m * 16 + fr;
        ia[m] = ra * 32 + ((fq ^ ((ra >> 1) & 3)) << 3);
        int rb = wc * 64 + m * 16 + fr;
        ib[m] = rb * 32 + ((fq ^ ((rb >> 1) & 3)) << 3);
    }

    f32x4 acc[4][4];
#pragma unroll
    for (int m = 0; m < 4; ++m)
#pragma unroll
        for (int n = 0; n < 4; ++n)
            acc[m][n] = (f32x4){0.f, 0.f, 0.f, 0.f};

    auto stage = [&](u16* dst, int t) {
#pragma unroll
        for (int i = 0; i < 2; ++i) {
            const int c = wv * 2 + i;
            const size_t so = (((size_t)t * 8 + c) << 9) + lane * 8;
            __builtin_amdgcn_global_load_lds(
                (const __attribute__((address_space(1))) u32*)(Ah + abase + so),
                (__attribute__((address_space(3))) u32*)(dst + c * 512), 16, 0, 0);
            __builtin_amdgcn_global_load_lds(
                (const __attribute__((address_space(1))) u32*)(Al + abase + so),
                (__attribute__((address_space(3))) u32*)(dst + 4096 + c * 512), 16, 0, 0);
            __builtin_amdgcn_global_load_lds(
                (const __attribute__((address_space(1))) u32*)(Wh + wbase + so),
                (__attribute__((address_space(3))) u32*)(dst + 8192 + c * 512), 16, 0, 0);
            __builtin_amdgcn_global_load_lds(
                (const __attribute__((address_space(1))) u32*)(Wl + wbase + so),
                (__attribute__((address_space(3))) u32*)(dst + 12288 + c * 512), 16, 0, 0);
        }
    };

    auto compute = [&](const u16* src) {
        s16x8 fah[4], fal[4], fbh[4], fbl[4];
#pragma unroll
        for (int m = 0; m < 4; ++m) {
            fah[m] = *(const s16x8*)&src[ia[m]];
            fal[m] = *(const s16x8*)&src[4096 + ia[m]];
            fbh[m] = *(const s16x8*)&src[8192 + ib[m]];
            fbl[m] = *(const s16x8*)&src[12288 + ib[m]];
        }
        __builtin_amdgcn_s_setprio(1);
#pragma unroll
        for (int m = 0; m < 4; ++m)
#pragma unroll
            for (int n = 0; n < 4; ++n) {
                acc[m][n] = __builtin_amdgcn_mfma_f32_16x16x32_bf16(fah[m], fbh[n], acc[m][n], 0, 0, 0);
                acc[m][n] = __builtin_amdgcn_mfma_f32_16x16x32_bf16(fah[m], fbl[n], acc[m][n], 0, 0, 0);
                acc[m][n] = __builtin_amdgcn_mfma_f32_16x16x32_bf16(fal[m], fbh[n], acc[m][n], 0, 0, 0);
            }
        __builtin_amdgcn_s_setprio(0);
    };

    u16* bufc = sm;
    u16* bufn = sm + 16384;

    stage(bufc, t0);
    for (int t = 0; t < tN; ++t) {
        if (t + 1 < tN) {
            stage(bufn, t0 + t + 1);
            asm volatile("s_waitcnt vmcnt(8)" ::: "memory");
        } else {
            asm volatile("s_waitcnt vmcnt(0)" ::: "memory");
        }
        asm volatile("s_barrier" ::: "memory");
        compute(bufc);
        asm volatile("s_barrier" ::: "memory");
        u16* tmp = bufc; bufc = bufn; bufn = tmp;
    }

    if (bias != nullptr) {
#pragma unroll
        for (int n = 0; n < 4; ++n) {
            int col = bn + wc * 64 + n * 16 + fr;
            float bb = bias[col];
#pragma unroll
            for (int m = 0; m < 4; ++m) {
                int row0 = bm + wr * 64 + m * 16 + fq * 4;
#pragma unroll
                for (int jj = 0; jj < 4; ++jj)
                    Cout[(size_t)(row0 + jj) * Nn + col] = fmaxf(acc[m][n][jj] + bb, 0.0f);
            }
        }
    } else {
        float* Cp = Cout + (size_t)bz * M * Nn;
#pragma unroll
        for (int n = 0; n < 4; ++n) {
            int col = bn + wc * 64 + n * 16 + fr;
#pragma unroll
            for (int m = 0; m < 4; ++m) {
                int row0 = bm + wr * 64 + m * 16 + fq * 4;
#pragma unroll
                for (int jj = 0; jj < 4; ++jj)
                    Cp[(size_t)(row0 + jj) * Nn + col] = acc[m][n][jj];
            }
        }
    }
}

// ============ round-7 2-phase GEMM (in-loop A split) — fallback ============
__global__ __launch_bounds__(256) void gemm_2ph(
    const float* __restrict__ A, const u16* __restrict__ WhT, const u16* __restrict__ WlT,
    const float* __restrict__ bias, float* __restrict__ Cout,
    int M, int Nn, int K, int KC)
{
    __shared__ u16 sm[2 * 16384];

    const int tid = threadIdx.x;
    const int lane = tid & 63;
    const int wv = tid >> 6;
    const int wr = wv >> 1, wc = wv & 1;

    const int flat = blockIdx.x + (blockIdx.y << 3) + (blockIdx.z << 8);
    const int xcd = flat & 7;
    const int j = flat >> 3;
    const int bxi = j & 7;
    const int yy = (j >> 3) & 3;
    const int bz = j >> 5;
    const int bm = (xcd * 4 + yy) * 128;
    const int bn = bxi * 128;
    const int k0 = bz * KC;
    const int NT = KC / 32;

    const int ar = tid >> 1;
    const int ah = tid & 1;
    const float* aPtr = A + (size_t)(bm + ar) * K + ah * 16;
    const int asw = (ar >> 1) & 3;
    const int ac0 = ((2 * ah) ^ asw) << 3;
    const int ac1 = ((2 * ah + 1) ^ asw) << 3;

    int wrow[2], wlc[2];
#pragma unroll
    for (int i = 0; i < 2; ++i) {
        int c = wv * 2 + i;
        wrow[i] = c * 16 + (lane >> 2);
        wlc[i] = ((lane & 3) ^ ((wrow[i] >> 1) & 3)) * 8;
    }

    const int fr = lane & 15, fq = lane >> 4;
    int ia[4], ib[4];
#pragma unroll
    for (int m = 0; m < 4; ++m) {
        int ra = wr * 64 + m * 16 + fr;
        ia[m] = ra * 32 + ((fq ^ ((ra >> 1) & 3)) << 3);
        int rb = wc * 64 + m * 16 + fr;
        ib[m] = rb * 32 + ((fq ^ ((rb >> 1) & 3)) << 3);
    }

    f32x4 acc[4][4];
#pragma unroll
    for (int m = 0; m < 4; ++m)
#pragma unroll
        for (int n = 0; n < 4; ++n)
            acc[m][n] = (f32x4){0.f, 0.f, 0.f, 0.f};

    auto stage_w = [&](u16* dst, int kk) {
#pragma unroll
        for (int i = 0; i < 2; ++i) {
            const int c = wv * 2 + i;
            const u16* gh = WhT + (size_t)(bn + wrow[i]) * K + kk + wlc[i];
            const u16* gl = WlT + (size_t)(bn + wrow[i]) * K + kk + wlc[i];
            __builtin_amdgcn_global_load_lds(
                (const __attribute__((address_space(1))) u32*)gh,
                (__attribute__((address_space(3))) u32*)(dst + 8192 + c * 512), 16, 0, 0);
            __builtin_amdgcn_global_load_lds(
                (const __attribute__((address_space(1))) u32*)gl,
                (__attribute__((address_space(3))) u32*)(dst + 12288 + c * 512), 16, 0, 0);
        }
    };

    auto split_a = [&](u16* dst, float4 v0, float4 v1, float4 v2, float4 v3) {
        u32 hp[8], lp[8];
        split2(v0.x, v0.y, hp[0], lp[0]);
        split2(v0.z, v0.w, hp[1], lp[1]);
        split2(v1.x, v1.y, hp[2], lp[2]);
        split2(v1.z, v1.w, hp[3], lp[3]);
        split2(v2.x, v2.y, hp[4], lp[4]);
        split2(v2.z, v2.w, hp[5], lp[5]);
        split2(v3.x, v3.y, hp[6], lp[6]);
        split2(v3.z, v3.w, hp[7], lp[7]);
        *(uint4*)&dst[ar * 32 + ac0] = make_uint4(hp[0], hp[1], hp[2], hp[3]);
        *(uint4*)&dst[ar * 32 + ac1] = make_uint4(hp[4], hp[5], hp[6], hp[7]);
        *(uint4*)&dst[4096 + ar * 32 + ac0] = make_uint4(lp[0], lp[1], lp[2], lp[3]);
        *(uint4*)&dst[4096 + ar * 32 + ac1] = make_uint4(lp[4], lp[5], lp[6], lp[7]);
    };

    auto compute = [&](const u16* src) {
        s16x8 fah[4], fal[4], fbh[4], fbl[4];
#pragma unroll
        for (int m = 0; m < 4; ++m) {
            fah[m] = *(const s16x8*)&src[ia[m]];
            fal[m] = *(const s16x8*)&src[4096 + ia[m]];
            fbh[m] = *(const s16x8*)&src[8192 + ib[m]];
            fbl[m] = *(const s16x8*)&src[12288 + ib[m]];
        }
        __builtin_amdgcn_s_setprio(1);
#pragma unroll
        for (int m = 0; m < 4; ++m)
#pragma unroll
            for (int n = 0; n < 4; ++n) {
                acc[m][n] = __builtin_amdgcn_mfma_f32_16x16x32_bf16(fah[m], fbh[n], acc[m][n], 0, 0, 0);
                acc[m][n] = __builtin_amdgcn_mfma_f32_16x16x32_bf16(fah[m], fbl[n], acc[m][n], 0, 0, 0);
                acc[m][n] = __builtin_amdgcn_mfma_f32_16x16x32_bf16(fal[m], fbh[n], acc[m][n], 0, 0, 0);
            }
        __builtin_amdgcn_s_setprio(0);
    };

    u16* bufc = sm;
    u16* bufn = sm + 16384;

    stage_w(bufc, k0);
    {
        float4 a0 = *(const float4*)(aPtr + k0 + 0);
        float4 a1 = *(const float4*)(aPtr + k0 + 4);
        float4 a2 = *(const float4*)(aPtr + k0 + 8);
        float4 a3 = *(const float4*)(aPtr + k0 + 12);
        split_a(bufc, a0, a1, a2, a3);
    }
    asm volatile("s_waitcnt vmcnt(0) lgkmcnt(0)\n\ts_barrier" ::: "memory");

    for (int t = 0; t < NT; ++t) {
        float4 a0{}, a1{}, a2{}, a3{};
        const bool hn = (t + 1 < NT);
        if (hn) {
            const int kk = k0 + (t + 1) * 32;
            stage_w(bufn, kk);
            a0 = *(const float4*)(aPtr + kk + 0);
            a1 = *(const float4*)(aPtr + kk + 4);
            a2 = *(const float4*)(aPtr + kk + 8);
            a3 = *(const float4*)(aPtr + kk + 12);
        }
        compute(bufc);
        if (hn) split_a(bufn, a0, a1, a2, a3);
        asm volatile("s_waitcnt vmcnt(0) lgkmcnt(0)\n\ts_barrier" ::: "memory");
        u16* tmp = bufc; bufc = bufn; bufn = tmp;
    }

    if (bias != nullptr) {
#pragma unroll
        for (int n = 0; n < 4; ++n) {
            int col = bn + wc * 64 + n * 16 + fr;
            float bb = bias[col];
#pragma unroll
            for (int m = 0; m < 4; ++m) {
                int row0 = bm + wr * 64 + m * 16 + fq * 4;
#pragma unroll
                for (int jj = 0; jj < 4; ++jj)
                    Cout[(size_t)(row0 + jj) * Nn + col] = fmaxf(acc[m][n][jj] + bb, 0.0f);
            }
        }
    } else {
        float* Cp = Cout + (size_t)bz * M * Nn;
#pragma unroll
        for (int n = 0; n < 4; ++n) {
            int col = bn + wc * 64 + n * 16 + fr;
#pragma unroll
            for (int m = 0; m < 4; ++m) {
                int row0 = bm + wr * 64 + m * 16 + fq * 4;
#pragma unroll
                for (int jj = 0; jj < 4; ++jj)
                    Cp[(size_t)(row0 + jj) * Nn + col] = acc[m][n][jj];
            }
        }
    }
}

// ============ reduce 4 partials + bias + relu (fp32 out, fallback) ============
__global__ __launch_bounds__(256) void reduce_bias_relu(
    const float* __restrict__ Cpart, const float* __restrict__ bias,
    float* __restrict__ X, int MN, int Nn)
{
    const int total = MN / 4;
    for (int i4 = blockIdx.x * 256 + threadIdx.x; i4 < total; i4 += gridDim.x * 256) {
        const size_t o = (size_t)i4 * 4;
        float4 a = *(const float4*)(Cpart + o);
        float4 b = *(const float4*)(Cpart + (size_t)MN + o);
        float4 c = *(const float4*)(Cpart + 2 * (size_t)MN + o);
        float4 d = *(const float4*)(Cpart + 3 * (size_t)MN + o);
        float4 bb = *(const float4*)(bias + (o & (size_t)(Nn - 1)));
        float4 r;
        r.x = fmaxf(a.x + b.x + c.x + d.x + bb.x, 0.0f);
        r.y = fmaxf(a.y + b.y + c.y + d.y + bb.y, 0.0f);
        r.z = fmaxf(a.z + b.z + c.z + d.z + bb.z, 0.0f);
        r.w = fmaxf(a.w + b.w + c.w + d.w + bb.w, 0.0f);
        *(float4*)(X + o) = r;
    }
}

// ============ reduce 2 partials + bias + relu (fp32 out, fc7 split-K) ============
__global__ __launch_bounds__(256) void reduce2_bias_relu(
    const float* __restrict__ Cpart, const float* __restrict__ bias,
    float* __restrict__ X, int MN, int Nn)
{
    const int total = MN / 4;
    for (int i4 = blockIdx.x * 256 + threadIdx.x; i4 < total; i4 += gridDim.x * 256) {
        const size_t o = (size_t)i4 * 4;
        float4 a = *(const float4*)(Cpart + o);
        float4 b = *(const float4*)(Cpart + (size_t)MN + o);
        float4 bb = *(const float4*)(bias + (o & (size_t)(Nn - 1)));
        float4 r;
        r.x = fmaxf(a.x + b.x + bb.x, 0.0f);
        r.y = fmaxf(a.y + b.y + bb.y, 0.0f);
        r.z = fmaxf(a.z + b.z + bb.z, 0.0f);
        r.w = fmaxf(a.w + b.w + bb.w, 0.0f);
        *(float4*)(X + o) = r;
    }
}

// ============ reduce 4 partials + bias + relu, emit tiled split bf16 ============
__global__ __launch_bounds__(256) void reduce_split_tiled(
    const float* __restrict__ Cpart, const float* __restrict__ bias,
    u16* __restrict__ Xh, u16* __restrict__ Xl, int MN, int Nn)
{
    const int total = MN / 8;
    for (int i = blockIdx.x * 256 + threadIdx.x; i < total; i += gridDim.x * 256) {
        const size_t o = (size_t)i * 8;
        float r8[8];
#pragma unroll
        for (int h = 0; h < 2; ++h) {
            float4 a = *(const float4*)(Cpart + o + h * 4);
            float4 b = *(const float4*)(Cpart + (size_t)MN + o + h * 4);
            float4 c = *(const float4*)(Cpart + 2 * (size_t)MN + o + h * 4);
            float4 d = *(const float4*)(Cpart + 3 * (size_t)MN + o + h * 4);
            float4 bb = *(const float4*)(bias + ((o + h * 4) & (size_t)(Nn - 1)));
            r8[h * 4 + 0] = fmaxf(a.x + b.x + c.x + d.x + bb.x, 0.0f);
            r8[h * 4 + 1] = fmaxf(a.y + b.y + c.y + d.y + bb.y, 0.0f);
            r8[h * 4 + 2] = fmaxf(a.z + b.z + c.z + d.z + bb.z, 0.0f);
            r8[h * 4 + 3] = fmaxf(a.w + b.w + c.w + d.w + bb.w, 0.0f);
        }
        u32 hp[4], lp[4];
#pragma unroll
        for (int t2 = 0; t2 < 4; ++t2)
            split2(r8[2 * t2], r8[2 * t2 + 1], hp[t2], lp[t2]);
        int row = (int)(o >> 10);                 // Nn == 1024
        int rem = (int)(o & 1023);
        int t = rem >> 5, g = (rem >> 3) & 3;
        size_t dsto = tile_off(row >> 7, 32, t, row, g);
        *(uint4*)&Xh[dsto] = make_uint4(hp[0], hp[1], hp[2], hp[3]);
        *(uint4*)&Xl[dsto] = make_uint4(lp[0], lp[1], lp[2], lp[3]);
    }
}

// ============ fused heads GEMM + postproc (16 rows/block, fp32 exact) ========
__global__ __launch_bounds__(256) void heads_postproc(
    const float* __restrict__ X2, const float* __restrict__ Wcat,
    const float* __restrict__ cls_b, const float* __restrict__ box_b,
    const float* __restrict__ proposals,
    float* __restrict__ bxo, float* __restrict__ sco,
    int* __restrict__ lbo, int* __restrict__ vdo)
{
    __shared__ float Xs[16][36];
    __shared__ float Ws[32 * NCOL];
    __shared__ float lgs[16][NCOL];
    const int tid = threadIdx.x;
    const int m0 = blockIdx.x * 16;
    const int tr = tid >> 4;            // 16 rows
    const int tc = tid & 15;            // 16 col-groups x 7
    float acc[7] = {};
    for (int k0 = 0; k0 < HID; k0 += 32) {
        if (tid < 128) {
            int i = tid >> 3, j4 = (tid & 7) * 4;
            float4 v = *(const float4*)(X2 + (size_t)(m0 + i) * HID + k0 + j4);
            Xs[i][j4] = v.x; Xs[i][j4 + 1] = v.y; Xs[i][j4 + 2] = v.z; Xs[i][j4 + 3] = v.w;
        }
        const float4* src = (const float4*)(Wcat + (size_t)k0 * NCOL);
        float4* dst = (float4*)Ws;
        for (int i4 = tid; i4 < (32 * NCOL) / 4; i4 += 256) dst[i4] = src[i4];
        __syncthreads();
#pragma unroll 4
        for (int kk = 0; kk < 32; ++kk) {
            float a0 = Xs[tr][kk];
#pragma unroll
            for (int j = 0; j < 7; ++j)
                acc[j] = fmaf(a0, Ws[kk * NCOL + tc * 7 + j], acc[j]);
        }
        __syncthreads();
    }
#pragma unroll
    for (int j = 0; j < 7; ++j)
        lgs[tr][tc * 7 + j] = acc[j];
    __syncthreads();

    if (tid < 16) {
        const int p = m0 + tid;
        const float* lg = lgs[tid];
        float l[21];
        float m = -1e30f;
#pragma unroll
        for (int c = 0; c < 21; ++c) { l[c] = lg[c] + cls_b[c]; m = fmaxf(m, l[c]); }
        float e[21]; float s = 0.0f;
#pragma unroll
        for (int c = 0; c < 21; ++c) { e[c] = expf(l[c] - m); s += e[c]; }
        int best = 1;
#pragma unroll
        for (int c = 2; c < 21; ++c) if (e[c] > e[best]) best = c;
        const float score = e[best] / s;

        float d0 = (lg[21 + best * 4 + 0] + box_b[best * 4 + 0]) * 0.1f;
        float d1 = (lg[21 + best * 4 + 1] + box_b[best * 4 + 1]) * 0.1f;
        float d2 = (lg[21 + best * 4 + 2] + box_b[best * 4 + 2]) * 0.2f;
        float d3 = (lg[21 + best * 4 + 3] + box_b[best * 4 + 3]) * 0.2f;
        const float* pr = proposals + p * 4;
        float w_ = pr[2] - pr[0], h_ = pr[3] - pr[1];
        float cx = pr[0] + 0.5f * w_, cy = pr[1] + 0.5f * h_;
        float pcx = d0 * w_ + cx, pcy = d1 * h_ + cy;
        float pw = expf(d2) * w_, ph = expf(d3) * h_;
        float b0 = pcx - 0.5f * pw, b1 = pcy - 0.5f * ph;
        float b2 = pcx + 0.5f * pw, b3 = pcy + 0.5f * ph;
        b0 = fminf(fmaxf(b0, 0.0f), IMG);
        b1 = fminf(fmaxf(b1, 0.0f), IMG);
        b2 = fminf(fmaxf(b2, 0.0f), IMG);
        b3 = fminf(fmaxf(b3, 0.0f), IMG);
        int vd = (b2 - b0 > 0.0f) && (b3 - b1 > 0.0f) && (score > SCORE_THRESH);
        bxo[p * 4 + 0] = b0; bxo[p * 4 + 1] = b1;
        bxo[p * 4 + 2] = b2; bxo[p * 4 + 3] = b3;
        sco[p] = score;
        lbo[p] = best;
        vdo[p] = vd;
    }
}

// ============ fused NMS + finalize: ballot mask build + pipelined scan ============
__global__ __launch_bounds__(1024) void nms_finalize(
    const float* __restrict__ bx, const float* __restrict__ sc,
    const int* __restrict__ label, const int* __restrict__ valid,
    const float* __restrict__ proposals, float* __restrict__ out)
{
    const int img = blockIdx.x;
    const int base = img * NPROP;
    const int tid = threadIdx.x;
    const int lane = tid & 63;
    const int wv = tid >> 6;                // 16 waves

    __shared__ u64 maskm[NPROP][16];        // 128 KB (aliases sort keys)
    __shared__ float4 sbx[NPROP];           // 16 KB
    __shared__ float sarea[NPROP];          // 4 KB
    __shared__ u64 kword[16];
    __shared__ int nv;

    u64* skey = &maskm[0][0];               // alias (dead before mask build)

    if (tid == 0) nv = 0;

    // key: ascending <=> (score desc, index asc) — stable argsort(-sc)
    {
        float s = valid[base + tid] ? sc[base + tid] : -1.0f;
        unsigned u = __float_as_uint(s);
        u = (u & 0x80000000u) ? ~u : (u | 0x80000000u);
        u = ~u;
        skey[tid] = ((u64)u << 32) | (unsigned)tid;
    }
    for (int k = 2; k <= NPROP; k <<= 1) {
        for (int j = k >> 1; j > 0; j >>= 1) {
            __syncthreads();
            int ixj = tid ^ j;
            if (ixj > tid) {
                u64 a = skey[tid], b = skey[ixj];
                bool up = ((tid & k) == 0);
                if (up ? (a > b) : (a < b)) { skey[tid] = b; skey[ixj] = a; }
            }
        }
    }
    __syncthreads();

    // sorted order; offset boxes (reference arithmetic); kword via per-wave ballot
    const int myp = (int)(skey[tid] & 0xffffffffu);
    {
        float off = (float)label[base + myp] * (IMG + 1.0f);
        float x0 = bx[(base + myp) * 4 + 0] + off;
        float y0 = bx[(base + myp) * 4 + 1] + off;
        float x1 = bx[(base + myp) * 4 + 2] + off;
        float y1 = bx[(base + myp) * 4 + 3] + off;
        sbx[tid] = make_float4(x0, y0, x1, y1);
        sarea[tid] = (x1 - x0) * (y1 - y0);
        int v = valid[base + myp];
        u64 bb = __ballot(v != 0);           // wave wv covers exactly word wv
        if (lane == 0) kword[wv] = bb;
        if (v) atomicMax(&nv, tid + 1);      // valids sort to the front
    }
    __syncthreads();
    const int nvalid = nv;

    // ballot mask build: wave owns row i; lane handles j = w*64 + lane.
    for (int i = wv; i < nvalid; i += 16) {
        const float4 bi = sbx[i];
        const float ai = sarea[i];
#pragma unroll 4
        for (int w = 0; w < 16; ++w) {
            const int j = w * 64 + lane;
            bool sup = false;
            if (j > i && j < nvalid) {
                float4 bj = sbx[j];
                float lt0 = fmaxf(bi.x, bj.x);
                float lt1 = fmaxf(bi.y, bj.y);
                float rb0 = fminf(bi.z, bj.z);
                float rb1 = fminf(bi.w, bj.w);
                float w_ = fmaxf(rb0 - lt0, 0.0f);
                float h_ = fmaxf(rb1 - lt1, 0.0f);
                float inter = w_ * h_;
                float denom = fmaxf(ai + sarea[j] - inter, 1e-9f);
                sup = inter / denom > NMS_THRESH;
            }
            u64 bits = __ballot(sup);
            if (lane == 0) maskm[i][w] = bits;
        }
    }
    __syncthreads();

    // serial greedy scan — single wave, depth-4 row prefetch (named regs, rule #20)
    if (tid < 64) {
        u64 kw = (tid < 16) ? kword[tid] : 0ull;
        u64 ra = 0, rb = 0, rc = 0, rd = 0;
        if (tid < 16) {
            if (0 < nvalid) ra = maskm[0][tid];
            if (1 < nvalid) rb = maskm[1][tid];
            if (2 < nvalid) rc = maskm[2][tid];
            if (3 < nvalid) rd = maskm[3][tid];
        }
        for (int i = 0; i < nvalid; i += 4) {
            {
                u64 srcw = __shfl(kw, i >> 6, 64);
                if ((srcw >> (i & 63)) & 1ull) { if (tid < 16) kw &= ~ra; }
                if (tid < 16 && i + 4 < nvalid) ra = maskm[i + 4][tid];
            }
            if (i + 1 < nvalid) {
                u64 srcw = __shfl(kw, (i + 1) >> 6, 64);
                if ((srcw >> ((i + 1) & 63)) & 1ull) { if (tid < 16) kw &= ~rb; }
                if (tid < 16 && i + 5 < nvalid) rb = maskm[i + 5][tid];
            }
            if (i + 2 < nvalid) {
                u64 srcw = __shfl(kw, (i + 2) >> 6, 64);
                if ((srcw >> ((i + 2) & 63)) & 1ull) { if (tid < 16) kw &= ~rc; }
                if (tid < 16 && i + 6 < nvalid) rc = maskm[i + 6][tid];
            }
            if (i + 3 < nvalid) {
                u64 srcw = __shfl(kw, (i + 3) >> 6, 64);
                if ((srcw >> ((i + 3) & 63)) & 1ull) { if (tid < 16) kw &= ~rd; }
                if (tid < 16 && i + 7 < nvalid) rd = maskm[i + 7][tid];
            }
        }
        if (tid < 16) kword[tid] = kw;
    }
    __syncthreads();

    // fused finalize: thread tid owns original proposal (base + myp)
    {
        const int p = base + myp;
        const bool k = ((kword[tid >> 6] >> (tid & 63)) & 1ull) != 0;
        float* res   = out;
        float* keepo = out + NPB * 6;
        float* rpn   = keepo + NPB;
        float* rcnn  = rpn + NPB * 6;
        float b0 = bx[p * 4 + 0], b1 = bx[p * 4 + 1];
        float b2 = bx[p * 4 + 2], b3 = bx[p * 4 + 3];
        res[p * 6 + 0] = k ? b0 : 0.0f;
        res[p * 6 + 1] = k ? b1 : 0.0f;
        res[p * 6 + 2] = k ? b2 : 0.0f;
        res[p * 6 + 3] = k ? b3 : 0.0f;
        res[p * 6 + 4] = k ? (float)(label[p] - 1) : 0.0f;
        res[p * 6 + 5] = k ? sc[p] : 0.0f;
        keepo[p] = k ? 1.0f : 0.0f;
        rpn[p * 6 + 0] = proposals[p * 4 + 0];
        rpn[p * 6 + 1] = proposals[p * 4 + 1];
        rpn[p * 6 + 2] = proposals[p * 4 + 2];
        rpn[p * 6 + 3] = proposals[p * 4 + 3];
        rpn[p * 6 + 4] = 0.0f;
        rpn[p * 6 + 5] = 0.0f;
        rcnn[p * 6 + 0] = b0;
        rcnn[p * 6 + 1] = b1;
        rcnn[p * 6 + 2] = b2;
        rcnn[p * 6 + 3] = b3;
        rcnn[p * 6 + 4] = 0.0f;
        rcnn[p * 6 + 5] = 0.0f;
    }
}

// ============ launch ============
extern "C" void kernel_launch(void* const* d_in, const int* in_sizes, int n_in,
                              void* d_out, int out_size, void* d_ws, size_t ws_size,
                              hipStream_t stream)
{
    const float* props_feature = (const float*)d_in[0];
    const float* proposals     = (const float*)d_in[1];
    const float* fc6_w         = (const float*)d_in[2];
    const float* fc6_b         = (const float*)d_in[3];
    const float* fc7_w         = (const float*)d_in[4];
    const float* fc7_b         = (const float*)d_in[5];
    const float* cls_w         = (const float*)d_in[6];
    const float* cls_b         = (const float*)d_in[7];
    const float* box_w         = (const float*)d_in[8];
    const float* box_b         = (const float*)d_in[9];
    float* out = (float*)d_out;

    char* ws = (char*)d_ws;
    float* X1     = (float*)(ws);                                  // 16 MB (fallbacks)
    float* X2     = (float*)(ws + 16777216);                       // 16 MB
    float* Wcat   = (float*)(ws + 33554432);
    float* bx     = (float*)(ws + 35848192);
    float* sc     = (float*)(ws + 35913728);
    int*   label  = (int*)  (ws + 35930112);
    int*   valid  = (int*)  (ws + 35946496);
    u16*   W6h    = (u16*)  (ws + 35979264);                       // 24.5 MB
    u16*   W6l    = (u16*)  (ws + 61669376);                       // 24.5 MB
    u16*   W7h    = (u16*)  (ws + 87359488);                       // 2 MB
    u16*   W7l    = (u16*)  (ws + 89456640);                       // 2 MB
    float* Cpart  = (float*)(ws + 91553792);                       // 64 MB
    u16*   A6h    = (u16*)  (ws + 158662656);                      // 98 MB (tiled)
    u16*   A6l    = (u16*)  (ws + 261423104);                      // 98 MB
    u16*   X1h    = (u16*)  (ws + 364183552);                      // 8 MB (tiled)
    u16*   X1l    = (u16*)  (ws + 372572160);                      // 8 MB
    const size_t NEED_SK   = 158662656ull;
    const size_t NEED_FULL = 380960768ull;

    if (ws_size >= NEED_FULL) {
        prep_kernel<<<NB_PREP, 256, 0, stream>>>(
            fc6_w, fc7_w, cls_w, box_w, props_feature,
            W6h, W6l, W7h, W7l, Wcat, A6h, A6l);
        // fc6: merged single dispatch (1024 blocks, 4 blocks/CU potential)
        gemm_2ph_tiled<<<dim3(8, 32, 4), 256, 0, stream>>>(
            A6h, A6l, W6h, W6l, nullptr, Cpart, NPB, HID, FEAT_DIM / 32, FEAT_DIM / 128,
            0, 3, 5);
        reduce_split_tiled<<<1024, 256, 0, stream>>>(
            Cpart, fc6_b, X1h, X1l, NPB * HID, HID);
        // fc7: split-K x2 (512 blocks = 2 blocks/CU), partials -> Cpart
        gemm_2ph_tiled<<<dim3(8, 32, 2), 256, 0, stream>>>(
            X1h, X1l, W7h, W7l, nullptr, Cpart, NPB, HID, HID / 32, HID / 64,
            0, 3, 5);
        reduce2_bias_relu<<<1024, 256, 0, stream>>>(
            Cpart, fc7_b, X2, NPB * HID, HID);
    } else if (ws_size >= NEED_SK) {
        build_wcat<<<(HID * NCOL + 255) / 256, 256, 0, stream>>>(cls_w, box_w, Wcat);
        transpose_split<<<dim3(HID / 32, FEAT_DIM / 32), 256, 0, stream>>>(
            fc6_w, W6h, W6l, FEAT_DIM, HID);
        transpose_split<<<dim3(HID / 32, HID / 32), 256, 0, stream>>>(
            fc7_w, W7h, W7l, HID, HID);
        gemm_2ph<<<dim3(8, 32, 4), 256, 0, stream>>>(
            props_feature, W6h, W6l, nullptr, Cpart, NPB, HID, FEAT_DIM, FEAT_DIM / 4);
        reduce_bias_relu<<<1024, 256, 0, stream>>>(Cpart, fc6_b, X1, NPB * HID, HID);
        gemm_2ph<<<dim3(8, 32, 1), 256, 0, stream>>>(
            X1, W7h, W7l, fc7_b, X2, NPB, HID, HID, HID);
    } else {
        build_wcat<<<(HID * NCOL + 255) / 256, 256, 0, stream>>>(cls_w, box_w, Wcat);
        transpose_split<<<dim3(HID / 32, FEAT_DIM / 32), 256, 0, stream>>>(
            fc6_w, W6h, W6l, FEAT_DIM, HID);
        transpose_split<<<dim3(HID / 32, HID / 32), 256, 0, stream>>>(
            fc7_w, W7h, W7l, HID, HID);
        gemm_2ph<<<dim3(8, 32, 1), 256, 0, stream>>>(
            props_feature, W6h, W6l, fc6_b, X1, NPB, HID, FEAT_DIM, FEAT_DIM);
        gemm_2ph<<<dim3(8, 32, 1), 256, 0, stream>>>(
            X1, W7h, W7l, fc7_b, X2, NPB, HID, HID, HID);
    }

    heads_postproc<<<NPB / 16, 256, 0, stream>>>(
        X2, Wcat, cls_b, box_b, proposals, bx, sc, label, valid);

    nms_finalize<<<BATCH, 1024, 0, stream>>>(bx, sc, label, valid, proposals, out);
}

// Round 19
// 641.399 us; speedup vs baseline: 1.1574x; 1.0034x over previous
//
#include <hip/hip_runtime.h>
#include <hip/hip_bf16.h>

// Problem constants (from reference)
#define BATCH 4
#define NPROP 1024
#define HID 1024
#define NUM_CLASSES 21
#define FEAT_DIM 12544
#define NPB (BATCH * NPROP)             // 4096
#define IMG 800.0f
#define SCORE_THRESH 0.1f
#define NMS_THRESH 0.5f
#define NCOL 112                        // padded 21+84

typedef unsigned short u16;
typedef unsigned int u32;
typedef unsigned long long u64;
typedef short s16x8 __attribute__((ext_vector_type(8)));
typedef float f32x4 __attribute__((ext_vector_type(4)));

// hi/lo split of 2 floats via native RTNE bf16 converts (v_cvt_pk_bf16_f32).
__device__ __forceinline__ void split2(float x0, float x1, u32& hp, u32& lp) {
    __hip_bfloat162 h2 = __float22bfloat162_rn(make_float2(x0, x1));
    u32 h = *(u32*)&h2;
    float f0 = __uint_as_float(h << 16);
    float f1 = __uint_as_float(h & 0xffff0000u);
    __hip_bfloat162 l2 = __float22bfloat162_rn(make_float2(x0 - f0, x1 - f1));
    hp = h;
    lp = *(u32*)&l2;
}

// Tiled layout (LDS-image order, swizzle baked in):
//   T[blk][t][c(8)][lane(64)][8 u16], flat u16 off = ((blk*NTt + t)*8 + c)*512 + lane*8
__device__ __forceinline__ size_t tile_off(int blk, int NTt, int t, int row, int g) {
    int r = row & 127;
    int c = r >> 4;
    int lanei = ((r & 15) << 2) | (g ^ ((r >> 1) & 3));
    return ((((size_t)blk * NTt + t) * 8 + c) << 9) + lanei * 8;
}

// ============ fused prep kernel (all global R/W full-line coalesced) ============
#define NB_WCAT 448
#define NB_T7C  256          // 8 nb x 32 t
#define NB_T6C  3136         // 8 nb x 392 t
#define NB_SPA  2048
#define NB_PREP (NB_WCAT + NB_T7C + NB_T6C + NB_SPA)

// one block per (nb, t): stage W[t*32..+32][nb*128..+128] via LDS, emit 8 chunks
__device__ __forceinline__ void w_chunks(
    const float* __restrict__ W, u16* __restrict__ Th, u16* __restrict__ Tl,
    int NTt, int nb, int t, int tid, float (*lt)[129])
{
    const int n0 = nb * 128;
#pragma unroll
    for (int p = 0; p < 4; ++p) {
        int e = (p * 256 + tid) * 4;            // 0..4095 step 4
        int k = e >> 7;                          // tile row (k) 0..31
        int n = e & 127;                         // tile col (n)
        float4 v = *(const float4*)(W + (size_t)(t * 32 + k) * 1024 + n0 + n);
        lt[k][n] = v.x; lt[k][n + 1] = v.y; lt[k][n + 2] = v.z; lt[k][n + 3] = v.w;
    }
    __syncthreads();
    const int lane = tid & 63, w = tid >> 6;
#pragma unroll
    for (int i = 0; i < 2; ++i) {
        const int c = w * 2 + i;
        const int rl = c * 16 + (lane >> 2);            // local row (n) 0..127
        const int q = (lane & 3) ^ ((rl >> 1) & 3);     // content k-group
        u32 hp[4], lp[4];
#pragma unroll
        for (int e2 = 0; e2 < 4; ++e2)
            split2(lt[q * 8 + 2 * e2][rl], lt[q * 8 + 2 * e2 + 1][rl], hp[e2], lp[e2]);
        const size_t dsto = ((((size_t)nb * NTt + t) * 8 + c) << 9) + lane * 8;
        *(uint4*)&Th[dsto] = make_uint4(hp[0], hp[1], hp[2], hp[3]);
        *(uint4*)&Tl[dsto] = make_uint4(lp[0], lp[1], lp[2], lp[3]);
    }
    __syncthreads();
}

__global__ __launch_bounds__(256) void prep_kernel(
    const float* __restrict__ fc6_w, const float* __restrict__ fc7_w,
    const float* __restrict__ cls_w, const float* __restrict__ box_w,
    const float* __restrict__ A,
    u16* __restrict__ W6h, u16* __restrict__ W6l,
    u16* __restrict__ W7h, u16* __restrict__ W7l,
    float* __restrict__ Wcat, u16* __restrict__ A6h, u16* __restrict__ A6l)
{
    __shared__ float lt[32][129];
    const int b = blockIdx.x;
    const int tid = threadIdx.x;

    if (b < NB_WCAT) {
        int i = b * 256 + tid;
        if (i < HID * NCOL) {
            int k = i / NCOL, c = i % NCOL;
            float v = 0.0f;
            if (c < 21) v = cls_w[k * 21 + c];
            else if (c < 105) v = box_w[k * 84 + (c - 21)];
            Wcat[i] = v;
        }
    } else if (b < NB_WCAT + NB_T7C) {
        int idx = b - NB_WCAT;                  // 8 nb x 32 t
        w_chunks(fc7_w, W7h, W7l, 32, idx / 32, idx % 32, tid, lt);
    } else if (b < NB_WCAT + NB_T7C + NB_T6C) {
        int idx = b - NB_WCAT - NB_T7C;         // 8 nb x 392 t
        w_chunks(fc6_w, W6h, W6l, 392, idx / 392, idx % 392, tid, lt);
    } else {
        // A chunk-gather, depth-4 software pipeline (8 loads in flight per wave).
        const int sb = b - NB_WCAT - NB_T7C - NB_T6C;   // 0..2047
        const int lane = tid & 63;
        const int w = tid >> 6;
        const int NCH = (NPB / 128) * (FEAT_DIM / 32) * 8;   // 100352
        const int STRIDE = NB_SPA * 4;                        // 8192
        const int STRIDE4 = STRIDE * 4;                       // 32768

        auto srcaddr = [&](int ch) -> const float* {
            const int c = ch & 7;
            const int tmp = ch >> 3;
            const int t = tmp % (FEAT_DIM / 32);
            const int blk = tmp / (FEAT_DIM / 32);
            const int r = blk * 128 + c * 16 + (lane >> 2);
            const int col = t * 32 + (((lane & 3) ^ ((r >> 1) & 3)) << 3);
            return A + (size_t)r * FEAT_DIM + col;
        };
        auto proc = [&](int ch, const float4& xx, const float4& yy) {
            u32 hp0, hp1, hp2, hp3, lp0, lp1, lp2, lp3;
            split2(xx.x, xx.y, hp0, lp0);
            split2(xx.z, xx.w, hp1, lp1);
            split2(yy.x, yy.y, hp2, lp2);
            split2(yy.z, yy.w, hp3, lp3);
            const size_t dsto = ((size_t)ch << 9) + lane * 8;
            *(uint4*)&A6h[dsto] = make_uint4(hp0, hp1, hp2, hp3);
            *(uint4*)&A6l[dsto] = make_uint4(lp0, lp1, lp2, lp3);
        };

        int c0 = sb * 4 + w;
        int c1 = c0 + STRIDE;
        int c2 = c1 + STRIDE;
        int c3 = c2 + STRIDE;
        float4 x0{}, y0{}, x1{}, y1{}, x2{}, y2{}, x3{}, y3{};
        { const float* s = srcaddr(c0); x0 = *(const float4*)s; y0 = *(const float4*)(s + 4); }
        { const float* s = srcaddr(c1); x1 = *(const float4*)s; y1 = *(const float4*)(s + 4); }
        { const float* s = srcaddr(c2); x2 = *(const float4*)s; y2 = *(const float4*)(s + 4); }
        { const float* s = srcaddr(c3); x3 = *(const float4*)s; y3 = *(const float4*)(s + 4); }

        while (c0 < NCH || c1 < NCH || c2 < NCH || c3 < NCH) {
            if (c0 < NCH) {
                proc(c0, x0, y0);
                c0 += STRIDE4;
                if (c0 < NCH) { const float* s = srcaddr(c0); x0 = *(const float4*)s; y0 = *(const float4*)(s + 4); }
            }
            if (c1 < NCH) {
                proc(c1, x1, y1);
                c1 += STRIDE4;
                if (c1 < NCH) { const float* s = srcaddr(c1); x1 = *(const float4*)s; y1 = *(const float4*)(s + 4); }
            }
            if (c2 < NCH) {
                proc(c2, x2, y2);
                c2 += STRIDE4;
                if (c2 < NCH) { const float* s = srcaddr(c2); x2 = *(const float4*)s; y2 = *(const float4*)(s + 4); }
            }
            if (c3 < NCH) {
                proc(c3, x3, y3);
                c3 += STRIDE4;
                if (c3 < NCH) { const float* s = srcaddr(c3); x3 = *(const float4*)s; y3 = *(const float4*)(s + 4); }
            }
        }
    }
}

// ============ linear transpose+split (fallback paths) ============
__global__ __launch_bounds__(256) void transpose_split(
    const float* __restrict__ W, u16* __restrict__ WhT, u16* __restrict__ WlT,
    int K, int N)
{
    __shared__ float tile[32][33];
    const int tid = threadIdx.x;
    const int n0 = blockIdx.x * 32;
    const int k0 = blockIdx.y * 32;
    {
        int i = tid >> 3, j4 = (tid & 7) * 4;
        float4 v = *(const float4*)(W + (size_t)(k0 + i) * N + n0 + j4);
        tile[i][j4] = v.x; tile[i][j4 + 1] = v.y; tile[i][j4 + 2] = v.z; tile[i][j4 + 3] = v.w;
    }
    __syncthreads();
    {
        int i = tid >> 3, j4 = (tid & 7) * 4;
        u32 hp0, lp0, hp1, lp1;
        split2(tile[j4 + 0][i], tile[j4 + 1][i], hp0, lp0);
        split2(tile[j4 + 2][i], tile[j4 + 3][i], hp1, lp1);
        size_t o = (size_t)(n0 + i) * K + k0 + j4;
        *(uint2*)&WhT[o] = make_uint2(hp0, hp1);
        *(uint2*)&WlT[o] = make_uint2(lp0, lp1);
    }
}

// ============ concat cls_w | box_w (fallback paths) ============
__global__ void build_wcat(const float* __restrict__ cls_w, const float* __restrict__ box_w,
                           float* __restrict__ Wcat)
{
    int i = blockIdx.x * 256 + threadIdx.x;
    if (i >= HID * NCOL) return;
    int k = i / NCOL, c = i % NCOL;
    float v = 0.0f;
    if (c < 21) v = cls_w[k * 21 + c];
    else if (c < 105) v = box_w[k * 84 + (c - 21)];
    Wcat[i] = v;
}

// ============ tiled 2-phase GEMM: pure contiguous global_load_lds staging ========
// Generalized swizzle: mb = mb0 + xcd*(ymask+1) + yy, bz = j>>bzshift.
__global__ __launch_bounds__(256) void gemm_2ph_tiled(
    const u16* __restrict__ Ah, const u16* __restrict__ Al,
    const u16* __restrict__ Wh, const u16* __restrict__ Wl,
    const float* __restrict__ bias, float* __restrict__ Cout,
    int M, int Nn, int NTt, int tN, int mb0, int ymask, int bzshift)
{
    __shared__ u16 sm[2 * 16384];

    const int tid = threadIdx.x;
    const int lane = tid & 63;
    const int wv = tid >> 6;
    const int wr = wv >> 1, wc = wv & 1;

    const int flat = blockIdx.x + (blockIdx.y << 3) + blockIdx.z * 8 * gridDim.y;
    const int xcd = flat & 7;
    const int j = flat >> 3;
    const int bxi = j & 7;
    const int yy = (j >> 3) & ymask;
    const int bz = j >> bzshift;
    const int mb = mb0 + xcd * (ymask + 1) + yy;
    const int nb = bxi;
    const int bm = mb * 128, bn = nb * 128;
    const int t0 = bz * tN;

    const size_t abase = (size_t)mb * NTt * 4096;
    const size_t wbase = (size_t)nb * NTt * 4096;

    const int fr = lane & 15, fq = lane >> 4;
    int ia[4], ib[4];
#pragma unroll
    for (int m = 0; m < 4; ++m) {
        int ra = wr * 64 + m * 16 + fr;
        ia[m] = ra * 32 + ((fq ^ ((ra >> 1) & 3)) << 3);
        int rb = wc * 64 + m * 16 + fr;
        ib[m] = rb * 32 + ((fq ^ ((rb >> 1) & 3)) << 3);
    }

    f32x4 acc[4][4];
#pragma unroll
    for (int m = 0; m < 4; ++m)
#pragma unroll
        for (int n = 0; n < 4; ++n)
            acc[m][n] = (f32x4){0.f, 0.f, 0.f, 0.f};

    auto stage = [&](u16* dst, int t) {
#pragma unroll
        for (int i = 0; i < 2; ++i) {
            const int c = wv * 2 + i;
            const size_t so = (((size_t)t * 8 + c) << 9) + lane * 8;
            __builtin_amdgcn_global_load_lds(
                (const __attribute__((address_space(1))) u32*)(Ah + abase + so),
                (__attribute__((address_space(3))) u32*)(dst + c * 512), 16, 0, 0);
            __builtin_amdgcn_global_load_lds(
                (const __attribute__((address_space(1))) u32*)(Al + abase + so),
                (__attribute__((address_space(3))) u32*)(dst + 4096 + c * 512), 16, 0, 0);
            __builtin_amdgcn_global_load_lds(
                (const __attribute__((address_space(1))) u32*)(Wh + wbase + so),
                (__attribute__((address_space(3))) u32*)(dst + 8192 + c * 512), 16, 0, 0);
            __builtin_amdgcn_global_load_lds(
                (const __attribute__((address_space(1))) u32*)(Wl + wbase + so),
                (__attribute__((address_space(3))) u32*)(dst + 12288 + c * 512), 16, 0, 0);
        }
    };

    auto compute = [&](const u16* src) {
        s16x8 fah[4], fal[4], fbh[4], fbl[4];
#pragma unroll
        for (int m = 0; m < 4; ++m) {
            fah[m] = *(const s16x8*)&src[ia[m]];
            fal[m] = *(const s16x8*)&src[4096 + ia[m]];
            fbh[m] = *(const s16x8*)&src[8192 + ib[m]];
            fbl[m] = *(const s16x8*)&src[12288 + ib[m]];
        }
        __builtin_amdgcn_s_setprio(1);
#pragma unroll
        for (int m = 0; m < 4; ++m)
#pragma unroll
            for (int n = 0; n < 4; ++n) {
                acc[m][n] = __builtin_amdgcn_mfma_f32_16x16x32_bf16(fah[m], fbh[n], acc[m][n], 0, 0, 0);
                acc[m][n] = __builtin_amdgcn_mfma_f32_16x16x32_bf16(fah[m], fbl[n], acc[m][n], 0, 0, 0);
                acc[m][n] = __builtin_amdgcn_mfma_f32_16x16x32_bf16(fal[m], fbh[n], acc[m][n], 0, 0, 0);
            }
        __builtin_amdgcn_s_setprio(0);
    };

    u16* bufc = sm;
    u16* bufn = sm + 16384;

    stage(bufc, t0);
    for (int t = 0; t < tN; ++t) {
        if (t + 1 < tN) {
            stage(bufn, t0 + t + 1);
            asm volatile("s_waitcnt vmcnt(8)" ::: "memory");
        } else {
            asm volatile("s_waitcnt vmcnt(0)" ::: "memory");
        }
        asm volatile("s_barrier" ::: "memory");
        compute(bufc);
        asm volatile("s_barrier" ::: "memory");
        u16* tmp = bufc; bufc = bufn; bufn = tmp;
    }

    if (bias != nullptr) {
#pragma unroll
        for (int n = 0; n < 4; ++n) {
            int col = bn + wc * 64 + n * 16 + fr;
            float bb = bias[col];
#pragma unroll
            for (int m = 0; m < 4; ++m) {
                int row0 = bm + wr * 64 + m * 16 + fq * 4;
#pragma unroll
                for (int jj = 0; jj < 4; ++jj)
                    Cout[(size_t)(row0 + jj) * Nn + col] = fmaxf(acc[m][n][jj] + bb, 0.0f);
            }
        }
    } else {
        float* Cp = Cout + (size_t)bz * M * Nn;
#pragma unroll
        for (int n = 0; n < 4; ++n) {
            int col = bn + wc * 64 + n * 16 + fr;
#pragma unroll
            for (int m = 0; m < 4; ++m) {
                int row0 = bm + wr * 64 + m * 16 + fq * 4;
#pragma unroll
                for (int jj = 0; jj < 4; ++jj)
                    Cp[(size_t)(row0 + jj) * Nn + col] = acc[m][n][jj];
            }
        }
    }
}

// ============ round-7 2-phase GEMM (in-loop A split) — fallback ============
__global__ __launch_bounds__(256) void gemm_2ph(
    const float* __restrict__ A, const u16* __restrict__ WhT, const u16* __restrict__ WlT,
    const float* __restrict__ bias, float* __restrict__ Cout,
    int M, int Nn, int K, int KC)
{
    __shared__ u16 sm[2 * 16384];

    const int tid = threadIdx.x;
    const int lane = tid & 63;
    const int wv = tid >> 6;
    const int wr = wv >> 1, wc = wv & 1;

    const int flat = blockIdx.x + (blockIdx.y << 3) + (blockIdx.z << 8);
    const int xcd = flat & 7;
    const int j = flat >> 3;
    const int bxi = j & 7;
    const int yy = (j >> 3) & 3;
    const int bz = j >> 5;
    const int bm = (xcd * 4 + yy) * 128;
    const int bn = bxi * 128;
    const int k0 = bz * KC;
    const int NT = KC / 32;

    const int ar = tid >> 1;
    const int ah = tid & 1;
    const float* aPtr = A + (size_t)(bm + ar) * K + ah * 16;
    const int asw = (ar >> 1) & 3;
    const int ac0 = ((2 * ah) ^ asw) << 3;
    const int ac1 = ((2 * ah + 1) ^ asw) << 3;

    int wrow[2], wlc[2];
#pragma unroll
    for (int i = 0; i < 2; ++i) {
        int c = wv * 2 + i;
        wrow[i] = c * 16 + (lane >> 2);
        wlc[i] = ((lane & 3) ^ ((wrow[i] >> 1) & 3)) * 8;
    }

    const int fr = lane & 15, fq = lane >> 4;
    int ia[4], ib[4];
#pragma unroll
    for (int m = 0; m < 4; ++m) {
        int ra = wr * 64 + m * 16 + fr;
        ia[m] = ra * 32 + ((fq ^ ((ra >> 1) & 3)) << 3);
        int rb = wc * 64 + m * 16 + fr;
        ib[m] = rb * 32 + ((fq ^ ((rb >> 1) & 3)) << 3);
    }

    f32x4 acc[4][4];
#pragma unroll
    for (int m = 0; m < 4; ++m)
#pragma unroll
        for (int n = 0; n < 4; ++n)
            acc[m][n] = (f32x4){0.f, 0.f, 0.f, 0.f};

    auto stage_w = [&](u16* dst, int kk) {
#pragma unroll
        for (int i = 0; i < 2; ++i) {
            const int c = wv * 2 + i;
            const u16* gh = WhT + (size_t)(bn + wrow[i]) * K + kk + wlc[i];
            const u16* gl = WlT + (size_t)(bn + wrow[i]) * K + kk + wlc[i];
            __builtin_amdgcn_global_load_lds(
                (const __attribute__((address_space(1))) u32*)gh,
                (__attribute__((address_space(3))) u32*)(dst + 8192 + c * 512), 16, 0, 0);
            __builtin_amdgcn_global_load_lds(
                (const __attribute__((address_space(1))) u32*)gl,
                (__attribute__((address_space(3))) u32*)(dst + 12288 + c * 512), 16, 0, 0);
        }
    };

    auto split_a = [&](u16* dst, float4 v0, float4 v1, float4 v2, float4 v3) {
        u32 hp[8], lp[8];
        split2(v0.x, v0.y, hp[0], lp[0]);
        split2(v0.z, v0.w, hp[1], lp[1]);
        split2(v1.x, v1.y, hp[2], lp[2]);
        split2(v1.z, v1.w, hp[3], lp[3]);
        split2(v2.x, v2.y, hp[4], lp[4]);
        split2(v2.z, v2.w, hp[5], lp[5]);
        split2(v3.x, v3.y, hp[6], lp[6]);
        split2(v3.z, v3.w, hp[7], lp[7]);
        *(uint4*)&dst[ar * 32 + ac0] = make_uint4(hp[0], hp[1], hp[2], hp[3]);
        *(uint4*)&dst[ar * 32 + ac1] = make_uint4(hp[4], hp[5], hp[6], hp[7]);
        *(uint4*)&dst[4096 + ar * 32 + ac0] = make_uint4(lp[0], lp[1], lp[2], lp[3]);
        *(uint4*)&dst[4096 + ar * 32 + ac1] = make_uint4(lp[4], lp[5], lp[6], lp[7]);
    };

    auto compute = [&](const u16* src) {
        s16x8 fah[4], fal[4], fbh[4], fbl[4];
#pragma unroll
        for (int m = 0; m < 4; ++m) {
            fah[m] = *(const s16x8*)&src[ia[m]];
            fal[m] = *(const s16x8*)&src[4096 + ia[m]];
            fbh[m] = *(const s16x8*)&src[8192 + ib[m]];
            fbl[m] = *(const s16x8*)&src[12288 + ib[m]];
        }
        __builtin_amdgcn_s_setprio(1);
#pragma unroll
        for (int m = 0; m < 4; ++m)
#pragma unroll
            for (int n = 0; n < 4; ++n) {
                acc[m][n] = __builtin_amdgcn_mfma_f32_16x16x32_bf16(fah[m], fbh[n], acc[m][n], 0, 0, 0);
                acc[m][n] = __builtin_amdgcn_mfma_f32_16x16x32_bf16(fah[m], fbl[n], acc[m][n], 0, 0, 0);
                acc[m][n] = __builtin_amdgcn_mfma_f32_16x16x32_bf16(fal[m], fbh[n], acc[m][n], 0, 0, 0);
            }
        __builtin_amdgcn_s_setprio(0);
    };

    u16* bufc = sm;
    u16* bufn = sm + 16384;

    stage_w(bufc, k0);
    {
        float4 a0 = *(const float4*)(aPtr + k0 + 0);
        float4 a1 = *(const float4*)(aPtr + k0 + 4);
        float4 a2 = *(const float4*)(aPtr + k0 + 8);
        float4 a3 = *(const float4*)(aPtr + k0 + 12);
        split_a(bufc, a0, a1, a2, a3);
    }
    asm volatile("s_waitcnt vmcnt(0) lgkmcnt(0)\n\ts_barrier" ::: "memory");

    for (int t = 0; t < NT; ++t) {
        float4 a0{}, a1{}, a2{}, a3{};
        const bool hn = (t + 1 < NT);
        if (hn) {
            const int kk = k0 + (t + 1) * 32;
            stage_w(bufn, kk);
            a0 = *(const float4*)(aPtr + kk + 0);
            a1 = *(const float4*)(aPtr + kk + 4);
            a2 = *(const float4*)(aPtr + kk + 8);
            a3 = *(const float4*)(aPtr + kk + 12);
        }
        compute(bufc);
        if (hn) split_a(bufn, a0, a1, a2, a3);
        asm volatile("s_waitcnt vmcnt(0) lgkmcnt(0)\n\ts_barrier" ::: "memory");
        u16* tmp = bufc; bufc = bufn; bufn = tmp;
    }

    if (bias != nullptr) {
#pragma unroll
        for (int n = 0; n < 4; ++n) {
            int col = bn + wc * 64 + n * 16 + fr;
            float bb = bias[col];
#pragma unroll
            for (int m = 0; m < 4; ++m) {
                int row0 = bm + wr * 64 + m * 16 + fq * 4;
#pragma unroll
                for (int jj = 0; jj < 4; ++jj)
                    Cout[(size_t)(row0 + jj) * Nn + col] = fmaxf(acc[m][n][jj] + bb, 0.0f);
            }
        }
    } else {
        float* Cp = Cout + (size_t)bz * M * Nn;
#pragma unroll
        for (int n = 0; n < 4; ++n) {
            int col = bn + wc * 64 + n * 16 + fr;
#pragma unroll
            for (int m = 0; m < 4; ++m) {
                int row0 = bm + wr * 64 + m * 16 + fq * 4;
#pragma unroll
                for (int jj = 0; jj < 4; ++jj)
                    Cp[(size_t)(row0 + jj) * Nn + col] = acc[m][n][jj];
            }
        }
    }
}

// ============ reduce 4 partials + bias + relu (fp32 out, fallback) ============
__global__ __launch_bounds__(256) void reduce_bias_relu(
    const float* __restrict__ Cpart, const float* __restrict__ bias,
    float* __restrict__ X, int MN, int Nn)
{
    const int total = MN / 4;
    for (int i4 = blockIdx.x * 256 + threadIdx.x; i4 < total; i4 += gridDim.x * 256) {
        const size_t o = (size_t)i4 * 4;
        float4 a = *(const float4*)(Cpart + o);
        float4 b = *(const float4*)(Cpart + (size_t)MN + o);
        float4 c = *(const float4*)(Cpart + 2 * (size_t)MN + o);
        float4 d = *(const float4*)(Cpart + 3 * (size_t)MN + o);
        float4 bb = *(const float4*)(bias + (o & (size_t)(Nn - 1)));
        float4 r;
        r.x = fmaxf(a.x + b.x + c.x + d.x + bb.x, 0.0f);
        r.y = fmaxf(a.y + b.y + c.y + d.y + bb.y, 0.0f);
        r.z = fmaxf(a.z + b.z + c.z + d.z + bb.z, 0.0f);
        r.w = fmaxf(a.w + b.w + c.w + d.w + bb.w, 0.0f);
        *(float4*)(X + o) = r;
    }
}

// ============ reduce 2 partials + bias + relu, emit tiled split bf16 (fc6) ======
__global__ __launch_bounds__(256) void reduce2_split_tiled(
    const float* __restrict__ Cpart, const float* __restrict__ bias,
    u16* __restrict__ Xh, u16* __restrict__ Xl, int MN, int Nn)
{
    const int total = MN / 8;
    for (int i = blockIdx.x * 256 + threadIdx.x; i < total; i += gridDim.x * 256) {
        const size_t o = (size_t)i * 8;
        float r8[8];
#pragma unroll
        for (int h = 0; h < 2; ++h) {
            float4 a = *(const float4*)(Cpart + o + h * 4);
            float4 b = *(const float4*)(Cpart + (size_t)MN + o + h * 4);
            float4 bb = *(const float4*)(bias + ((o + h * 4) & (size_t)(Nn - 1)));
            r8[h * 4 + 0] = fmaxf(a.x + b.x + bb.x, 0.0f);
            r8[h * 4 + 1] = fmaxf(a.y + b.y + bb.y, 0.0f);
            r8[h * 4 + 2] = fmaxf(a.z + b.z + bb.z, 0.0f);
            r8[h * 4 + 3] = fmaxf(a.w + b.w + bb.w, 0.0f);
        }
        u32 hp[4], lp[4];
#pragma unroll
        for (int t2 = 0; t2 < 4; ++t2)
            split2(r8[2 * t2], r8[2 * t2 + 1], hp[t2], lp[t2]);
        int row = (int)(o >> 10);                 // Nn == 1024
        int rem = (int)(o & 1023);
        int t = rem >> 5, g = (rem >> 3) & 3;
        size_t dsto = tile_off(row >> 7, 32, t, row, g);
        *(uint4*)&Xh[dsto] = make_uint4(hp[0], hp[1], hp[2], hp[3]);
        *(uint4*)&Xl[dsto] = make_uint4(lp[0], lp[1], lp[2], lp[3]);
    }
}

// ============ heads GEMM + postproc; optionally fuses fc7's 2-partial reduce =====
// fused==1: X-stage = relu(P[o] + P[MN+o] + f7b[col]); else plain X2 load.
__global__ __launch_bounds__(256) void heads_postproc(
    const float* __restrict__ X2, const float* __restrict__ P,
    const float* __restrict__ f7b, int fused,
    const float* __restrict__ Wcat,
    const float* __restrict__ cls_b, const float* __restrict__ box_b,
    const float* __restrict__ proposals,
    float* __restrict__ bxo, float* __restrict__ sco,
    int* __restrict__ lbo, int* __restrict__ vdo)
{
    __shared__ float Xs[16][36];
    __shared__ float Ws[32 * NCOL];
    __shared__ float lgs[16][NCOL];
    const int tid = threadIdx.x;
    const int m0 = blockIdx.x * 16;
    const int tr = tid >> 4;            // 16 rows
    const int tc = tid & 15;            // 16 col-groups x 7
    const size_t MN = (size_t)NPB * HID;
    float acc[7] = {};
    for (int k0 = 0; k0 < HID; k0 += 32) {
        if (tid < 128) {
            int i = tid >> 3, j4 = (tid & 7) * 4;
            size_t off = (size_t)(m0 + i) * HID + k0 + j4;
            float4 v;
            if (fused) {
                float4 a = *(const float4*)(P + off);
                float4 b = *(const float4*)(P + MN + off);
                float4 bb = *(const float4*)(f7b + k0 + j4);
                v.x = fmaxf(a.x + b.x + bb.x, 0.0f);
                v.y = fmaxf(a.y + b.y + bb.y, 0.0f);
                v.z = fmaxf(a.z + b.z + bb.z, 0.0f);
                v.w = fmaxf(a.w + b.w + bb.w, 0.0f);
            } else {
                v = *(const float4*)(X2 + off);
            }
            Xs[i][j4] = v.x; Xs[i][j4 + 1] = v.y; Xs[i][j4 + 2] = v.z; Xs[i][j4 + 3] = v.w;
        }
        const float4* src = (const float4*)(Wcat + (size_t)k0 * NCOL);
        float4* dst = (float4*)Ws;
        for (int i4 = tid; i4 < (32 * NCOL) / 4; i4 += 256) dst[i4] = src[i4];
        __syncthreads();
#pragma unroll 4
        for (int kk = 0; kk < 32; ++kk) {
            float a0 = Xs[tr][kk];
#pragma unroll
            for (int j = 0; j < 7; ++j)
                acc[j] = fmaf(a0, Ws[kk * NCOL + tc * 7 + j], acc[j]);
        }
        __syncthreads();
    }
#pragma unroll
    for (int j = 0; j < 7; ++j)
        lgs[tr][tc * 7 + j] = acc[j];
    __syncthreads();

    if (tid < 16) {
        const int p = m0 + tid;
        const float* lg = lgs[tid];
        float l[21];
        float m = -1e30f;
#pragma unroll
        for (int c = 0; c < 21; ++c) { l[c] = lg[c] + cls_b[c]; m = fmaxf(m, l[c]); }
        float e[21]; float s = 0.0f;
#pragma unroll
        for (int c = 0; c < 21; ++c) { e[c] = expf(l[c] - m); s += e[c]; }
        int best = 1;
#pragma unroll
        for (int c = 2; c < 21; ++c) if (e[c] > e[best]) best = c;
        const float score = e[best] / s;

        float d0 = (lg[21 + best * 4 + 0] + box_b[best * 4 + 0]) * 0.1f;
        float d1 = (lg[21 + best * 4 + 1] + box_b[best * 4 + 1]) * 0.1f;
        float d2 = (lg[21 + best * 4 + 2] + box_b[best * 4 + 2]) * 0.2f;
        float d3 = (lg[21 + best * 4 + 3] + box_b[best * 4 + 3]) * 0.2f;
        const float* pr = proposals + p * 4;
        float w_ = pr[2] - pr[0], h_ = pr[3] - pr[1];
        float cx = pr[0] + 0.5f * w_, cy = pr[1] + 0.5f * h_;
        float pcx = d0 * w_ + cx, pcy = d1 * h_ + cy;
        float pw = expf(d2) * w_, ph = expf(d3) * h_;
        float b0 = pcx - 0.5f * pw, b1 = pcy - 0.5f * ph;
        float b2 = pcx + 0.5f * pw, b3 = pcy + 0.5f * ph;
        b0 = fminf(fmaxf(b0, 0.0f), IMG);
        b1 = fminf(fmaxf(b1, 0.0f), IMG);
        b2 = fminf(fmaxf(b2, 0.0f), IMG);
        b3 = fminf(fmaxf(b3, 0.0f), IMG);
        int vd = (b2 - b0 > 0.0f) && (b3 - b1 > 0.0f) && (score > SCORE_THRESH);
        bxo[p * 4 + 0] = b0; bxo[p * 4 + 1] = b1;
        bxo[p * 4 + 2] = b2; bxo[p * 4 + 3] = b3;
        sco[p] = score;
        lbo[p] = best;
        vdo[p] = vd;
    }
}

// ============ fused NMS + finalize: ballot mask build + pipelined scan ============
__global__ __launch_bounds__(1024) void nms_finalize(
    const float* __restrict__ bx, const float* __restrict__ sc,
    const int* __restrict__ label, const int* __restrict__ valid,
    const float* __restrict__ proposals, float* __restrict__ out)
{
    const int img = blockIdx.x;
    const int base = img * NPROP;
    const int tid = threadIdx.x;
    const int lane = tid & 63;
    const int wv = tid >> 6;                // 16 waves

    __shared__ u64 maskm[NPROP][16];        // 128 KB (aliases sort keys)
    __shared__ float4 sbx[NPROP];           // 16 KB
    __shared__ float sarea[NPROP];          // 4 KB
    __shared__ u64 kword[16];
    __shared__ int nv;

    u64* skey = &maskm[0][0];               // alias (dead before mask build)

    if (tid == 0) nv = 0;

    {
        float s = valid[base + tid] ? sc[base + tid] : -1.0f;
        unsigned u = __float_as_uint(s);
        u = (u & 0x80000000u) ? ~u : (u | 0x80000000u);
        u = ~u;
        skey[tid] = ((u64)u << 32) | (unsigned)tid;
    }
    for (int k = 2; k <= NPROP; k <<= 1) {
        for (int j = k >> 1; j > 0; j >>= 1) {
            __syncthreads();
            int ixj = tid ^ j;
            if (ixj > tid) {
                u64 a = skey[tid], b = skey[ixj];
                bool up = ((tid & k) == 0);
                if (up ? (a > b) : (a < b)) { skey[tid] = b; skey[ixj] = a; }
            }
        }
    }
    __syncthreads();

    const int myp = (int)(skey[tid] & 0xffffffffu);
    {
        float off = (float)label[base + myp] * (IMG + 1.0f);
        float x0 = bx[(base + myp) * 4 + 0] + off;
        float y0 = bx[(base + myp) * 4 + 1] + off;
        float x1 = bx[(base + myp) * 4 + 2] + off;
        float y1 = bx[(base + myp) * 4 + 3] + off;
        sbx[tid] = make_float4(x0, y0, x1, y1);
        sarea[tid] = (x1 - x0) * (y1 - y0);
        int v = valid[base + myp];
        u64 bb = __ballot(v != 0);
        if (lane == 0) kword[wv] = bb;
        if (v) atomicMax(&nv, tid + 1);
    }
    __syncthreads();
    const int nvalid = nv;

    for (int i = wv; i < nvalid; i += 16) {
        const float4 bi = sbx[i];
        const float ai = sarea[i];
#pragma unroll 4
        for (int w = 0; w < 16; ++w) {
            const int j = w * 64 + lane;
            bool sup = false;
            if (j > i && j < nvalid) {
                float4 bj = sbx[j];
                float lt0 = fmaxf(bi.x, bj.x);
                float lt1 = fmaxf(bi.y, bj.y);
                float rb0 = fminf(bi.z, bj.z);
                float rb1 = fminf(bi.w, bj.w);
                float w_ = fmaxf(rb0 - lt0, 0.0f);
                float h_ = fmaxf(rb1 - lt1, 0.0f);
                float inter = w_ * h_;
                float denom = fmaxf(ai + sarea[j] - inter, 1e-9f);
                sup = inter / denom > NMS_THRESH;
            }
            u64 bits = __ballot(sup);
            if (lane == 0) maskm[i][w] = bits;
        }
    }
    __syncthreads();

    if (tid < 64) {
        u64 kw = (tid < 16) ? kword[tid] : 0ull;
        u64 ra = 0, rb = 0, rc = 0, rd = 0;
        if (tid < 16) {
            if (0 < nvalid) ra = maskm[0][tid];
            if (1 < nvalid) rb = maskm[1][tid];
            if (2 < nvalid) rc = maskm[2][tid];
            if (3 < nvalid) rd = maskm[3][tid];
        }
        for (int i = 0; i < nvalid; i += 4) {
            {
                u64 srcw = __shfl(kw, i >> 6, 64);
                if ((srcw >> (i & 63)) & 1ull) { if (tid < 16) kw &= ~ra; }
                if (tid < 16 && i + 4 < nvalid) ra = maskm[i + 4][tid];
            }
            if (i + 1 < nvalid) {
                u64 srcw = __shfl(kw, (i + 1) >> 6, 64);
                if ((srcw >> ((i + 1) & 63)) & 1ull) { if (tid < 16) kw &= ~rb; }
                if (tid < 16 && i + 5 < nvalid) rb = maskm[i + 5][tid];
            }
            if (i + 2 < nvalid) {
                u64 srcw = __shfl(kw, (i + 2) >> 6, 64);
                if ((srcw >> ((i + 2) & 63)) & 1ull) { if (tid < 16) kw &= ~rc; }
                if (tid < 16 && i + 6 < nvalid) rc = maskm[i + 6][tid];
            }
            if (i + 3 < nvalid) {
                u64 srcw = __shfl(kw, (i + 3) >> 6, 64);
                if ((srcw >> ((i + 3) & 63)) & 1ull) { if (tid < 16) kw &= ~rd; }
                if (tid < 16 && i + 7 < nvalid) rd = maskm[i + 7][tid];
            }
        }
        if (tid < 16) kword[tid] = kw;
    }
    __syncthreads();

    {
        const int p = base + myp;
        const bool k = ((kword[tid >> 6] >> (tid & 63)) & 1ull) != 0;
        float* res   = out;
        float* keepo = out + NPB * 6;
        float* rpn   = keepo + NPB;
        float* rcnn  = rpn + NPB * 6;
        float b0 = bx[p * 4 + 0], b1 = bx[p * 4 + 1];
        float b2 = bx[p * 4 + 2], b3 = bx[p * 4 + 3];
        res[p * 6 + 0] = k ? b0 : 0.0f;
        res[p * 6 + 1] = k ? b1 : 0.0f;
        res[p * 6 + 2] = k ? b2 : 0.0f;
        res[p * 6 + 3] = k ? b3 : 0.0f;
        res[p * 6 + 4] = k ? (float)(label[p] - 1) : 0.0f;
        res[p * 6 + 5] = k ? sc[p] : 0.0f;
        keepo[p] = k ? 1.0f : 0.0f;
        rpn[p * 6 + 0] = proposals[p * 4 + 0];
        rpn[p * 6 + 1] = proposals[p * 4 + 1];
        rpn[p * 6 + 2] = proposals[p * 4 + 2];
        rpn[p * 6 + 3] = proposals[p * 4 + 3];
        rpn[p * 6 + 4] = 0.0f;
        rpn[p * 6 + 5] = 0.0f;
        rcnn[p * 6 + 0] = b0;
        rcnn[p * 6 + 1] = b1;
        rcnn[p * 6 + 2] = b2;
        rcnn[p * 6 + 3] = b3;
        rcnn[p * 6 + 4] = 0.0f;
        rcnn[p * 6 + 5] = 0.0f;
    }
}

// ============ launch ============
extern "C" void kernel_launch(void* const* d_in, const int* in_sizes, int n_in,
                              void* d_out, int out_size, void* d_ws, size_t ws_size,
                              hipStream_t stream)
{
    const float* props_feature = (const float*)d_in[0];
    const float* proposals     = (const float*)d_in[1];
    const float* fc6_w         = (const float*)d_in[2];
    const float* fc6_b         = (const float*)d_in[3];
    const float* fc7_w         = (const float*)d_in[4];
    const float* fc7_b         = (const float*)d_in[5];
    const float* cls_w         = (const float*)d_in[6];
    const float* cls_b         = (const float*)d_in[7];
    const float* box_w         = (const float*)d_in[8];
    const float* box_b         = (const float*)d_in[9];
    float* out = (float*)d_out;

    char* ws = (char*)d_ws;
    float* X1     = (float*)(ws);                                  // 16 MB (fallbacks)
    float* X2     = (float*)(ws + 16777216);                       // 16 MB
    float* Wcat   = (float*)(ws + 33554432);
    float* bx     = (float*)(ws + 35848192);
    float* sc     = (float*)(ws + 35913728);
    int*   label  = (int*)  (ws + 35930112);
    int*   valid  = (int*)  (ws + 35946496);
    u16*   W6h    = (u16*)  (ws + 35979264);                       // 24.5 MB
    u16*   W6l    = (u16*)  (ws + 61669376);                       // 24.5 MB
    u16*   W7h    = (u16*)  (ws + 87359488);                       // 2 MB
    u16*   W7l    = (u16*)  (ws + 89456640);                       // 2 MB
    float* Cpart  = (float*)(ws + 91553792);                       // 64 MB
    u16*   A6h    = (u16*)  (ws + 158662656);                      // 98 MB (tiled)
    u16*   A6l    = (u16*)  (ws + 261423104);                      // 98 MB
    u16*   X1h    = (u16*)  (ws + 364183552);                      // 8 MB (tiled)
    u16*   X1l    = (u16*)  (ws + 372572160);                      // 8 MB
    const size_t NEED_SK   = 158662656ull;
    const size_t NEED_FULL = 380960768ull;

    if (ws_size >= NEED_FULL) {
        prep_kernel<<<NB_PREP, 256, 0, stream>>>(
            fc6_w, fc7_w, cls_w, box_w, props_feature,
            W6h, W6l, W7h, W7l, Wcat, A6h, A6l);
        // fc6: split-K x2 (512 blocks = exactly 2/CU; halves partial traffic)
        gemm_2ph_tiled<<<dim3(8, 32, 2), 256, 0, stream>>>(
            A6h, A6l, W6h, W6l, nullptr, Cpart, NPB, HID, FEAT_DIM / 32, FEAT_DIM / 64,
            0, 3, 5);
        reduce2_split_tiled<<<1024, 256, 0, stream>>>(
            Cpart, fc6_b, X1h, X1l, NPB * HID, HID);
        // fc7: split-K x2, partials -> Cpart; reduce fused into heads
        gemm_2ph_tiled<<<dim3(8, 32, 2), 256, 0, stream>>>(
            X1h, X1l, W7h, W7l, nullptr, Cpart, NPB, HID, HID / 32, HID / 64,
            0, 3, 5);
        heads_postproc<<<NPB / 16, 256, 0, stream>>>(
            nullptr, Cpart, fc7_b, 1, Wcat, cls_b, box_b, proposals,
            bx, sc, label, valid);
    } else if (ws_size >= NEED_SK) {
        build_wcat<<<(HID * NCOL + 255) / 256, 256, 0, stream>>>(cls_w, box_w, Wcat);
        transpose_split<<<dim3(HID / 32, FEAT_DIM / 32), 256, 0, stream>>>(
            fc6_w, W6h, W6l, FEAT_DIM, HID);
        transpose_split<<<dim3(HID / 32, HID / 32), 256, 0, stream>>>(
            fc7_w, W7h, W7l, HID, HID);
        gemm_2ph<<<dim3(8, 32, 4), 256, 0, stream>>>(
            props_feature, W6h, W6l, nullptr, Cpart, NPB, HID, FEAT_DIM, FEAT_DIM / 4);
        reduce_bias_relu<<<1024, 256, 0, stream>>>(Cpart, fc6_b, X1, NPB * HID, HID);
        gemm_2ph<<<dim3(8, 32, 1), 256, 0, stream>>>(
            X1, W7h, W7l, fc7_b, X2, NPB, HID, HID, HID);
        heads_postproc<<<NPB / 16, 256, 0, stream>>>(
            X2, nullptr, nullptr, 0, Wcat, cls_b, box_b, proposals,
            bx, sc, label, valid);
    } else {
        build_wcat<<<(HID * NCOL + 255) / 256, 256, 0, stream>>>(cls_w, box_w, Wcat);
        transpose_split<<<dim3(HID / 32, FEAT_DIM / 32), 256, 0, stream>>>(
            fc6_w, W6h, W6l, FEAT_DIM, HID);
        transpose_split<<<dim3(HID / 32, HID / 32), 256, 0, stream>>>(
            fc7_w, W7h, W7l, HID, HID);
        gemm_2ph<<<dim3(8, 32, 1), 256, 0, stream>>>(
            props_feature, W6h, W6l, fc6_b, X1, NPB, HID, FEAT_DIM, FEAT_DIM);
        gemm_2ph<<<dim3(8, 32, 1), 256, 0, stream>>>(
            X1, W7h, W7l, fc7_b, X2, NPB, HID, HID, HID);
        heads_postproc<<<NPB / 16, 256, 0, stream>>>(
            X2, nullptr, nullptr, 0, Wcat, cls_b, box_b, proposals,
            bx, sc, label, valid);
    }

    nms_finalize<<<BATCH, 1024, 0, stream>>>(bx, sc, label, valid, proposals, out);
}